// Round 1
// baseline (1482.280 us; speedup 1.0000x reference)
//
#include <hip/hip_runtime.h>
#include <math.h>

#define TT 4
#define BB 16
#define CC 384
#define NS 256
#define NHD 8
#define HDD 48
#define PLANE 98304      /* CC*NS */
#define TSTR  1572864    /* BB*PLANE */
#define TOT   6291456    /* TT*TSTR */

// workspace float offsets
#define OFF_XS   0L            /* xs spikes / later: out+identity (oid) */
#define OFF_Q    (1L*TOT)      /* q_pre -> q spikes -> tim-out spikes */
#define OFF_K    (2L*TOT)      /* k_pre -> k spikes -> proj_pre */
#define OFF_V    (3L*TOT)      /* v_pre -> v spikes */
#define OFF_OUTS (4L*TOT)      /* TIM outs [T,B,C,N] */
#define OFF_KT   (5L*TOT)
#define OFF_VT   (6L*TOT)
#define OFF_CNT  (7L*TOT)      /* u32 spike counter (16B region) */
#define OFF_AMAP_BYTES ((7L*TOT + 16L)*4L)  /* u8 attn map, 33554432 B */

// ---------------- LIF over input x -> xs (vth=1.0) ----------------
__global__ __launch_bounds__(256) void k_lif_x(const float* __restrict__ x,
                                               float* __restrict__ xs)
{
    int i = blockIdx.x*256 + threadIdx.x;   // [0, TSTR)
    float v = 0.f;
    #pragma unroll
    for (int t = 0; t < TT; t++) {
        float xt = x[t*TSTR + i];
        v += (xt - v)*0.5f;
        float s = (v - 1.0f) >= 0.f ? 1.f : 0.f;
        xs[t*TSTR + i] = s;
        v *= (1.f - s);
    }
}

// ---------------- QKV GEMM: Y[t,b] = W @ xs[t,b], BN on k/v ----------------
__global__ __launch_bounds__(256) void k_gemm_qkv(
    const float* __restrict__ wq, const float* __restrict__ wk, const float* __restrict__ wv,
    const float* __restrict__ kbn, const float* __restrict__ vbn,
    const float* __restrict__ xs,
    float* __restrict__ qo, float* __restrict__ ko, float* __restrict__ vo)
{
    int which = blockIdx.z >> 6;      // 0=q,1=k,2=v
    int tb    = blockIdx.z & 63;
    const float* W  = (which==0) ? wq : (which==1 ? wk : wv);
    const float* bn = (which==0) ? nullptr : (which==1 ? kbn : vbn);
    float* Y        = (which==0) ? qo : (which==1 ? ko : vo);
    const float* X  = xs + (long)tb*PLANE;
    Y += (long)tb*PLANE;
    int d0 = blockIdx.y*64, n0 = blockIdx.x*64;

    __shared__ float As[16][68];
    __shared__ float Bs[16][68];
    int tid = threadIdx.x;
    int ty = tid >> 4, tx = tid & 15;
    float acc[4][4] = {};

    for (int k0 = 0; k0 < CC; k0 += 16) {
        {   // A: W tile 64x16 -> As[k][d]
            int d  = tid >> 2;
            int kq = (tid & 3)*4;
            float4 a4 = *(const float4*)&W[(long)(d0+d)*CC + k0 + kq];
            As[kq+0][d]=a4.x; As[kq+1][d]=a4.y; As[kq+2][d]=a4.z; As[kq+3][d]=a4.w;
        }
        {   // B: X tile 16x64
            int k  = tid >> 4;
            int nq = (tid & 15)*4;
            *(float4*)&Bs[k][nq] = *(const float4*)&X[(long)(k0+k)*NS + n0 + nq];
        }
        __syncthreads();
        #pragma unroll
        for (int kk = 0; kk < 16; kk++) {
            float a0=As[kk][ty*4+0], a1=As[kk][ty*4+1], a2=As[kk][ty*4+2], a3=As[kk][ty*4+3];
            float b0=Bs[kk][tx*4+0], b1=Bs[kk][tx*4+1], b2=Bs[kk][tx*4+2], b3=Bs[kk][tx*4+3];
            acc[0][0]+=a0*b0; acc[0][1]+=a0*b1; acc[0][2]+=a0*b2; acc[0][3]+=a0*b3;
            acc[1][0]+=a1*b0; acc[1][1]+=a1*b1; acc[1][2]+=a1*b2; acc[1][3]+=a1*b3;
            acc[2][0]+=a2*b0; acc[2][1]+=a2*b1; acc[2][2]+=a2*b2; acc[2][3]+=a2*b3;
            acc[3][0]+=a3*b0; acc[3][1]+=a3*b1; acc[3][2]+=a3*b2; acc[3][3]+=a3*b3;
        }
        __syncthreads();
    }
    #pragma unroll
    for (int i = 0; i < 4; i++) {
        int d = d0 + ty*4 + i;
        float inv = 1.f, mu = 0.f, be = 0.f;
        bool hasbn = (bn != nullptr);
        if (hasbn) {
            float g = bn[d]; be = bn[CC+d]; mu = bn[2*CC+d]; float va = bn[3*CC+d];
            inv = g / sqrtf(va + 1e-5f);
        }
        float4 o4;
        float v0 = acc[i][0], v1 = acc[i][1], v2 = acc[i][2], v3 = acc[i][3];
        if (hasbn) { v0 = inv*(v0-mu)+be; v1 = inv*(v1-mu)+be; v2 = inv*(v2-mu)+be; v3 = inv*(v3-mu)+be; }
        o4.x=v0; o4.y=v1; o4.z=v2; o4.w=v3;
        *(float4*)&Y[(long)d*NS + n0 + tx*4] = o4;
    }
}

// ---------------- LIF for q(0.05)/k(1.0)/v(1.0), in-place ----------------
// also: q at t=0 -> outs[0]; v spikes -> d_out v-region in heads layout
__global__ __launch_bounds__(256) void k_lif_qkv(
    float* __restrict__ qb, float* __restrict__ kb, float* __restrict__ vb,
    float* __restrict__ outs0, float* __restrict__ vout)
{
    int which = blockIdx.y;
    int i = blockIdx.x*256 + threadIdx.x;
    float* buf = (which==0) ? qb : (which==1 ? kb : vb);
    float vth  = (which==0) ? 0.05f : 1.0f;
    int b=0, n=0, h=0, dd=0;
    if (which == 2) {
        b = i / PLANE; int r = i % PLANE;
        int c = r >> 8; n = r & 255;
        h = c / HDD; dd = c % HDD;
    }
    float v = 0.f;
    #pragma unroll
    for (int t = 0; t < TT; t++) {
        float xt = buf[t*TSTR + i];
        v += (xt - v)*0.5f;
        float s = (v - vth) >= 0.f ? 1.f : 0.f;
        buf[t*TSTR + i] = s;
        if (which == 0 && t == 0) outs0[i] = s;
        if (which == 2)
            vout[(((long)(t*BB+b)*NHD + h)*NS + n)*HDD + dd] = s;
        v *= (1.f - s);
    }
}

// ---------------- TIM conv1d step i: cur = s*0.6 + q_i*0.4 ----------------
__global__ __launch_bounds__(256) void k_tim_conv(
    const float* __restrict__ w, const float* __restrict__ bias,
    const float* __restrict__ prev,   // outs[i-1], [B,C,N]
    const float* __restrict__ qi,     // q spikes at t=i, [B,C,N]
    float* __restrict__ cur)          // outs[i]
{
    int b = blockIdx.z, d0 = blockIdx.y*64, n0 = blockIdx.x*32;
    __shared__ float Ws[64][85];   // [d][ci*5+k]
    __shared__ float Xs[16][40];   // [ci][n halo 36]
    int tid = threadIdx.x, ty = tid >> 4, tx = tid & 15;  // 4 d x 2 n per thread
    float acc[4][2] = {};

    for (int c0 = 0; c0 < CC; c0 += 16) {
        {   // W chunk: 64 x 80
            int d = tid >> 2, p = (tid & 3)*20;
            const float* src = &w[(long)(d0+d)*CC*5 + c0*5 + p];
            #pragma unroll
            for (int q = 0; q < 5; q++) {
                float4 t4 = *(const float4*)&src[q*4];
                Ws[d][p+q*4+0]=t4.x; Ws[d][p+q*4+1]=t4.y; Ws[d][p+q*4+2]=t4.z; Ws[d][p+q*4+3]=t4.w;
            }
        }
        for (int idx = tid; idx < 16*36; idx += 256) {
            int ci = idx / 36, col = idx % 36;
            int n = n0 + col - 2;
            Xs[ci][col] = (n >= 0 && n < NS) ? prev[(long)b*PLANE + (c0+ci)*NS + n] : 0.f;
        }
        __syncthreads();
        #pragma unroll
        for (int ci = 0; ci < 16; ci++) {
            #pragma unroll
            for (int k = 0; k < 5; k++) {
                float w0=Ws[ty*4+0][ci*5+k], w1=Ws[ty*4+1][ci*5+k];
                float w2=Ws[ty*4+2][ci*5+k], w3=Ws[ty*4+3][ci*5+k];
                float x0=Xs[ci][tx*2+0+k],   x1=Xs[ci][tx*2+1+k];
                acc[0][0]+=w0*x0; acc[0][1]+=w0*x1;
                acc[1][0]+=w1*x0; acc[1][1]+=w1*x1;
                acc[2][0]+=w2*x0; acc[2][1]+=w2*x1;
                acc[3][0]+=w3*x0; acc[3][1]+=w3*x1;
            }
        }
        __syncthreads();
    }
    #pragma unroll
    for (int i = 0; i < 4; i++) {
        int d = d0 + ty*4 + i;
        float bv = bias[d];
        #pragma unroll
        for (int j = 0; j < 2; j++) {
            int n = n0 + tx*2 + j;
            float c = acc[i][j] + bv;
            float s = (c*0.5f - 0.3f) >= 0.f ? 1.f : 0.f;
            float qv = qi[(long)b*PLANE + d*NS + n];
            cur[(long)b*PLANE + d*NS + n] = s*0.6f + qv*0.4f;
        }
    }
}

// ---------------- TIM output LIF (vth=0.5) + spike count ----------------
__global__ __launch_bounds__(256) void k_tim_lif(const float* __restrict__ outs,
                                                 float* __restrict__ q,
                                                 unsigned* __restrict__ cnt)
{
    int i = blockIdx.x*256 + threadIdx.x;
    float v = 0.f; unsigned c = 0;
    #pragma unroll
    for (int t = 0; t < TT; t++) {
        float xt = outs[t*TSTR + i];
        v += (xt - v)*0.5f;
        float s = (v - 0.5f) >= 0.f ? 1.f : 0.f;
        q[t*TSTR + i] = s;
        c += (unsigned)s;
        v *= (1.f - s);
    }
    #pragma unroll
    for (int off = 32; off >= 1; off >>= 1) c += __shfl_down(c, off, 64);
    if ((threadIdx.x & 63) == 0) atomicAdd(cnt, c);
}

// ---------------- dst transform + bn_last for k_t / v_t ----------------
__global__ __launch_bounds__(256) void k_dst(
    const float* __restrict__ dw, const float* __restrict__ dbn,
    const float* __restrict__ kin, const float* __restrict__ vin,
    float* __restrict__ kt, float* __restrict__ vt)
{
    int tb  = blockIdx.z;
    int h   = blockIdx.y & 7;
    int isv = blockIdx.y >> 3;
    int n0  = blockIdx.x*32;
    const float* src = (isv ? vin : kin) + (long)tb*PLANE + (h*HDD)*NS;
    float* dst       = (isv ? vt  : kt)  + ((long)(tb*NHD + h)*NS)*HDD;
    __shared__ float Xs[48][33];
    __shared__ float Wsh[48][49];
    int tid = threadIdx.x;
    for (int idx = tid; idx < 48*32; idx += 256) {
        int d = idx >> 5, n = idx & 31;
        Xs[d][n] = src[d*NS + n0 + n];
    }
    for (int idx = tid; idx < 48*48; idx += 256) {
        int e = idx / 48, d = idx % 48;
        Wsh[e][d] = dw[idx];
    }
    __syncthreads();
    #pragma unroll
    for (int r = 0; r < 6; r++) {
        int o = tid + r*256;
        int n = o / 48, e = o % 48;
        float acc = 0.f;
        #pragma unroll
        for (int d = 0; d < 48; d++) acc += Wsh[e][d]*Xs[d][n];
        float g = dbn[e], be = dbn[48+e], mu = dbn[96+e], va = dbn[144+e];
        float val = g / sqrtf(va + 1e-5f) * (acc - mu) + be;
        dst[(long)(n0+n)*HDD + e] = val;
    }
}

// ---------------- attention QK^T * c1 -> fused LIF(0.5) -> u8 map ----------------
__global__ __launch_bounds__(256) void k_attn(
    const float* __restrict__ q, const float* __restrict__ kt,
    const unsigned* __restrict__ cnt, unsigned char* __restrict__ amap)
{
    int bh = blockIdx.z;            // b*8+h
    int b = bh >> 3, h = bh & 7;
    int n0 = blockIdx.y*32, m0 = blockIdx.x*32;
    float mean = (float)(*cnt) / 6291456.0f;
    float c1 = fminf(1.0f / sqrtf(mean*48.0f + 1e-6f), 10.0f);

    __shared__ float Qs[48][33];
    __shared__ float Ks[32][49];
    int tid = threadIdx.x;
    int n   = tid >> 3;          // 0..31
    int m0l = (tid & 7)*4;       // 0..28
    float vmem[4] = {0.f,0.f,0.f,0.f};

    for (int t = 0; t < TT; t++) {
        int tb = t*BB + b;
        const float* qsrc = q  + (long)tb*PLANE + (h*HDD)*NS;
        const float* ksrc = kt + ((long)(tb*NHD + h)*NS)*HDD;
        __syncthreads();
        for (int idx = tid; idx < 48*32; idx += 256) {
            int d = idx >> 5, nn = idx & 31;
            Qs[d][nn] = qsrc[d*NS + n0 + nn];
        }
        for (int idx = tid; idx < 32*48; idx += 256) {
            int m = idx / 48, e = idx % 48;
            Ks[m][e] = ksrc[(long)(m0+m)*HDD + e];
        }
        __syncthreads();
        uchar4 sv;
        unsigned char* svp = (unsigned char*)&sv;
        #pragma unroll
        for (int r = 0; r < 4; r++) {
            int m = m0l + r;
            float acc = 0.f;
            #pragma unroll
            for (int d = 0; d < 48; d++) acc += Qs[d][n]*Ks[m][d];
            float a = acc*c1;
            float v = vmem[r];
            v += (a - v)*0.5f;
            float s = (v - 0.5f) >= 0.f ? 1.f : 0.f;
            svp[r] = (unsigned char)s;
            vmem[r] = v*(1.f - s);
        }
        *(uchar4*)&amap[((long)(tb*NHD + h)*NS + n0 + n)*NS + m0 + m0l] = sv;
    }
}

// ---------------- out = attn_map @ v_t, reorder + identity ----------------
__global__ __launch_bounds__(256) void k_outmm(
    const unsigned char* __restrict__ amap, const float* __restrict__ vt,
    const float* __restrict__ x, float* __restrict__ oid)
{
    int tb = blockIdx.z;
    int h  = blockIdx.y;
    int n0 = blockIdx.x*64;
    __shared__ float As[64][65];
    __shared__ float Vs[64][49];
    int tid = threadIdx.x, ty = tid >> 4, tx = tid & 15;  // ty->3 e, tx->4 n
    float acc[4][3] = {};
    const unsigned char* abase = amap + ((long)(tb*NHD + h)*NS + n0)*NS;
    const float* vbase = vt + ((long)(tb*NHD + h)*NS)*HDD;

    for (int m0 = 0; m0 < NS; m0 += 64) {
        for (int idx = tid; idx < 1024; idx += 256) {
            int n = idx >> 4, mq = (idx & 15)*4;
            uchar4 u = *(const uchar4*)&abase[(long)n*NS + m0 + mq];
            As[n][mq+0]=(float)u.x; As[n][mq+1]=(float)u.y; As[n][mq+2]=(float)u.z; As[n][mq+3]=(float)u.w;
        }
        for (int idx = tid; idx < 64*48; idx += 256) {
            int m = idx / 48, e = idx % 48;
            Vs[m][e] = vbase[(long)(m0+m)*HDD + e];
        }
        __syncthreads();
        #pragma unroll
        for (int m = 0; m < 64; m++) {
            float a0=As[tx*4+0][m], a1=As[tx*4+1][m], a2=As[tx*4+2][m], a3=As[tx*4+3][m];
            float v0=Vs[m][ty*3+0], v1=Vs[m][ty*3+1], v2=Vs[m][ty*3+2];
            acc[0][0]+=a0*v0; acc[0][1]+=a0*v1; acc[0][2]+=a0*v2;
            acc[1][0]+=a1*v0; acc[1][1]+=a1*v1; acc[1][2]+=a1*v2;
            acc[2][0]+=a2*v0; acc[2][1]+=a2*v1; acc[2][2]+=a2*v2;
            acc[3][0]+=a3*v0; acc[3][1]+=a3*v1; acc[3][2]+=a3*v2;
        }
        __syncthreads();
    }
    #pragma unroll
    for (int j = 0; j < 3; j++) {
        int e = ty*3 + j;
        long base = (long)tb*PLANE + (h*HDD + e)*NS + n0 + tx*4;
        float4 o4;
        o4.x = acc[0][j] + x[base+0];
        o4.y = acc[1][j] + x[base+1];
        o4.z = acc[2][j] + x[base+2];
        o4.w = acc[3][j] + x[base+3];
        *(float4*)&oid[base] = o4;
    }
}

// ---------------- proj GEMM + bias + BN ----------------
__global__ __launch_bounds__(256) void k_gemm_proj(
    const float* __restrict__ W, const float* __restrict__ bias, const float* __restrict__ bn,
    const float* __restrict__ Xfull, float* __restrict__ Yfull)
{
    int tb = blockIdx.z;
    const float* X = Xfull + (long)tb*PLANE;
    float* Y = Yfull + (long)tb*PLANE;
    int d0 = blockIdx.y*64, n0 = blockIdx.x*64;

    __shared__ float As[16][68];
    __shared__ float Bs[16][68];
    int tid = threadIdx.x;
    int ty = tid >> 4, tx = tid & 15;
    float acc[4][4] = {};

    for (int k0 = 0; k0 < CC; k0 += 16) {
        {
            int d = tid >> 2, kq = (tid & 3)*4;
            float4 a4 = *(const float4*)&W[(long)(d0+d)*CC + k0 + kq];
            As[kq+0][d]=a4.x; As[kq+1][d]=a4.y; As[kq+2][d]=a4.z; As[kq+3][d]=a4.w;
        }
        {
            int k = tid >> 4, nq = (tid & 15)*4;
            *(float4*)&Bs[k][nq] = *(const float4*)&X[(long)(k0+k)*NS + n0 + nq];
        }
        __syncthreads();
        #pragma unroll
        for (int kk = 0; kk < 16; kk++) {
            float a0=As[kk][ty*4+0], a1=As[kk][ty*4+1], a2=As[kk][ty*4+2], a3=As[kk][ty*4+3];
            float b0=Bs[kk][tx*4+0], b1=Bs[kk][tx*4+1], b2=Bs[kk][tx*4+2], b3=Bs[kk][tx*4+3];
            acc[0][0]+=a0*b0; acc[0][1]+=a0*b1; acc[0][2]+=a0*b2; acc[0][3]+=a0*b3;
            acc[1][0]+=a1*b0; acc[1][1]+=a1*b1; acc[1][2]+=a1*b2; acc[1][3]+=a1*b3;
            acc[2][0]+=a2*b0; acc[2][1]+=a2*b1; acc[2][2]+=a2*b2; acc[2][3]+=a2*b3;
            acc[3][0]+=a3*b0; acc[3][1]+=a3*b1; acc[3][2]+=a3*b2; acc[3][3]+=a3*b3;
        }
        __syncthreads();
    }
    #pragma unroll
    for (int i = 0; i < 4; i++) {
        int d = d0 + ty*4 + i;
        float g = bn[d], be = bn[CC+d], mu = bn[2*CC+d], va = bn[3*CC+d];
        float inv = g / sqrtf(va + 1e-5f);
        float bv = bias[d];
        float4 o4;
        o4.x = inv*((acc[i][0]+bv) - mu) + be;
        o4.y = inv*((acc[i][1]+bv) - mu) + be;
        o4.z = inv*((acc[i][2]+bv) - mu) + be;
        o4.w = inv*((acc[i][3]+bv) - mu) + be;
        *(float4*)&Y[(long)d*NS + n0 + tx*4] = o4;
    }
}

// ---------------- final LIF (vth=1.0) -> d_out ----------------
__global__ __launch_bounds__(256) void k_final_lif(const float* __restrict__ pre,
                                                   float* __restrict__ out)
{
    int i = blockIdx.x*256 + threadIdx.x;
    float v = 0.f;
    #pragma unroll
    for (int t = 0; t < TT; t++) {
        float xt = pre[t*TSTR + i];
        v += (xt - v)*0.5f;
        float s = (v - 1.0f) >= 0.f ? 1.f : 0.f;
        out[t*TSTR + i] = s;
        v *= (1.f - s);
    }
}

extern "C" void kernel_launch(void* const* d_in, const int* in_sizes, int n_in,
                              void* d_out, int out_size, void* d_ws, size_t ws_size,
                              hipStream_t stream) {
    const float* x   = (const float*)d_in[0];
    const float* wq  = (const float*)d_in[1];
    const float* wk  = (const float*)d_in[2];
    const float* wv  = (const float*)d_in[3];
    const float* kbn = (const float*)d_in[4];
    const float* vbn = (const float*)d_in[5];
    const float* dw  = (const float*)d_in[6];
    const float* dbn = (const float*)d_in[7];
    const float* pw  = (const float*)d_in[8];
    const float* pb  = (const float*)d_in[9];
    const float* pbn = (const float*)d_in[10];
    const float* tw  = (const float*)d_in[11];
    const float* tbi = (const float*)d_in[12];

    float* out  = (float*)d_out;
    float* vout = out + TOT;

    float* ws   = (float*)d_ws;
    float* xs   = ws + OFF_XS;     // xs spikes; later reused as oid
    float* qb   = ws + OFF_Q;
    float* kb   = ws + OFF_K;      // later reused as proj_pre
    float* vb   = ws + OFF_V;
    float* outs = ws + OFF_OUTS;
    float* kt   = ws + OFF_KT;
    float* vt   = ws + OFF_VT;
    unsigned* cnt = (unsigned*)(ws + OFF_CNT);
    unsigned char* amap = (unsigned char*)d_ws + OFF_AMAP_BYTES;

    hipMemsetAsync(cnt, 0, 16, stream);

    // 1. shortcut LIF
    k_lif_x<<<dim3(TSTR/256), 256, 0, stream>>>(x, xs);
    // 2. q/k/v 1x1 convs (+BN for k,v)
    k_gemm_qkv<<<dim3(4, 6, 192), 256, 0, stream>>>(wq, wk, wv, kbn, vbn, xs, qb, kb, vb);
    // 3. LIF on q/k/v; q[0]->outs[0]; v spikes -> d_out (heads layout)
    k_lif_qkv<<<dim3(TSTR/256, 3), 256, 0, stream>>>(qb, kb, vb, outs, vout);
    // 4. TIM recurrent conv chain
    for (int i = 1; i < TT; i++) {
        k_tim_conv<<<dim3(8, 6, 16), 256, 0, stream>>>(
            tw, tbi, outs + (long)(i-1)*TSTR, qb + (long)i*TSTR, outs + (long)i*TSTR);
    }
    // 5. TIM output LIF (vth 0.5) -> q spikes (overwrites qb) + spike count
    k_tim_lif<<<dim3(TSTR/256), 256, 0, stream>>>(outs, qb, cnt);
    // 6. dst transform + bn_last
    k_dst<<<dim3(8, 16, 64), 256, 0, stream>>>(dw, dbn, kb, vb, kt, vt);
    // 7. attention + fused LIF -> binary map
    k_attn<<<dim3(8, 8, 128), 256, 0, stream>>>(qb, kt, cnt, amap);
    // 8. attn_map @ v_t, reorder, + identity  (oid into xs buffer)
    k_outmm<<<dim3(4, 8, 64), 256, 0, stream>>>(amap, vt, x, xs);
    // 9. proj GEMM + bias + BN (proj_pre into kb buffer)
    k_gemm_proj<<<dim3(4, 6, 64), 256, 0, stream>>>(pw, pb, pbn, xs, kb);
    // 10. final LIF -> out
    k_final_lif<<<dim3(TSTR/256), 256, 0, stream>>>(kb, out);
}

// Round 2
// 1222.020 us; speedup vs baseline: 1.2130x; 1.2130x over previous
//
#include <hip/hip_runtime.h>
#include <math.h>

#define TT 4
#define BB 16
#define CC 384
#define NS 256
#define NHD 8
#define HDD 48
#define PLANE 98304      /* CC*NS */
#define TSTR  1572864    /* BB*PLANE */
#define TOT   6291456    /* TT*TSTR */

// workspace float offsets
#define OFF_XS   0L            /* xs spikes / later: out+identity (oid) */
#define OFF_Q    (1L*TOT)      /* q_pre -> q spikes -> tim-out spikes */
#define OFF_K    (2L*TOT)      /* k_pre -> k spikes -> proj_pre */
#define OFF_V    (3L*TOT)      /* v_pre -> v spikes */
#define OFF_OUTS (4L*TOT)      /* TIM outs [T,B,C,N] */
#define OFF_KT   (5L*TOT)      /* kt; ALSO: spike-count partials live here
                                  transiently between k_tim_lif and k_reduce
                                  (k_dst overwrites later in stream order) */
#define OFF_VT   (6L*TOT)
#define OFF_CNT  (7L*TOT)      /* u32 spike counter (16B region) */
#define OFF_AMAP_BYTES ((7L*TOT + 16L)*4L)  /* u8 attn map, 33554432 B */

#define NPART 6144             /* TSTR/256 blocks of k_tim_lif */

// ---------------- LIF over input x -> xs (vth=1.0) ----------------
__global__ __launch_bounds__(256) void k_lif_x(const float* __restrict__ x,
                                               float* __restrict__ xs)
{
    int i = blockIdx.x*256 + threadIdx.x;   // [0, TSTR)
    float v = 0.f;
    #pragma unroll
    for (int t = 0; t < TT; t++) {
        float xt = x[t*TSTR + i];
        v += (xt - v)*0.5f;
        float s = (v - 1.0f) >= 0.f ? 1.f : 0.f;
        xs[t*TSTR + i] = s;
        v *= (1.f - s);
    }
}

// ---------------- QKV GEMM: Y[t,b] = W @ xs[t,b], BN on k/v ----------------
__global__ __launch_bounds__(256) void k_gemm_qkv(
    const float* __restrict__ wq, const float* __restrict__ wk, const float* __restrict__ wv,
    const float* __restrict__ kbn, const float* __restrict__ vbn,
    const float* __restrict__ xs,
    float* __restrict__ qo, float* __restrict__ ko, float* __restrict__ vo)
{
    int which = blockIdx.z >> 6;      // 0=q,1=k,2=v
    int tb    = blockIdx.z & 63;
    const float* W  = (which==0) ? wq : (which==1 ? wk : wv);
    const float* bn = (which==0) ? nullptr : (which==1 ? kbn : vbn);
    float* Y        = (which==0) ? qo : (which==1 ? ko : vo);
    const float* X  = xs + (long)tb*PLANE;
    Y += (long)tb*PLANE;
    int d0 = blockIdx.y*64, n0 = blockIdx.x*64;

    __shared__ float As[16][68];
    __shared__ float Bs[16][68];
    int tid = threadIdx.x;
    int ty = tid >> 4, tx = tid & 15;
    float acc[4][4] = {};

    for (int k0 = 0; k0 < CC; k0 += 16) {
        {   // A: W tile 64x16 -> As[k][d]
            int d  = tid >> 2;
            int kq = (tid & 3)*4;
            float4 a4 = *(const float4*)&W[(long)(d0+d)*CC + k0 + kq];
            As[kq+0][d]=a4.x; As[kq+1][d]=a4.y; As[kq+2][d]=a4.z; As[kq+3][d]=a4.w;
        }
        {   // B: X tile 16x64
            int k  = tid >> 4;
            int nq = (tid & 15)*4;
            *(float4*)&Bs[k][nq] = *(const float4*)&X[(long)(k0+k)*NS + n0 + nq];
        }
        __syncthreads();
        #pragma unroll
        for (int kk = 0; kk < 16; kk++) {
            float a0=As[kk][ty*4+0], a1=As[kk][ty*4+1], a2=As[kk][ty*4+2], a3=As[kk][ty*4+3];
            float b0=Bs[kk][tx*4+0], b1=Bs[kk][tx*4+1], b2=Bs[kk][tx*4+2], b3=Bs[kk][tx*4+3];
            acc[0][0]+=a0*b0; acc[0][1]+=a0*b1; acc[0][2]+=a0*b2; acc[0][3]+=a0*b3;
            acc[1][0]+=a1*b0; acc[1][1]+=a1*b1; acc[1][2]+=a1*b2; acc[1][3]+=a1*b3;
            acc[2][0]+=a2*b0; acc[2][1]+=a2*b1; acc[2][2]+=a2*b2; acc[2][3]+=a2*b3;
            acc[3][0]+=a3*b0; acc[3][1]+=a3*b1; acc[3][2]+=a3*b2; acc[3][3]+=a3*b3;
        }
        __syncthreads();
    }
    #pragma unroll
    for (int i = 0; i < 4; i++) {
        int d = d0 + ty*4 + i;
        float inv = 1.f, mu = 0.f, be = 0.f;
        bool hasbn = (bn != nullptr);
        if (hasbn) {
            float g = bn[d]; be = bn[CC+d]; mu = bn[2*CC+d]; float va = bn[3*CC+d];
            inv = g / sqrtf(va + 1e-5f);
        }
        float4 o4;
        float v0 = acc[i][0], v1 = acc[i][1], v2 = acc[i][2], v3 = acc[i][3];
        if (hasbn) { v0 = inv*(v0-mu)+be; v1 = inv*(v1-mu)+be; v2 = inv*(v2-mu)+be; v3 = inv*(v3-mu)+be; }
        o4.x=v0; o4.y=v1; o4.z=v2; o4.w=v3;
        *(float4*)&Y[(long)d*NS + n0 + tx*4] = o4;
    }
}

// ---------------- LIF for q(0.05)/k(1.0)/v(1.0), in-place ----------------
// also: q at t=0 -> outs[0]; v spikes -> d_out v-region in heads layout
__global__ __launch_bounds__(256) void k_lif_qkv(
    float* __restrict__ qb, float* __restrict__ kb, float* __restrict__ vb,
    float* __restrict__ outs0, float* __restrict__ vout)
{
    int which = blockIdx.y;
    int i = blockIdx.x*256 + threadIdx.x;
    float* buf = (which==0) ? qb : (which==1 ? kb : vb);
    float vth  = (which==0) ? 0.05f : 1.0f;
    int b=0, n=0, h=0, dd=0;
    if (which == 2) {
        b = i / PLANE; int r = i % PLANE;
        int c = r >> 8; n = r & 255;
        h = c / HDD; dd = c % HDD;
    }
    float v = 0.f;
    #pragma unroll
    for (int t = 0; t < TT; t++) {
        float xt = buf[t*TSTR + i];
        v += (xt - v)*0.5f;
        float s = (v - vth) >= 0.f ? 1.f : 0.f;
        buf[t*TSTR + i] = s;
        if (which == 0 && t == 0) outs0[i] = s;
        if (which == 2)
            vout[(((long)(t*BB+b)*NHD + h)*NS + n)*HDD + dd] = s;
        v *= (1.f - s);
    }
}

// ---------------- TIM conv1d step i: cur = s*0.6 + q_i*0.4 ----------------
__global__ __launch_bounds__(256) void k_tim_conv(
    const float* __restrict__ w, const float* __restrict__ bias,
    const float* __restrict__ prev,   // outs[i-1], [B,C,N]
    const float* __restrict__ qi,     // q spikes at t=i, [B,C,N]
    float* __restrict__ cur)          // outs[i]
{
    int b = blockIdx.z, d0 = blockIdx.y*64, n0 = blockIdx.x*32;
    __shared__ float Ws[64][85];   // [d][ci*5+k]
    __shared__ float Xs[16][40];   // [ci][n halo 36]
    int tid = threadIdx.x, ty = tid >> 4, tx = tid & 15;  // 4 d x 2 n per thread
    float acc[4][2] = {};

    for (int c0 = 0; c0 < CC; c0 += 16) {
        {   // W chunk: 64 x 80
            int d = tid >> 2, p = (tid & 3)*20;
            const float* src = &w[(long)(d0+d)*CC*5 + c0*5 + p];
            #pragma unroll
            for (int q = 0; q < 5; q++) {
                float4 t4 = *(const float4*)&src[q*4];
                Ws[d][p+q*4+0]=t4.x; Ws[d][p+q*4+1]=t4.y; Ws[d][p+q*4+2]=t4.z; Ws[d][p+q*4+3]=t4.w;
            }
        }
        for (int idx = tid; idx < 16*36; idx += 256) {
            int ci = idx / 36, col = idx % 36;
            int n = n0 + col - 2;
            Xs[ci][col] = (n >= 0 && n < NS) ? prev[(long)b*PLANE + (c0+ci)*NS + n] : 0.f;
        }
        __syncthreads();
        #pragma unroll
        for (int ci = 0; ci < 16; ci++) {
            #pragma unroll
            for (int k = 0; k < 5; k++) {
                float w0=Ws[ty*4+0][ci*5+k], w1=Ws[ty*4+1][ci*5+k];
                float w2=Ws[ty*4+2][ci*5+k], w3=Ws[ty*4+3][ci*5+k];
                float x0=Xs[ci][tx*2+0+k],   x1=Xs[ci][tx*2+1+k];
                acc[0][0]+=w0*x0; acc[0][1]+=w0*x1;
                acc[1][0]+=w1*x0; acc[1][1]+=w1*x1;
                acc[2][0]+=w2*x0; acc[2][1]+=w2*x1;
                acc[3][0]+=w3*x0; acc[3][1]+=w3*x1;
            }
        }
        __syncthreads();
    }
    #pragma unroll
    for (int i = 0; i < 4; i++) {
        int d = d0 + ty*4 + i;
        float bv = bias[d];
        #pragma unroll
        for (int j = 0; j < 2; j++) {
            int n = n0 + tx*2 + j;
            float c = acc[i][j] + bv;
            float s = (c*0.5f - 0.3f) >= 0.f ? 1.f : 0.f;
            float qv = qi[(long)b*PLANE + d*NS + n];
            cur[(long)b*PLANE + d*NS + n] = s*0.6f + qv*0.4f;
        }
    }
}

// ---------------- TIM output LIF (vth=0.5) + per-block spike count ----------------
// Atomic-free: block-reduce into partials[blockIdx.x]; k_cnt_reduce sums them.
// (R0 post-mortem: 24576 single-address device atomics serialized -> 283us.)
__global__ __launch_bounds__(256) void k_tim_lif(const float* __restrict__ outs,
                                                 float* __restrict__ q,
                                                 unsigned* __restrict__ partials)
{
    int i = blockIdx.x*256 + threadIdx.x;
    float v = 0.f; unsigned c = 0;
    #pragma unroll
    for (int t = 0; t < TT; t++) {
        float xt = outs[t*TSTR + i];
        v += (xt - v)*0.5f;
        float s = (v - 0.5f) >= 0.f ? 1.f : 0.f;
        q[t*TSTR + i] = s;
        c += (unsigned)s;
        v *= (1.f - s);
    }
    #pragma unroll
    for (int off = 32; off >= 1; off >>= 1) c += __shfl_down(c, off, 64);
    __shared__ unsigned wsum[4];
    if ((threadIdx.x & 63) == 0) wsum[threadIdx.x >> 6] = c;
    __syncthreads();
    if (threadIdx.x == 0)
        partials[blockIdx.x] = wsum[0] + wsum[1] + wsum[2] + wsum[3];
}

// ---------------- reduce NPART partials -> cnt ----------------
__global__ __launch_bounds__(256) void k_cnt_reduce(const unsigned* __restrict__ partials,
                                                    unsigned* __restrict__ cnt)
{
    unsigned c = 0;
    for (int i = threadIdx.x; i < NPART; i += 256) c += partials[i];
    #pragma unroll
    for (int off = 32; off >= 1; off >>= 1) c += __shfl_down(c, off, 64);
    __shared__ unsigned wsum[4];
    if ((threadIdx.x & 63) == 0) wsum[threadIdx.x >> 6] = c;
    __syncthreads();
    if (threadIdx.x == 0)
        cnt[0] = wsum[0] + wsum[1] + wsum[2] + wsum[3];
}

// ---------------- dst transform + bn_last for k_t / v_t ----------------
__global__ __launch_bounds__(256) void k_dst(
    const float* __restrict__ dw, const float* __restrict__ dbn,
    const float* __restrict__ kin, const float* __restrict__ vin,
    float* __restrict__ kt, float* __restrict__ vt)
{
    int tb  = blockIdx.z;
    int h   = blockIdx.y & 7;
    int isv = blockIdx.y >> 3;
    int n0  = blockIdx.x*32;
    const float* src = (isv ? vin : kin) + (long)tb*PLANE + (h*HDD)*NS;
    float* dst       = (isv ? vt  : kt)  + ((long)(tb*NHD + h)*NS)*HDD;
    __shared__ float Xs[48][33];
    __shared__ float Wsh[48][49];
    int tid = threadIdx.x;
    for (int idx = tid; idx < 48*32; idx += 256) {
        int d = idx >> 5, n = idx & 31;
        Xs[d][n] = src[d*NS + n0 + n];
    }
    for (int idx = tid; idx < 48*48; idx += 256) {
        int e = idx / 48, d = idx % 48;
        Wsh[e][d] = dw[idx];
    }
    __syncthreads();
    #pragma unroll
    for (int r = 0; r < 6; r++) {
        int o = tid + r*256;
        int n = o / 48, e = o % 48;
        float acc = 0.f;
        #pragma unroll
        for (int d = 0; d < 48; d++) acc += Wsh[e][d]*Xs[d][n];
        float g = dbn[e], be = dbn[48+e], mu = dbn[96+e], va = dbn[144+e];
        float val = g / sqrtf(va + 1e-5f) * (acc - mu) + be;
        dst[(long)(n0+n)*HDD + e] = val;
    }
}

// ---------------- attention QK^T * c1 -> fused LIF(0.5) -> u8 map ----------------
__global__ __launch_bounds__(256) void k_attn(
    const float* __restrict__ q, const float* __restrict__ kt,
    const unsigned* __restrict__ cnt, unsigned char* __restrict__ amap)
{
    int bh = blockIdx.z;            // b*8+h
    int b = bh >> 3, h = bh & 7;
    int n0 = blockIdx.y*32, m0 = blockIdx.x*32;
    float mean = (float)(*cnt) / 6291456.0f;
    float c1 = fminf(1.0f / sqrtf(mean*48.0f + 1e-6f), 10.0f);

    __shared__ float Qs[48][33];
    __shared__ float Ks[32][49];
    int tid = threadIdx.x;
    int n   = tid >> 3;          // 0..31
    int m0l = (tid & 7)*4;       // 0..28
    float vmem[4] = {0.f,0.f,0.f,0.f};

    for (int t = 0; t < TT; t++) {
        int tb = t*BB + b;
        const float* qsrc = q  + (long)tb*PLANE + (h*HDD)*NS;
        const float* ksrc = kt + ((long)(tb*NHD + h)*NS)*HDD;
        __syncthreads();
        for (int idx = tid; idx < 48*32; idx += 256) {
            int d = idx >> 5, nn = idx & 31;
            Qs[d][nn] = qsrc[d*NS + n0 + nn];
        }
        for (int idx = tid; idx < 32*48; idx += 256) {
            int m = idx / 48, e = idx % 48;
            Ks[m][e] = ksrc[(long)(m0+m)*HDD + e];
        }
        __syncthreads();
        uchar4 sv;
        unsigned char* svp = (unsigned char*)&sv;
        #pragma unroll
        for (int r = 0; r < 4; r++) {
            int m = m0l + r;
            float acc = 0.f;
            #pragma unroll
            for (int d = 0; d < 48; d++) acc += Qs[d][n]*Ks[m][d];
            float a = acc*c1;
            float v = vmem[r];
            v += (a - v)*0.5f;
            float s = (v - 0.5f) >= 0.f ? 1.f : 0.f;
            svp[r] = (unsigned char)s;
            vmem[r] = v*(1.f - s);
        }
        *(uchar4*)&amap[((long)(tb*NHD + h)*NS + n0 + n)*NS + m0 + m0l] = sv;
    }
}

// ---------------- out = attn_map @ v_t, reorder + identity ----------------
__global__ __launch_bounds__(256) void k_outmm(
    const unsigned char* __restrict__ amap, const float* __restrict__ vt,
    const float* __restrict__ x, float* __restrict__ oid)
{
    int tb = blockIdx.z;
    int h  = blockIdx.y;
    int n0 = blockIdx.x*64;
    __shared__ float As[64][65];
    __shared__ float Vs[64][49];
    int tid = threadIdx.x, ty = tid >> 4, tx = tid & 15;  // ty->3 e, tx->4 n
    float acc[4][3] = {};
    const unsigned char* abase = amap + ((long)(tb*NHD + h)*NS + n0)*NS;
    const float* vbase = vt + ((long)(tb*NHD + h)*NS)*HDD;

    for (int m0 = 0; m0 < NS; m0 += 64) {
        for (int idx = tid; idx < 1024; idx += 256) {
            int n = idx >> 4, mq = (idx & 15)*4;
            uchar4 u = *(const uchar4*)&abase[(long)n*NS + m0 + mq];
            As[n][mq+0]=(float)u.x; As[n][mq+1]=(float)u.y; As[n][mq+2]=(float)u.z; As[n][mq+3]=(float)u.w;
        }
        for (int idx = tid; idx < 64*48; idx += 256) {
            int m = idx / 48, e = idx % 48;
            Vs[m][e] = vbase[(long)(m0+m)*HDD + e];
        }
        __syncthreads();
        #pragma unroll
        for (int m = 0; m < 64; m++) {
            float a0=As[tx*4+0][m], a1=As[tx*4+1][m], a2=As[tx*4+2][m], a3=As[tx*4+3][m];
            float v0=Vs[m][ty*3+0], v1=Vs[m][ty*3+1], v2=Vs[m][ty*3+2];
            acc[0][0]+=a0*v0; acc[0][1]+=a0*v1; acc[0][2]+=a0*v2;
            acc[1][0]+=a1*v0; acc[1][1]+=a1*v1; acc[1][2]+=a1*v2;
            acc[2][0]+=a2*v0; acc[2][1]+=a2*v1; acc[2][2]+=a2*v2;
            acc[3][0]+=a3*v0; acc[3][1]+=a3*v1; acc[3][2]+=a3*v2;
        }
        __syncthreads();
    }
    #pragma unroll
    for (int j = 0; j < 3; j++) {
        int e = ty*3 + j;
        long base = (long)tb*PLANE + (h*HDD + e)*NS + n0 + tx*4;
        float4 o4;
        o4.x = acc[0][j] + x[base+0];
        o4.y = acc[1][j] + x[base+1];
        o4.z = acc[2][j] + x[base+2];
        o4.w = acc[3][j] + x[base+3];
        *(float4*)&oid[base] = o4;
    }
}

// ---------------- proj GEMM + bias + BN ----------------
__global__ __launch_bounds__(256) void k_gemm_proj(
    const float* __restrict__ W, const float* __restrict__ bias, const float* __restrict__ bn,
    const float* __restrict__ Xfull, float* __restrict__ Yfull)
{
    int tb = blockIdx.z;
    const float* X = Xfull + (long)tb*PLANE;
    float* Y = Yfull + (long)tb*PLANE;
    int d0 = blockIdx.y*64, n0 = blockIdx.x*64;

    __shared__ float As[16][68];
    __shared__ float Bs[16][68];
    int tid = threadIdx.x;
    int ty = tid >> 4, tx = tid & 15;
    float acc[4][4] = {};

    for (int k0 = 0; k0 < CC; k0 += 16) {
        {
            int d = tid >> 2, kq = (tid & 3)*4;
            float4 a4 = *(const float4*)&W[(long)(d0+d)*CC + k0 + kq];
            As[kq+0][d]=a4.x; As[kq+1][d]=a4.y; As[kq+2][d]=a4.z; As[kq+3][d]=a4.w;
        }
        {
            int k = tid >> 4, nq = (tid & 15)*4;
            *(float4*)&Bs[k][nq] = *(const float4*)&X[(long)(k0+k)*NS + n0 + nq];
        }
        __syncthreads();
        #pragma unroll
        for (int kk = 0; kk < 16; kk++) {
            float a0=As[kk][ty*4+0], a1=As[kk][ty*4+1], a2=As[kk][ty*4+2], a3=As[kk][ty*4+3];
            float b0=Bs[kk][tx*4+0], b1=Bs[kk][tx*4+1], b2=Bs[kk][tx*4+2], b3=Bs[kk][tx*4+3];
            acc[0][0]+=a0*b0; acc[0][1]+=a0*b1; acc[0][2]+=a0*b2; acc[0][3]+=a0*b3;
            acc[1][0]+=a1*b0; acc[1][1]+=a1*b1; acc[1][2]+=a1*b2; acc[1][3]+=a1*b3;
            acc[2][0]+=a2*b0; acc[2][1]+=a2*b1; acc[2][2]+=a2*b2; acc[2][3]+=a2*b3;
            acc[3][0]+=a3*b0; acc[3][1]+=a3*b1; acc[3][2]+=a3*b2; acc[3][3]+=a3*b3;
        }
        __syncthreads();
    }
    #pragma unroll
    for (int i = 0; i < 4; i++) {
        int d = d0 + ty*4 + i;
        float g = bn[d], be = bn[CC+d], mu = bn[2*CC+d], va = bn[3*CC+d];
        float inv = g / sqrtf(va + 1e-5f);
        float bv = bias[d];
        float4 o4;
        o4.x = inv*((acc[i][0]+bv) - mu) + be;
        o4.y = inv*((acc[i][1]+bv) - mu) + be;
        o4.z = inv*((acc[i][2]+bv) - mu) + be;
        o4.w = inv*((acc[i][3]+bv) - mu) + be;
        *(float4*)&Y[(long)d*NS + n0 + tx*4] = o4;
    }
}

// ---------------- final LIF (vth=1.0) -> d_out ----------------
__global__ __launch_bounds__(256) void k_final_lif(const float* __restrict__ pre,
                                                   float* __restrict__ out)
{
    int i = blockIdx.x*256 + threadIdx.x;
    float v = 0.f;
    #pragma unroll
    for (int t = 0; t < TT; t++) {
        float xt = pre[t*TSTR + i];
        v += (xt - v)*0.5f;
        float s = (v - 1.0f) >= 0.f ? 1.f : 0.f;
        out[t*TSTR + i] = s;
        v *= (1.f - s);
    }
}

extern "C" void kernel_launch(void* const* d_in, const int* in_sizes, int n_in,
                              void* d_out, int out_size, void* d_ws, size_t ws_size,
                              hipStream_t stream) {
    const float* x   = (const float*)d_in[0];
    const float* wq  = (const float*)d_in[1];
    const float* wk  = (const float*)d_in[2];
    const float* wv  = (const float*)d_in[3];
    const float* kbn = (const float*)d_in[4];
    const float* vbn = (const float*)d_in[5];
    const float* dw  = (const float*)d_in[6];
    const float* dbn = (const float*)d_in[7];
    const float* pw  = (const float*)d_in[8];
    const float* pb  = (const float*)d_in[9];
    const float* pbn = (const float*)d_in[10];
    const float* tw  = (const float*)d_in[11];
    const float* tbi = (const float*)d_in[12];

    float* out  = (float*)d_out;
    float* vout = out + TOT;

    float* ws   = (float*)d_ws;
    float* xs   = ws + OFF_XS;     // xs spikes; later reused as oid
    float* qb   = ws + OFF_Q;
    float* kb   = ws + OFF_K;      // later reused as proj_pre
    float* vb   = ws + OFF_V;
    float* outs = ws + OFF_OUTS;
    float* kt   = ws + OFF_KT;
    float* vt   = ws + OFF_VT;
    unsigned* cnt = (unsigned*)(ws + OFF_CNT);
    unsigned* partials = (unsigned*)(ws + OFF_KT);  // transient; dead before k_dst
    unsigned char* amap = (unsigned char*)d_ws + OFF_AMAP_BYTES;

    // 1. shortcut LIF
    k_lif_x<<<dim3(TSTR/256), 256, 0, stream>>>(x, xs);
    // 2. q/k/v 1x1 convs (+BN for k,v)
    k_gemm_qkv<<<dim3(4, 6, 192), 256, 0, stream>>>(wq, wk, wv, kbn, vbn, xs, qb, kb, vb);
    // 3. LIF on q/k/v; q[0]->outs[0]; v spikes -> d_out (heads layout)
    k_lif_qkv<<<dim3(TSTR/256, 3), 256, 0, stream>>>(qb, kb, vb, outs, vout);
    // 4. TIM recurrent conv chain
    for (int i = 1; i < TT; i++) {
        k_tim_conv<<<dim3(8, 6, 16), 256, 0, stream>>>(
            tw, tbi, outs + (long)(i-1)*TSTR, qb + (long)i*TSTR, outs + (long)i*TSTR);
    }
    // 5. TIM output LIF (vth 0.5) -> q spikes (overwrites qb) + per-block counts
    k_tim_lif<<<dim3(NPART), 256, 0, stream>>>(outs, qb, partials);
    // 5b. reduce partial counts -> cnt (single block, before k_dst reuses region)
    k_cnt_reduce<<<dim3(1), 256, 0, stream>>>(partials, cnt);
    // 6. dst transform + bn_last
    k_dst<<<dim3(8, 16, 64), 256, 0, stream>>>(dw, dbn, kb, vb, kt, vt);
    // 7. attention + fused LIF -> binary map
    k_attn<<<dim3(8, 8, 128), 256, 0, stream>>>(qb, kt, cnt, amap);
    // 8. attn_map @ v_t, reorder, + identity  (oid into xs buffer)
    k_outmm<<<dim3(4, 8, 64), 256, 0, stream>>>(amap, vt, x, xs);
    // 9. proj GEMM + bias + BN (proj_pre into kb buffer)
    k_gemm_proj<<<dim3(4, 6, 64), 256, 0, stream>>>(pw, pb, pbn, xs, kb);
    // 10. final LIF -> out
    k_final_lif<<<dim3(TSTR/256), 256, 0, stream>>>(kb, out);
}

// Round 3
// 1088.871 us; speedup vs baseline: 1.3613x; 1.1223x over previous
//
#include <hip/hip_runtime.h>
#include <math.h>

#define TT 4
#define BB 16
#define CC 384
#define NS 256
#define NHD 8
#define HDD 48
#define PLANE 98304      /* CC*NS */
#define TSTR  1572864    /* BB*PLANE */
#define TOT   6291456    /* TT*TSTR */

// workspace float offsets (total (8*TOT+16)*4 = 201.3 MB)
#define OFF_XS   0L            /* xs spikes / later: out+identity (oid) */
#define OFF_Q    (1L*TOT)      /* q_pre -> q spikes (fp32, tim input); qbf u16 overlays after tim */
#define OFF_K    (2L*TOT)      /* k_pre -> k spikes -> proj_pre */
#define OFF_V    (3L*TOT)      /* v_pre -> v spikes */
#define OFF_OUTS (4L*TOT)      /* TIM outs [T,B,C,N]; amap u8 overlays after k_tim_lif */
#define OFF_KTS  (11L*TOT/2)   /* kt hi/mid/lo u16 planes (3*TOT u16); partials transient */
#define OFF_VT   (7L*TOT)      /* vt fp32 */
#define OFF_CNT  (8L*TOT)      /* u32 spike counter */

#define NPART 6144             /* TSTR/256 blocks of k_tim_lif */

typedef __attribute__((ext_vector_type(8))) short short8;
typedef __attribute__((ext_vector_type(4))) float f32x4;

__device__ __forceinline__ ushort f2bf(float x) {   // RTNE fp32->bf16
    union { float f; unsigned u; } c; c.f = x;
    unsigned r = c.u + 0x7FFFu + ((c.u >> 16) & 1u);
    return (ushort)(r >> 16);
}
__device__ __forceinline__ float bf2f(ushort h) {
    union { unsigned u; float f; } c; c.u = ((unsigned)h) << 16;
    return c.f;
}

// ---------------- LIF over input x -> xs (vth=1.0) ----------------
__global__ __launch_bounds__(256) void k_lif_x(const float* __restrict__ x,
                                               float* __restrict__ xs)
{
    int i = blockIdx.x*256 + threadIdx.x;   // [0, TSTR)
    float v = 0.f;
    #pragma unroll
    for (int t = 0; t < TT; t++) {
        float xt = x[t*TSTR + i];
        v += (xt - v)*0.5f;
        float s = (v - 1.0f) >= 0.f ? 1.f : 0.f;
        xs[t*TSTR + i] = s;
        v *= (1.f - s);
    }
}

// ---------------- QKV GEMM: Y[t,b] = W @ xs[t,b], BN on k/v ----------------
__global__ __launch_bounds__(256) void k_gemm_qkv(
    const float* __restrict__ wq, const float* __restrict__ wk, const float* __restrict__ wv,
    const float* __restrict__ kbn, const float* __restrict__ vbn,
    const float* __restrict__ xs,
    float* __restrict__ qo, float* __restrict__ ko, float* __restrict__ vo)
{
    int which = blockIdx.z >> 6;      // 0=q,1=k,2=v
    int tb    = blockIdx.z & 63;
    const float* W  = (which==0) ? wq : (which==1 ? wk : wv);
    const float* bn = (which==0) ? nullptr : (which==1 ? kbn : vbn);
    float* Y        = (which==0) ? qo : (which==1 ? ko : vo);
    const float* X  = xs + (long)tb*PLANE;
    Y += (long)tb*PLANE;
    int d0 = blockIdx.y*64, n0 = blockIdx.x*64;

    __shared__ float As[16][68];
    __shared__ float Bs[16][68];
    int tid = threadIdx.x;
    int ty = tid >> 4, tx = tid & 15;
    float acc[4][4] = {};

    for (int k0 = 0; k0 < CC; k0 += 16) {
        {   // A: W tile 64x16 -> As[k][d]
            int d  = tid >> 2;
            int kq = (tid & 3)*4;
            float4 a4 = *(const float4*)&W[(long)(d0+d)*CC + k0 + kq];
            As[kq+0][d]=a4.x; As[kq+1][d]=a4.y; As[kq+2][d]=a4.z; As[kq+3][d]=a4.w;
        }
        {   // B: X tile 16x64
            int k  = tid >> 4;
            int nq = (tid & 15)*4;
            *(float4*)&Bs[k][nq] = *(const float4*)&X[(long)(k0+k)*NS + n0 + nq];
        }
        __syncthreads();
        #pragma unroll
        for (int kk = 0; kk < 16; kk++) {
            float a0=As[kk][ty*4+0], a1=As[kk][ty*4+1], a2=As[kk][ty*4+2], a3=As[kk][ty*4+3];
            float b0=Bs[kk][tx*4+0], b1=Bs[kk][tx*4+1], b2=Bs[kk][tx*4+2], b3=Bs[kk][tx*4+3];
            acc[0][0]+=a0*b0; acc[0][1]+=a0*b1; acc[0][2]+=a0*b2; acc[0][3]+=a0*b3;
            acc[1][0]+=a1*b0; acc[1][1]+=a1*b1; acc[1][2]+=a1*b2; acc[1][3]+=a1*b3;
            acc[2][0]+=a2*b0; acc[2][1]+=a2*b1; acc[2][2]+=a2*b2; acc[2][3]+=a2*b3;
            acc[3][0]+=a3*b0; acc[3][1]+=a3*b1; acc[3][2]+=a3*b2; acc[3][3]+=a3*b3;
        }
        __syncthreads();
    }
    #pragma unroll
    for (int i = 0; i < 4; i++) {
        int d = d0 + ty*4 + i;
        float inv = 1.f, mu = 0.f, be = 0.f;
        bool hasbn = (bn != nullptr);
        if (hasbn) {
            float g = bn[d]; be = bn[CC+d]; mu = bn[2*CC+d]; float va = bn[3*CC+d];
            inv = g / sqrtf(va + 1e-5f);
        }
        float4 o4;
        float v0 = acc[i][0], v1 = acc[i][1], v2 = acc[i][2], v3 = acc[i][3];
        if (hasbn) { v0 = inv*(v0-mu)+be; v1 = inv*(v1-mu)+be; v2 = inv*(v2-mu)+be; v3 = inv*(v3-mu)+be; }
        o4.x=v0; o4.y=v1; o4.z=v2; o4.w=v3;
        *(float4*)&Y[(long)d*NS + n0 + tx*4] = o4;
    }
}

// ---------------- LIF for q(0.05)/k(1.0)/v(1.0), in-place ----------------
__global__ __launch_bounds__(256) void k_lif_qkv(
    float* __restrict__ qb, float* __restrict__ kb, float* __restrict__ vb,
    float* __restrict__ outs0, float* __restrict__ vout)
{
    int which = blockIdx.y;
    int i = blockIdx.x*256 + threadIdx.x;
    float* buf = (which==0) ? qb : (which==1 ? kb : vb);
    float vth  = (which==0) ? 0.05f : 1.0f;
    int b=0, n=0, h=0, dd=0;
    if (which == 2) {
        b = i / PLANE; int r = i % PLANE;
        int c = r >> 8; n = r & 255;
        h = c / HDD; dd = c % HDD;
    }
    float v = 0.f;
    #pragma unroll
    for (int t = 0; t < TT; t++) {
        float xt = buf[t*TSTR + i];
        v += (xt - v)*0.5f;
        float s = (v - vth) >= 0.f ? 1.f : 0.f;
        buf[t*TSTR + i] = s;
        if (which == 0 && t == 0) outs0[i] = s;
        if (which == 2)
            vout[(((long)(t*BB+b)*NHD + h)*NS + n)*HDD + dd] = s;
        v *= (1.f - s);
    }
}

// ---------------- TIM conv1d step i: cur = s*0.6 + q_i*0.4 ----------------
__global__ __launch_bounds__(256) void k_tim_conv(
    const float* __restrict__ w, const float* __restrict__ bias,
    const float* __restrict__ prev,   // outs[i-1], [B,C,N]
    const float* __restrict__ qi,     // q spikes at t=i, [B,C,N]
    float* __restrict__ cur)          // outs[i]
{
    int b = blockIdx.z, d0 = blockIdx.y*64, n0 = blockIdx.x*32;
    __shared__ float Ws[64][85];   // [d][ci*5+k]
    __shared__ float Xs[16][40];   // [ci][n halo 36]
    int tid = threadIdx.x, ty = tid >> 4, tx = tid & 15;  // 4 d x 2 n per thread
    float acc[4][2] = {};

    for (int c0 = 0; c0 < CC; c0 += 16) {
        {   // W chunk: 64 x 80
            int d = tid >> 2, p = (tid & 3)*20;
            const float* src = &w[(long)(d0+d)*CC*5 + c0*5 + p];
            #pragma unroll
            for (int q = 0; q < 5; q++) {
                float4 t4 = *(const float4*)&src[q*4];
                Ws[d][p+q*4+0]=t4.x; Ws[d][p+q*4+1]=t4.y; Ws[d][p+q*4+2]=t4.z; Ws[d][p+q*4+3]=t4.w;
            }
        }
        for (int idx = tid; idx < 16*36; idx += 256) {
            int ci = idx / 36, col = idx % 36;
            int n = n0 + col - 2;
            Xs[ci][col] = (n >= 0 && n < NS) ? prev[(long)b*PLANE + (c0+ci)*NS + n] : 0.f;
        }
        __syncthreads();
        #pragma unroll
        for (int ci = 0; ci < 16; ci++) {
            #pragma unroll
            for (int k = 0; k < 5; k++) {
                float w0=Ws[ty*4+0][ci*5+k], w1=Ws[ty*4+1][ci*5+k];
                float w2=Ws[ty*4+2][ci*5+k], w3=Ws[ty*4+3][ci*5+k];
                float x0=Xs[ci][tx*2+0+k],   x1=Xs[ci][tx*2+1+k];
                acc[0][0]+=w0*x0; acc[0][1]+=w0*x1;
                acc[1][0]+=w1*x0; acc[1][1]+=w1*x1;
                acc[2][0]+=w2*x0; acc[2][1]+=w2*x1;
                acc[3][0]+=w3*x0; acc[3][1]+=w3*x1;
            }
        }
        __syncthreads();
    }
    #pragma unroll
    for (int i = 0; i < 4; i++) {
        int d = d0 + ty*4 + i;
        float bv = bias[d];
        #pragma unroll
        for (int j = 0; j < 2; j++) {
            int n = n0 + tx*2 + j;
            float c = acc[i][j] + bv;
            float s = (c*0.5f - 0.3f) >= 0.f ? 1.f : 0.f;
            float qv = qi[(long)b*PLANE + d*NS + n];
            cur[(long)b*PLANE + d*NS + n] = s*0.6f + qv*0.4f;
        }
    }
}

// ---------------- TIM output LIF (vth=0.5) -> bf16 spikes + per-block count ----------------
__global__ __launch_bounds__(256) void k_tim_lif(const float* __restrict__ outs,
                                                 ushort* __restrict__ qbf,
                                                 unsigned* __restrict__ partials)
{
    int i = blockIdx.x*256 + threadIdx.x;
    float v = 0.f; unsigned c = 0;
    #pragma unroll
    for (int t = 0; t < TT; t++) {
        float xt = outs[t*TSTR + i];
        v += (xt - v)*0.5f;
        float s = (v - 0.5f) >= 0.f ? 1.f : 0.f;
        qbf[t*TSTR + i] = (s != 0.f) ? (ushort)0x3F80 : (ushort)0;  // bf16 1.0 / 0.0
        c += (unsigned)s;
        v *= (1.f - s);
    }
    #pragma unroll
    for (int off = 32; off >= 1; off >>= 1) c += __shfl_down(c, off, 64);
    __shared__ unsigned wsum[4];
    if ((threadIdx.x & 63) == 0) wsum[threadIdx.x >> 6] = c;
    __syncthreads();
    if (threadIdx.x == 0)
        partials[blockIdx.x] = wsum[0] + wsum[1] + wsum[2] + wsum[3];
}

// ---------------- reduce NPART partials -> cnt ----------------
__global__ __launch_bounds__(256) void k_cnt_reduce(const unsigned* __restrict__ partials,
                                                    unsigned* __restrict__ cnt)
{
    unsigned c = 0;
    for (int i = threadIdx.x; i < NPART; i += 256) c += partials[i];
    #pragma unroll
    for (int off = 32; off >= 1; off >>= 1) c += __shfl_down(c, off, 64);
    __shared__ unsigned wsum[4];
    if ((threadIdx.x & 63) == 0) wsum[threadIdx.x >> 6] = c;
    __syncthreads();
    if (threadIdx.x == 0)
        cnt[0] = wsum[0] + wsum[1] + wsum[2] + wsum[3];
}

// ---------------- dst transform + bn_last; kt -> bf16 hi/mid/lo, vt fp32 ----------------
__global__ __launch_bounds__(256) void k_dst(
    const float* __restrict__ dw, const float* __restrict__ dbn,
    const float* __restrict__ kin, const float* __restrict__ vin,
    ushort* __restrict__ kth, ushort* __restrict__ ktm, ushort* __restrict__ ktl,
    float* __restrict__ vt)
{
    int tb  = blockIdx.z;
    int h   = blockIdx.y & 7;
    int isv = blockIdx.y >> 3;
    int n0  = blockIdx.x*32;
    const float* src = (isv ? vin : kin) + (long)tb*PLANE + (h*HDD)*NS;
    long dstbase = ((long)(tb*NHD + h)*NS)*HDD;
    __shared__ float Xs[48][33];
    __shared__ float Wsh[48][49];
    int tid = threadIdx.x;
    for (int idx = tid; idx < 48*32; idx += 256) {
        int d = idx >> 5, n = idx & 31;
        Xs[d][n] = src[d*NS + n0 + n];
    }
    for (int idx = tid; idx < 48*48; idx += 256) {
        int e = idx / 48, d = idx % 48;
        Wsh[e][d] = dw[idx];
    }
    __syncthreads();
    #pragma unroll
    for (int r = 0; r < 6; r++) {
        int o = tid + r*256;
        int n = o / 48, e = o % 48;
        float acc = 0.f;
        #pragma unroll
        for (int d = 0; d < 48; d++) acc += Wsh[e][d]*Xs[d][n];
        float g = dbn[e], be = dbn[48+e], mu = dbn[96+e], va = dbn[144+e];
        float val = g / sqrtf(va + 1e-5f) * (acc - mu) + be;
        long gi = dstbase + (long)(n0+n)*HDD + e;
        if (isv) {
            vt[gi] = val;
        } else {
            ushort hi = f2bf(val);
            float r1 = val - bf2f(hi);
            ushort md = f2bf(r1);
            float r2 = r1 - bf2f(md);
            ushort lo = f2bf(r2);
            kth[gi] = hi; ktm[gi] = md; ktl[gi] = lo;
        }
    }
}

// ---------------- MFMA attention: QK^T * c1 -> fused LIF(0.5) -> u8 map ----------------
// q binary bf16 (exact); kt split hi/mid/lo bf16 (reconstructs fp32 to ~2^-24).
// 64x64 output tile/block; LIF membrane held in regs across t.
__global__ __launch_bounds__(256) void k_attn_mfma(
    const ushort* __restrict__ qbf,
    const ushort* __restrict__ kth, const ushort* __restrict__ ktm, const ushort* __restrict__ ktl,
    const unsigned* __restrict__ cnt, unsigned char* __restrict__ amap)
{
    int bh = blockIdx.z;            // b*8+h
    int b = bh >> 3, h = bh & 7;
    int nbase = blockIdx.y*64, mbase = blockIdx.x*64;

    __shared__ ushort Qs[64][72];   // [n][d], d padded to 64 with zeros
    __shared__ ushort Kh[64][72];   // [m][e]
    __shared__ ushort Km[64][72];
    __shared__ ushort Kl[64][72];

    int tid  = threadIdx.x;
    int lane = tid & 63, w = tid >> 6;
    int q4 = lane >> 4, l16 = lane & 15;

    float mean = (float)(*cnt) / 6291456.0f;
    float c1 = fminf(1.0f / sqrtf(mean*48.0f + 1e-6f), 10.0f);

    // zero-init LDS once (pad cols 48..63 persist zero across t)
    {
        unsigned* z0 = (unsigned*)&Qs[0][0];
        unsigned* z1 = (unsigned*)&Kh[0][0];
        unsigned* z2 = (unsigned*)&Km[0][0];
        unsigned* z3 = (unsigned*)&Kl[0][0];
        for (int i2 = tid; i2 < 64*72/2; i2 += 256) {
            z0[i2] = 0; z1[i2] = 0; z2[i2] = 0; z3[i2] = 0;
        }
    }

    float vmem[4][4];
    #pragma unroll
    for (int a = 0; a < 4; a++)
        #pragma unroll
        for (int r = 0; r < 4; r++) vmem[a][r] = 0.f;

    for (int t = 0; t < TT; t++) {
        int tb = t*BB + b;
        __syncthreads();   // protect LDS from previous iteration's readers (and init)
        // stage Q tile transposed: qbf[tb][h*48+d][nbase+n] -> Qs[n][d]
        const ushort* qsrc = qbf + (long)tb*PLANE + (long)(h*HDD)*NS + nbase;
        for (int idx = tid; idx < 1536; idx += 256) {     // 48 d x 32 n-pairs
            int d = idx >> 5, np = (idx & 31) << 1;
            unsigned v = *(const unsigned*)(qsrc + (long)d*NS + np);
            Qs[np  ][d] = (ushort)(v & 0xFFFFu);
            Qs[np+1][d] = (ushort)(v >> 16);
        }
        // stage K tiles (rows contiguous in global): kt*[ (tb*8+h)*256 + mbase + m ][e]
        long kb0 = ((long)(tb*NHD + h)*NS + mbase)*HDD;
        const ushort* kbh = kth + kb0;
        const ushort* kbm = ktm + kb0;
        const ushort* kbl = ktl + kb0;
        for (int idx = tid; idx < 1536; idx += 256) {     // 3072 u16 as uints
            int e2 = idx << 1;
            int m = e2 / HDD, er = e2 % HDD;
            *(unsigned*)&Kh[m][er] = *(const unsigned*)(kbh + e2);
            *(unsigned*)&Km[m][er] = *(const unsigned*)(kbm + e2);
            *(unsigned*)&Kl[m][er] = *(const unsigned*)(kbl + e2);
        }
        __syncthreads();

        // compute: wave w owns 16-row n-strip [w*16, w*16+16), all 64 m
        int nrow = w*16 + l16;
        f32x4 acc[4];
        #pragma unroll
        for (int mt = 0; mt < 4; mt++) acc[mt] = (f32x4){0.f, 0.f, 0.f, 0.f};

        #pragma unroll
        for (int ks = 0; ks < 2; ks++) {
            short8 a = *(short8*)&Qs[nrow][ks*32 + q4*8];
            #pragma unroll
            for (int mt = 0; mt < 4; mt++) {
                int mrow = mt*16 + l16;
                short8 b_h = *(short8*)&Kh[mrow][ks*32 + q4*8];
                short8 b_m = *(short8*)&Km[mrow][ks*32 + q4*8];
                short8 b_l = *(short8*)&Kl[mrow][ks*32 + q4*8];
                acc[mt] = __builtin_amdgcn_mfma_f32_16x16x32_bf16(a, b_h, acc[mt], 0, 0, 0);
                acc[mt] = __builtin_amdgcn_mfma_f32_16x16x32_bf16(a, b_m, acc[mt], 0, 0, 0);
                acc[mt] = __builtin_amdgcn_mfma_f32_16x16x32_bf16(a, b_l, acc[mt], 0, 0, 0);
            }
        }

        // epilogue: LIF update + u8 spike store. D layout: col=lane&15, row=quad*4+reg.
        long abase0 = ((long)(tb*NHD + h)*NS)*NS;
        #pragma unroll
        for (int mt = 0; mt < 4; mt++) {
            int m = mbase + mt*16 + l16;
            #pragma unroll
            for (int r = 0; r < 4; r++) {
                int n = nbase + w*16 + q4*4 + r;
                float a = acc[mt][r]*c1;
                float v = vmem[mt][r];
                v += (a - v)*0.5f;
                float s = (v - 0.5f) >= 0.f ? 1.f : 0.f;
                amap[abase0 + (long)n*NS + m] = (unsigned char)s;
                vmem[mt][r] = v*(1.f - s);
            }
        }
    }
}

// ---------------- out = attn_map @ v_t, reorder + identity ----------------
__global__ __launch_bounds__(256) void k_outmm(
    const unsigned char* __restrict__ amap, const float* __restrict__ vt,
    const float* __restrict__ x, float* __restrict__ oid)
{
    int tb = blockIdx.z;
    int h  = blockIdx.y;
    int n0 = blockIdx.x*64;
    __shared__ float As[64][65];
    __shared__ float Vs[64][49];
    int tid = threadIdx.x, ty = tid >> 4, tx = tid & 15;  // ty->3 e, tx->4 n
    float acc[4][3] = {};
    const unsigned char* abase = amap + ((long)(tb*NHD + h)*NS + n0)*NS;
    const float* vbase = vt + ((long)(tb*NHD + h)*NS)*HDD;

    for (int m0 = 0; m0 < NS; m0 += 64) {
        for (int idx = tid; idx < 1024; idx += 256) {
            int n = idx >> 4, mq = (idx & 15)*4;
            uchar4 u = *(const uchar4*)&abase[(long)n*NS + m0 + mq];
            As[n][mq+0]=(float)u.x; As[n][mq+1]=(float)u.y; As[n][mq+2]=(float)u.z; As[n][mq+3]=(float)u.w;
        }
        for (int idx = tid; idx < 64*48; idx += 256) {
            int m = idx / 48, e = idx % 48;
            Vs[m][e] = vbase[(long)(m0+m)*HDD + e];
        }
        __syncthreads();
        #pragma unroll
        for (int m = 0; m < 64; m++) {
            float a0=As[tx*4+0][m], a1=As[tx*4+1][m], a2=As[tx*4+2][m], a3=As[tx*4+3][m];
            float v0=Vs[m][ty*3+0], v1=Vs[m][ty*3+1], v2=Vs[m][ty*3+2];
            acc[0][0]+=a0*v0; acc[0][1]+=a0*v1; acc[0][2]+=a0*v2;
            acc[1][0]+=a1*v0; acc[1][1]+=a1*v1; acc[1][2]+=a1*v2;
            acc[2][0]+=a2*v0; acc[2][1]+=a2*v1; acc[2][2]+=a2*v2;
            acc[3][0]+=a3*v0; acc[3][1]+=a3*v1; acc[3][2]+=a3*v2;
        }
        __syncthreads();
    }
    #pragma unroll
    for (int j = 0; j < 3; j++) {
        int e = ty*3 + j;
        long base = (long)tb*PLANE + (h*HDD + e)*NS + n0 + tx*4;
        float4 o4;
        o4.x = acc[0][j] + x[base+0];
        o4.y = acc[1][j] + x[base+1];
        o4.z = acc[2][j] + x[base+2];
        o4.w = acc[3][j] + x[base+3];
        *(float4*)&oid[base] = o4;
    }
}

// ---------------- proj GEMM + bias + BN ----------------
__global__ __launch_bounds__(256) void k_gemm_proj(
    const float* __restrict__ W, const float* __restrict__ bias, const float* __restrict__ bn,
    const float* __restrict__ Xfull, float* __restrict__ Yfull)
{
    int tb = blockIdx.z;
    const float* X = Xfull + (long)tb*PLANE;
    float* Y = Yfull + (long)tb*PLANE;
    int d0 = blockIdx.y*64, n0 = blockIdx.x*64;

    __shared__ float As[16][68];
    __shared__ float Bs[16][68];
    int tid = threadIdx.x;
    int ty = tid >> 4, tx = tid & 15;
    float acc[4][4] = {};

    for (int k0 = 0; k0 < CC; k0 += 16) {
        {
            int d = tid >> 2, kq = (tid & 3)*4;
            float4 a4 = *(const float4*)&W[(long)(d0+d)*CC + k0 + kq];
            As[kq+0][d]=a4.x; As[kq+1][d]=a4.y; As[kq+2][d]=a4.z; As[kq+3][d]=a4.w;
        }
        {
            int k = tid >> 4, nq = (tid & 15)*4;
            *(float4*)&Bs[k][nq] = *(const float4*)&X[(long)(k0+k)*NS + n0 + nq];
        }
        __syncthreads();
        #pragma unroll
        for (int kk = 0; kk < 16; kk++) {
            float a0=As[kk][ty*4+0], a1=As[kk][ty*4+1], a2=As[kk][ty*4+2], a3=As[kk][ty*4+3];
            float b0=Bs[kk][tx*4+0], b1=Bs[kk][tx*4+1], b2=Bs[kk][tx*4+2], b3=Bs[kk][tx*4+3];
            acc[0][0]+=a0*b0; acc[0][1]+=a0*b1; acc[0][2]+=a0*b2; acc[0][3]+=a0*b3;
            acc[1][0]+=a1*b0; acc[1][1]+=a1*b1; acc[1][2]+=a1*b2; acc[1][3]+=a1*b3;
            acc[2][0]+=a2*b0; acc[2][1]+=a2*b1; acc[2][2]+=a2*b2; acc[2][3]+=a2*b3;
            acc[3][0]+=a3*b0; acc[3][1]+=a3*b1; acc[3][2]+=a3*b2; acc[3][3]+=a3*b3;
        }
        __syncthreads();
    }
    #pragma unroll
    for (int i = 0; i < 4; i++) {
        int d = d0 + ty*4 + i;
        float g = bn[d], be = bn[CC+d], mu = bn[2*CC+d], va = bn[3*CC+d];
        float inv = g / sqrtf(va + 1e-5f);
        float bv = bias[d];
        float4 o4;
        o4.x = inv*((acc[i][0]+bv) - mu) + be;
        o4.y = inv*((acc[i][1]+bv) - mu) + be;
        o4.z = inv*((acc[i][2]+bv) - mu) + be;
        o4.w = inv*((acc[i][3]+bv) - mu) + be;
        *(float4*)&Y[(long)d*NS + n0 + tx*4] = o4;
    }
}

// ---------------- final LIF (vth=1.0) -> d_out ----------------
__global__ __launch_bounds__(256) void k_final_lif(const float* __restrict__ pre,
                                                   float* __restrict__ out)
{
    int i = blockIdx.x*256 + threadIdx.x;
    float v = 0.f;
    #pragma unroll
    for (int t = 0; t < TT; t++) {
        float xt = pre[t*TSTR + i];
        v += (xt - v)*0.5f;
        float s = (v - 1.0f) >= 0.f ? 1.f : 0.f;
        out[t*TSTR + i] = s;
        v *= (1.f - s);
    }
}

extern "C" void kernel_launch(void* const* d_in, const int* in_sizes, int n_in,
                              void* d_out, int out_size, void* d_ws, size_t ws_size,
                              hipStream_t stream) {
    const float* x   = (const float*)d_in[0];
    const float* wq  = (const float*)d_in[1];
    const float* wk  = (const float*)d_in[2];
    const float* wv  = (const float*)d_in[3];
    const float* kbn = (const float*)d_in[4];
    const float* vbn = (const float*)d_in[5];
    const float* dw  = (const float*)d_in[6];
    const float* dbn = (const float*)d_in[7];
    const float* pw  = (const float*)d_in[8];
    const float* pb  = (const float*)d_in[9];
    const float* pbn = (const float*)d_in[10];
    const float* tw  = (const float*)d_in[11];
    const float* tbi = (const float*)d_in[12];

    float* out  = (float*)d_out;
    float* vout = out + TOT;

    float* ws   = (float*)d_ws;
    float* xs   = ws + OFF_XS;     // xs spikes; later reused as oid
    float* qb   = ws + OFF_Q;      // q_pre -> q spikes (fp32, tim chain input)
    float* kb   = ws + OFF_K;      // later reused as proj_pre
    float* vb   = ws + OFF_V;
    float* outs = ws + OFF_OUTS;
    ushort* qbf = (ushort*)(ws + OFF_Q);      // overlays qb after tim chain done
    ushort* kth = (ushort*)(ws + OFF_KTS);
    ushort* ktm = kth + TOT;
    ushort* ktl = kth + 2L*TOT;
    float* vt   = ws + OFF_VT;
    unsigned* cnt = (unsigned*)(ws + OFF_CNT);
    unsigned* partials = (unsigned*)(ws + OFF_KTS);   // transient; dead before k_dst
    unsigned char* amap = (unsigned char*)(ws + OFF_OUTS);  // overlays outs after k_tim_lif

    // 1. shortcut LIF
    k_lif_x<<<dim3(TSTR/256), 256, 0, stream>>>(x, xs);
    // 2. q/k/v 1x1 convs (+BN for k,v)
    k_gemm_qkv<<<dim3(4, 6, 192), 256, 0, stream>>>(wq, wk, wv, kbn, vbn, xs, qb, kb, vb);
    // 3. LIF on q/k/v; q[0]->outs[0]; v spikes -> d_out (heads layout)
    k_lif_qkv<<<dim3(TSTR/256, 3), 256, 0, stream>>>(qb, kb, vb, outs, vout);
    // 4. TIM recurrent conv chain
    for (int i = 1; i < TT; i++) {
        k_tim_conv<<<dim3(8, 6, 16), 256, 0, stream>>>(
            tw, tbi, outs + (long)(i-1)*TSTR, qb + (long)i*TSTR, outs + (long)i*TSTR);
    }
    // 5. TIM output LIF -> bf16 q spikes (overlay on qb region) + per-block counts
    k_tim_lif<<<dim3(NPART), 256, 0, stream>>>(outs, qbf, partials);
    // 5b. reduce partial counts -> cnt (before k_dst reuses the region)
    k_cnt_reduce<<<dim3(1), 256, 0, stream>>>(partials, cnt);
    // 6. dst transform + bn_last; kt as bf16 hi/mid/lo, vt fp32
    k_dst<<<dim3(8, 16, 64), 256, 0, stream>>>(dw, dbn, kb, vb, kth, ktm, ktl, vt);
    // 7. MFMA attention + fused LIF -> binary map (overlays outs region)
    k_attn_mfma<<<dim3(4, 4, 128), 256, 0, stream>>>(qbf, kth, ktm, ktl, cnt, amap);
    // 8. attn_map @ v_t, reorder, + identity  (oid into xs buffer)
    k_outmm<<<dim3(4, 8, 64), 256, 0, stream>>>(amap, vt, x, xs);
    // 9. proj GEMM + bias + BN (proj_pre into kb buffer)
    k_gemm_proj<<<dim3(4, 6, 64), 256, 0, stream>>>(pw, pb, pbn, xs, kb);
    // 10. final LIF -> out
    k_final_lif<<<dim3(TSTR/256), 256, 0, stream>>>(kb, out);
}

// Round 4
// 1032.100 us; speedup vs baseline: 1.4362x; 1.0550x over previous
//
#include <hip/hip_runtime.h>
#include <math.h>

#define TT 4
#define BB 16
#define CC 384
#define NS 256
#define NHD 8
#define HDD 48
#define PLANE 98304      /* CC*NS */
#define TSTR  1572864    /* BB*PLANE */
#define TOT   6291456    /* TT*TSTR */
#define CCSQ  147456     /* CC*CC */

// workspace float offsets (total (8*TOT+16)*4 = 201.3 MB)
#define OFF_XS   0L            /* xs bf16 spikes / later: oid fp32 */
#define OFF_Q    (1L*TOT)      /* q_pre fp32 -> q spikes; qbf u16 overlays after tim */
#define OFF_K    (2L*TOT)      /* k_pre -> k spikes -> proj_pre */
#define OFF_V    (3L*TOT)      /* v_pre -> v spikes */
#define OFF_OUTS (4L*TOT)      /* TIM outs [T,B,C,N]; amap u8 overlays after k_tim_lif */
#define OFF_KTS  (11L*TOT/2)   /* wsplit (step2) -> partials (step5) -> kt hi/mid/lo (step6) */
#define OFF_VT   (7L*TOT)      /* vt fp32 */
#define OFF_CNT  (8L*TOT)      /* u32 spike counter */

#define NPART 6144             /* TSTR/256 blocks of k_tim_lif */

typedef __attribute__((ext_vector_type(8))) short short8;
typedef __attribute__((ext_vector_type(4))) float f32x4;

__device__ __forceinline__ ushort f2bf(float x) {   // RTNE fp32->bf16
    union { float f; unsigned u; } c; c.f = x;
    unsigned r = c.u + 0x7FFFu + ((c.u >> 16) & 1u);
    return (ushort)(r >> 16);
}
__device__ __forceinline__ float bf2f(ushort h) {
    union { unsigned u; float f; } c; c.u = ((unsigned)h) << 16;
    return c.f;
}

// ---------------- LIF over input x -> xs bf16 spikes (vth=1.0) ----------------
__global__ __launch_bounds__(256) void k_lif_x(const float* __restrict__ x,
                                               ushort* __restrict__ xs)
{
    int i = blockIdx.x*256 + threadIdx.x;   // [0, TSTR)
    float v = 0.f;
    #pragma unroll
    for (int t = 0; t < TT; t++) {
        float xt = x[t*TSTR + i];
        v += (xt - v)*0.5f;
        float s = (v - 1.0f) >= 0.f ? 1.f : 0.f;
        xs[t*TSTR + i] = (s != 0.f) ? (ushort)0x3F80 : (ushort)0;
        v *= (1.f - s);
    }
}

// ---------------- split wq/wk/wv into bf16 hi/mid/lo planes ----------------
__global__ __launch_bounds__(256) void k_wsplit(
    const float* __restrict__ wq, const float* __restrict__ wk, const float* __restrict__ wv,
    ushort* __restrict__ wsp)
{
    int i = blockIdx.x*256 + threadIdx.x;   // [0, 3*CCSQ)
    int which = i / CCSQ, r = i % CCSQ;
    const float* W = (which==0) ? wq : (which==1 ? wk : wv);
    float v = W[r];
    ushort hi = f2bf(v);  float r1 = v - bf2f(hi);
    ushort md = f2bf(r1); float r2 = r1 - bf2f(md);
    ushort lo = f2bf(r2);
    long b = (long)which*3*CCSQ;
    wsp[b + r] = hi; wsp[b + CCSQ + r] = md; wsp[b + 2L*CCSQ + r] = lo;
}

// ---------------- MFMA QKV GEMM: Y[t,b] = W @ xs[t,b], BN on k/v ----------------
// xs binary bf16 (exact); W 3-split bf16. 64x64 tile, K-chunk 32.
__global__ __launch_bounds__(256) void k_gemm_qkv_mfma(
    const ushort* __restrict__ wsp,
    const float* __restrict__ kbn, const float* __restrict__ vbn,
    const ushort* __restrict__ xs,
    float* __restrict__ qo, float* __restrict__ ko, float* __restrict__ vo)
{
    int which = blockIdx.z >> 6;      // 0=q,1=k,2=v
    int tb    = blockIdx.z & 63;
    const float* bn = (which==0) ? nullptr : (which==1 ? kbn : vbn);
    float* Y        = ((which==0) ? qo : (which==1 ? ko : vo)) + (long)tb*PLANE;
    const ushort* X = xs + (long)tb*PLANE;
    const ushort* Wb = wsp + (long)which*3*CCSQ;
    int d0 = blockIdx.y*64, n0 = blockIdx.x*64;

    __shared__ ushort Ws[3][64][40];   // stride 40 u16 = 80 B (16B-aligned rows)
    __shared__ ushort Xs[64][40];

    int tid = threadIdx.x, lane = tid & 63, w = tid >> 6;
    int q4 = lane >> 4, l16 = lane & 15;

    f32x4 acc[4];
    #pragma unroll
    for (int nt = 0; nt < 4; nt++) acc[nt] = (f32x4){0.f,0.f,0.f,0.f};

    for (int k0 = 0; k0 < CC; k0 += 32) {
        __syncthreads();
        {   // W planes: 64 d x 32 k, 16B loads
            int d = tid >> 2, kq = (tid & 3)*8;
            long gofs = (long)(d0+d)*CC + k0 + kq;
            #pragma unroll
            for (int pl = 0; pl < 3; pl++) {
                uint4 t = *(const uint4*)(Wb + (long)pl*CCSQ + gofs);
                *(uint4*)&Ws[pl][d][kq] = t;
            }
        }
        // X transpose-stage: [k][n] global -> Xs[n][k]
        for (int idx = tid; idx < 1024; idx += 256) {
            int kk = idx >> 5;            // 0..31
            int np = (idx & 31) << 1;     // 0,2,..,62
            unsigned v = *(const unsigned*)(X + (long)(k0+kk)*NS + n0 + np);
            Xs[np  ][kk] = (ushort)(v & 0xFFFFu);
            Xs[np+1][kk] = (ushort)(v >> 16);
        }
        __syncthreads();

        short8 a0 = *(short8*)&Ws[0][w*16 + l16][q4*8];
        short8 a1 = *(short8*)&Ws[1][w*16 + l16][q4*8];
        short8 a2 = *(short8*)&Ws[2][w*16 + l16][q4*8];
        #pragma unroll
        for (int nt = 0; nt < 4; nt++) {
            short8 b = *(short8*)&Xs[nt*16 + l16][q4*8];
            acc[nt] = __builtin_amdgcn_mfma_f32_16x16x32_bf16(a0, b, acc[nt], 0, 0, 0);
            acc[nt] = __builtin_amdgcn_mfma_f32_16x16x32_bf16(a1, b, acc[nt], 0, 0, 0);
            acc[nt] = __builtin_amdgcn_mfma_f32_16x16x32_bf16(a2, b, acc[nt], 0, 0, 0);
        }
    }

    // epilogue: D row=q4*4+r -> d, col=l16 -> n (within nt tile)
    bool hasbn = (bn != nullptr);
    #pragma unroll
    for (int r = 0; r < 4; r++) {
        int d = d0 + w*16 + q4*4 + r;
        float inv = 1.f, mu = 0.f, be = 0.f;
        if (hasbn) {
            float g = bn[d]; be = bn[CC+d]; mu = bn[2*CC+d]; float va = bn[3*CC+d];
            inv = g / sqrtf(va + 1e-5f);
        }
        #pragma unroll
        for (int nt = 0; nt < 4; nt++) {
            int n = n0 + nt*16 + l16;
            float v = acc[nt][r];
            if (hasbn) v = inv*(v - mu) + be;
            Y[(long)d*NS + n] = v;
        }
    }
}

// ---------------- LIF for q(0.05)/k(1.0)/v(1.0), in-place ----------------
__global__ __launch_bounds__(256) void k_lif_qkv(
    float* __restrict__ qb, float* __restrict__ kb, float* __restrict__ vb,
    float* __restrict__ outs0, float* __restrict__ vout)
{
    int which = blockIdx.y;
    int i = blockIdx.x*256 + threadIdx.x;
    float* buf = (which==0) ? qb : (which==1 ? kb : vb);
    float vth  = (which==0) ? 0.05f : 1.0f;
    int b=0, n=0, h=0, dd=0;
    if (which == 2) {
        b = i / PLANE; int r = i % PLANE;
        int c = r >> 8; n = r & 255;
        h = c / HDD; dd = c % HDD;
    }
    float v = 0.f;
    #pragma unroll
    for (int t = 0; t < TT; t++) {
        float xt = buf[t*TSTR + i];
        v += (xt - v)*0.5f;
        float s = (v - vth) >= 0.f ? 1.f : 0.f;
        buf[t*TSTR + i] = s;
        if (which == 0 && t == 0) outs0[i] = s;
        if (which == 2)
            vout[(((long)(t*BB+b)*NHD + h)*NS + n)*HDD + dd] = s;
        v *= (1.f - s);
    }
}

// ---------------- TIM conv1d step i: cur = s*0.6 + q_i*0.4 ----------------
__global__ __launch_bounds__(256) void k_tim_conv(
    const float* __restrict__ w, const float* __restrict__ bias,
    const float* __restrict__ prev,   // outs[i-1], [B,C,N]
    const float* __restrict__ qi,     // q spikes at t=i, [B,C,N]
    float* __restrict__ cur)          // outs[i]
{
    int b = blockIdx.z, d0 = blockIdx.y*64, n0 = blockIdx.x*32;
    __shared__ float Ws[64][85];   // [d][ci*5+k]
    __shared__ float Xs[16][40];   // [ci][n halo 36]
    int tid = threadIdx.x, ty = tid >> 4, tx = tid & 15;  // 4 d x 2 n per thread
    float acc[4][2] = {};

    for (int c0 = 0; c0 < CC; c0 += 16) {
        {   // W chunk: 64 x 80
            int d = tid >> 2, p = (tid & 3)*20;
            const float* src = &w[(long)(d0+d)*CC*5 + c0*5 + p];
            #pragma unroll
            for (int q = 0; q < 5; q++) {
                float4 t4 = *(const float4*)&src[q*4];
                Ws[d][p+q*4+0]=t4.x; Ws[d][p+q*4+1]=t4.y; Ws[d][p+q*4+2]=t4.z; Ws[d][p+q*4+3]=t4.w;
            }
        }
        for (int idx = tid; idx < 16*36; idx += 256) {
            int ci = idx / 36, col = idx % 36;
            int n = n0 + col - 2;
            Xs[ci][col] = (n >= 0 && n < NS) ? prev[(long)b*PLANE + (c0+ci)*NS + n] : 0.f;
        }
        __syncthreads();
        #pragma unroll
        for (int ci = 0; ci < 16; ci++) {
            #pragma unroll
            for (int k = 0; k < 5; k++) {
                float w0=Ws[ty*4+0][ci*5+k], w1=Ws[ty*4+1][ci*5+k];
                float w2=Ws[ty*4+2][ci*5+k], w3=Ws[ty*4+3][ci*5+k];
                float x0=Xs[ci][tx*2+0+k],   x1=Xs[ci][tx*2+1+k];
                acc[0][0]+=w0*x0; acc[0][1]+=w0*x1;
                acc[1][0]+=w1*x0; acc[1][1]+=w1*x1;
                acc[2][0]+=w2*x0; acc[2][1]+=w2*x1;
                acc[3][0]+=w3*x0; acc[3][1]+=w3*x1;
            }
        }
        __syncthreads();
    }
    #pragma unroll
    for (int i = 0; i < 4; i++) {
        int d = d0 + ty*4 + i;
        float bv = bias[d];
        #pragma unroll
        for (int j = 0; j < 2; j++) {
            int n = n0 + tx*2 + j;
            float c = acc[i][j] + bv;
            float s = (c*0.5f - 0.3f) >= 0.f ? 1.f : 0.f;
            float qv = qi[(long)b*PLANE + d*NS + n];
            cur[(long)b*PLANE + d*NS + n] = s*0.6f + qv*0.4f;
        }
    }
}

// ---------------- TIM output LIF (vth=0.5) -> bf16 spikes + per-block count ----------------
__global__ __launch_bounds__(256) void k_tim_lif(const float* __restrict__ outs,
                                                 ushort* __restrict__ qbf,
                                                 unsigned* __restrict__ partials)
{
    int i = blockIdx.x*256 + threadIdx.x;
    float v = 0.f; unsigned c = 0;
    #pragma unroll
    for (int t = 0; t < TT; t++) {
        float xt = outs[t*TSTR + i];
        v += (xt - v)*0.5f;
        float s = (v - 0.5f) >= 0.f ? 1.f : 0.f;
        qbf[t*TSTR + i] = (s != 0.f) ? (ushort)0x3F80 : (ushort)0;  // bf16 1.0 / 0.0
        c += (unsigned)s;
        v *= (1.f - s);
    }
    #pragma unroll
    for (int off = 32; off >= 1; off >>= 1) c += __shfl_down(c, off, 64);
    __shared__ unsigned wsum[4];
    if ((threadIdx.x & 63) == 0) wsum[threadIdx.x >> 6] = c;
    __syncthreads();
    if (threadIdx.x == 0)
        partials[blockIdx.x] = wsum[0] + wsum[1] + wsum[2] + wsum[3];
}

// ---------------- reduce NPART partials -> cnt ----------------
__global__ __launch_bounds__(256) void k_cnt_reduce(const unsigned* __restrict__ partials,
                                                    unsigned* __restrict__ cnt)
{
    unsigned c = 0;
    for (int i = threadIdx.x; i < NPART; i += 256) c += partials[i];
    #pragma unroll
    for (int off = 32; off >= 1; off >>= 1) c += __shfl_down(c, off, 64);
    __shared__ unsigned wsum[4];
    if ((threadIdx.x & 63) == 0) wsum[threadIdx.x >> 6] = c;
    __syncthreads();
    if (threadIdx.x == 0)
        cnt[0] = wsum[0] + wsum[1] + wsum[2] + wsum[3];
}

// ---------------- dst transform + bn_last; kt -> bf16 hi/mid/lo, vt fp32 ----------------
__global__ __launch_bounds__(256) void k_dst(
    const float* __restrict__ dw, const float* __restrict__ dbn,
    const float* __restrict__ kin, const float* __restrict__ vin,
    ushort* __restrict__ kth, ushort* __restrict__ ktm, ushort* __restrict__ ktl,
    float* __restrict__ vt)
{
    int tb  = blockIdx.z;
    int h   = blockIdx.y & 7;
    int isv = blockIdx.y >> 3;
    int n0  = blockIdx.x*32;
    const float* src = (isv ? vin : kin) + (long)tb*PLANE + (h*HDD)*NS;
    long dstbase = ((long)(tb*NHD + h)*NS)*HDD;
    __shared__ float Xs[48][33];
    __shared__ float Wsh[48][49];
    int tid = threadIdx.x;
    for (int idx = tid; idx < 48*32; idx += 256) {
        int d = idx >> 5, n = idx & 31;
        Xs[d][n] = src[d*NS + n0 + n];
    }
    for (int idx = tid; idx < 48*48; idx += 256) {
        int e = idx / 48, d = idx % 48;
        Wsh[e][d] = dw[idx];
    }
    __syncthreads();
    #pragma unroll
    for (int r = 0; r < 6; r++) {
        int o = tid + r*256;
        int n = o / 48, e = o % 48;
        float acc = 0.f;
        #pragma unroll
        for (int d = 0; d < 48; d++) acc += Wsh[e][d]*Xs[d][n];
        float g = dbn[e], be = dbn[48+e], mu = dbn[96+e], va = dbn[144+e];
        float val = g / sqrtf(va + 1e-5f) * (acc - mu) + be;
        long gi = dstbase + (long)(n0+n)*HDD + e;
        if (isv) {
            vt[gi] = val;
        } else {
            ushort hi = f2bf(val);
            float r1 = val - bf2f(hi);
            ushort md = f2bf(r1);
            float r2 = r1 - bf2f(md);
            ushort lo = f2bf(r2);
            kth[gi] = hi; ktm[gi] = md; ktl[gi] = lo;
        }
    }
}

// ---------------- MFMA attention: QK^T * c1 -> fused LIF(0.5) -> u8 map ----------------
__global__ __launch_bounds__(256) void k_attn_mfma(
    const ushort* __restrict__ qbf,
    const ushort* __restrict__ kth, const ushort* __restrict__ ktm, const ushort* __restrict__ ktl,
    const unsigned* __restrict__ cnt, unsigned char* __restrict__ amap)
{
    int bh = blockIdx.z;            // b*8+h
    int b = bh >> 3, h = bh & 7;
    int nbase = blockIdx.y*64, mbase = blockIdx.x*64;

    __shared__ ushort Qs[64][72];   // [n][d], d padded to 64 with zeros
    __shared__ ushort Kh[64][72];   // [m][e]
    __shared__ ushort Km[64][72];
    __shared__ ushort Kl[64][72];

    int tid  = threadIdx.x;
    int lane = tid & 63, w = tid >> 6;
    int q4 = lane >> 4, l16 = lane & 15;

    float mean = (float)(*cnt) / 6291456.0f;
    float c1 = fminf(1.0f / sqrtf(mean*48.0f + 1e-6f), 10.0f);

    {   // zero-init LDS once (pad cols 48..63 persist zero across t)
        unsigned* z0 = (unsigned*)&Qs[0][0];
        unsigned* z1 = (unsigned*)&Kh[0][0];
        unsigned* z2 = (unsigned*)&Km[0][0];
        unsigned* z3 = (unsigned*)&Kl[0][0];
        for (int i2 = tid; i2 < 64*72/2; i2 += 256) {
            z0[i2] = 0; z1[i2] = 0; z2[i2] = 0; z3[i2] = 0;
        }
    }

    float vmem[4][4];
    #pragma unroll
    for (int a = 0; a < 4; a++)
        #pragma unroll
        for (int r = 0; r < 4; r++) vmem[a][r] = 0.f;

    for (int t = 0; t < TT; t++) {
        int tb = t*BB + b;
        __syncthreads();
        const ushort* qsrc = qbf + (long)tb*PLANE + (long)(h*HDD)*NS + nbase;
        for (int idx = tid; idx < 1536; idx += 256) {
            int d = idx >> 5, np = (idx & 31) << 1;
            unsigned v = *(const unsigned*)(qsrc + (long)d*NS + np);
            Qs[np  ][d] = (ushort)(v & 0xFFFFu);
            Qs[np+1][d] = (ushort)(v >> 16);
        }
        long kb0 = ((long)(tb*NHD + h)*NS + mbase)*HDD;
        const ushort* kbh = kth + kb0;
        const ushort* kbm = ktm + kb0;
        const ushort* kbl = ktl + kb0;
        for (int idx = tid; idx < 1536; idx += 256) {
            int e2 = idx << 1;
            int m = e2 / HDD, er = e2 % HDD;
            *(unsigned*)&Kh[m][er] = *(const unsigned*)(kbh + e2);
            *(unsigned*)&Km[m][er] = *(const unsigned*)(kbm + e2);
            *(unsigned*)&Kl[m][er] = *(const unsigned*)(kbl + e2);
        }
        __syncthreads();

        int nrow = w*16 + l16;
        f32x4 acc[4];
        #pragma unroll
        for (int mt = 0; mt < 4; mt++) acc[mt] = (f32x4){0.f, 0.f, 0.f, 0.f};

        #pragma unroll
        for (int ks = 0; ks < 2; ks++) {
            short8 a = *(short8*)&Qs[nrow][ks*32 + q4*8];
            #pragma unroll
            for (int mt = 0; mt < 4; mt++) {
                int mrow = mt*16 + l16;
                short8 b_h = *(short8*)&Kh[mrow][ks*32 + q4*8];
                short8 b_m = *(short8*)&Km[mrow][ks*32 + q4*8];
                short8 b_l = *(short8*)&Kl[mrow][ks*32 + q4*8];
                acc[mt] = __builtin_amdgcn_mfma_f32_16x16x32_bf16(a, b_h, acc[mt], 0, 0, 0);
                acc[mt] = __builtin_amdgcn_mfma_f32_16x16x32_bf16(a, b_m, acc[mt], 0, 0, 0);
                acc[mt] = __builtin_amdgcn_mfma_f32_16x16x32_bf16(a, b_l, acc[mt], 0, 0, 0);
            }
        }

        long abase0 = ((long)(tb*NHD + h)*NS)*NS;
        #pragma unroll
        for (int mt = 0; mt < 4; mt++) {
            int m = mbase + mt*16 + l16;
            #pragma unroll
            for (int r = 0; r < 4; r++) {
                int n = nbase + w*16 + q4*4 + r;
                float a = acc[mt][r]*c1;
                float v = vmem[mt][r];
                v += (a - v)*0.5f;
                float s = (v - 0.5f) >= 0.f ? 1.f : 0.f;
                amap[abase0 + (long)n*NS + m] = (unsigned char)s;
                vmem[mt][r] = v*(1.f - s);
            }
        }
    }
}

// ---------------- out = attn_map @ v_t, reorder + identity ----------------
__global__ __launch_bounds__(256) void k_outmm(
    const unsigned char* __restrict__ amap, const float* __restrict__ vt,
    const float* __restrict__ x, float* __restrict__ oid)
{
    int tb = blockIdx.z;
    int h  = blockIdx.y;
    int n0 = blockIdx.x*64;
    __shared__ float As[64][65];
    __shared__ float Vs[64][49];
    int tid = threadIdx.x, ty = tid >> 4, tx = tid & 15;  // ty->3 e, tx->4 n
    float acc[4][3] = {};
    const unsigned char* abase = amap + ((long)(tb*NHD + h)*NS + n0)*NS;
    const float* vbase = vt + ((long)(tb*NHD + h)*NS)*HDD;

    for (int m0 = 0; m0 < NS; m0 += 64) {
        for (int idx = tid; idx < 1024; idx += 256) {
            int n = idx >> 4, mq = (idx & 15)*4;
            uchar4 u = *(const uchar4*)&abase[(long)n*NS + m0 + mq];
            As[n][mq+0]=(float)u.x; As[n][mq+1]=(float)u.y; As[n][mq+2]=(float)u.z; As[n][mq+3]=(float)u.w;
        }
        for (int idx = tid; idx < 64*48; idx += 256) {
            int m = idx / 48, e = idx % 48;
            Vs[m][e] = vbase[(long)(m0+m)*HDD + e];
        }
        __syncthreads();
        #pragma unroll
        for (int m = 0; m < 64; m++) {
            float a0=As[tx*4+0][m], a1=As[tx*4+1][m], a2=As[tx*4+2][m], a3=As[tx*4+3][m];
            float v0=Vs[m][ty*3+0], v1=Vs[m][ty*3+1], v2=Vs[m][ty*3+2];
            acc[0][0]+=a0*v0; acc[0][1]+=a0*v1; acc[0][2]+=a0*v2;
            acc[1][0]+=a1*v0; acc[1][1]+=a1*v1; acc[1][2]+=a1*v2;
            acc[2][0]+=a2*v0; acc[2][1]+=a2*v1; acc[2][2]+=a2*v2;
            acc[3][0]+=a3*v0; acc[3][1]+=a3*v1; acc[3][2]+=a3*v2;
        }
        __syncthreads();
    }
    #pragma unroll
    for (int j = 0; j < 3; j++) {
        int e = ty*3 + j;
        long base = (long)tb*PLANE + (h*HDD + e)*NS + n0 + tx*4;
        float4 o4;
        o4.x = acc[0][j] + x[base+0];
        o4.y = acc[1][j] + x[base+1];
        o4.z = acc[2][j] + x[base+2];
        o4.w = acc[3][j] + x[base+3];
        *(float4*)&oid[base] = o4;
    }
}

// ---------------- proj GEMM + bias + BN ----------------
__global__ __launch_bounds__(256) void k_gemm_proj(
    const float* __restrict__ W, const float* __restrict__ bias, const float* __restrict__ bn,
    const float* __restrict__ Xfull, float* __restrict__ Yfull)
{
    int tb = blockIdx.z;
    const float* X = Xfull + (long)tb*PLANE;
    float* Y = Yfull + (long)tb*PLANE;
    int d0 = blockIdx.y*64, n0 = blockIdx.x*64;

    __shared__ float As[16][68];
    __shared__ float Bs[16][68];
    int tid = threadIdx.x;
    int ty = tid >> 4, tx = tid & 15;
    float acc[4][4] = {};

    for (int k0 = 0; k0 < CC; k0 += 16) {
        {
            int d = tid >> 2, kq = (tid & 3)*4;
            float4 a4 = *(const float4*)&W[(long)(d0+d)*CC + k0 + kq];
            As[kq+0][d]=a4.x; As[kq+1][d]=a4.y; As[kq+2][d]=a4.z; As[kq+3][d]=a4.w;
        }
        {
            int k = tid >> 4, nq = (tid & 15)*4;
            *(float4*)&Bs[k][nq] = *(const float4*)&X[(long)(k0+k)*NS + n0 + nq];
        }
        __syncthreads();
        #pragma unroll
        for (int kk = 0; kk < 16; kk++) {
            float a0=As[kk][ty*4+0], a1=As[kk][ty*4+1], a2=As[kk][ty*4+2], a3=As[kk][ty*4+3];
            float b0=Bs[kk][tx*4+0], b1=Bs[kk][tx*4+1], b2=Bs[kk][tx*4+2], b3=Bs[kk][tx*4+3];
            acc[0][0]+=a0*b0; acc[0][1]+=a0*b1; acc[0][2]+=a0*b2; acc[0][3]+=a0*b3;
            acc[1][0]+=a1*b0; acc[1][1]+=a1*b1; acc[1][2]+=a1*b2; acc[1][3]+=a1*b3;
            acc[2][0]+=a2*b0; acc[2][1]+=a2*b1; acc[2][2]+=a2*b2; acc[2][3]+=a2*b3;
            acc[3][0]+=a3*b0; acc[3][1]+=a3*b1; acc[3][2]+=a3*b2; acc[3][3]+=a3*b3;
        }
        __syncthreads();
    }
    #pragma unroll
    for (int i = 0; i < 4; i++) {
        int d = d0 + ty*4 + i;
        float g = bn[d], be = bn[CC+d], mu = bn[2*CC+d], va = bn[3*CC+d];
        float inv = g / sqrtf(va + 1e-5f);
        float bv = bias[d];
        float4 o4;
        o4.x = inv*((acc[i][0]+bv) - mu) + be;
        o4.y = inv*((acc[i][1]+bv) - mu) + be;
        o4.z = inv*((acc[i][2]+bv) - mu) + be;
        o4.w = inv*((acc[i][3]+bv) - mu) + be;
        *(float4*)&Y[(long)d*NS + n0 + tx*4] = o4;
    }
}

// ---------------- final LIF (vth=1.0) -> d_out ----------------
__global__ __launch_bounds__(256) void k_final_lif(const float* __restrict__ pre,
                                                   float* __restrict__ out)
{
    int i = blockIdx.x*256 + threadIdx.x;
    float v = 0.f;
    #pragma unroll
    for (int t = 0; t < TT; t++) {
        float xt = pre[t*TSTR + i];
        v += (xt - v)*0.5f;
        float s = (v - 1.0f) >= 0.f ? 1.f : 0.f;
        out[t*TSTR + i] = s;
        v *= (1.f - s);
    }
}

extern "C" void kernel_launch(void* const* d_in, const int* in_sizes, int n_in,
                              void* d_out, int out_size, void* d_ws, size_t ws_size,
                              hipStream_t stream) {
    const float* x   = (const float*)d_in[0];
    const float* wq  = (const float*)d_in[1];
    const float* wk  = (const float*)d_in[2];
    const float* wv  = (const float*)d_in[3];
    const float* kbn = (const float*)d_in[4];
    const float* vbn = (const float*)d_in[5];
    const float* dw  = (const float*)d_in[6];
    const float* dbn = (const float*)d_in[7];
    const float* pw  = (const float*)d_in[8];
    const float* pb  = (const float*)d_in[9];
    const float* pbn = (const float*)d_in[10];
    const float* tw  = (const float*)d_in[11];
    const float* tbi = (const float*)d_in[12];

    float* out  = (float*)d_out;
    float* vout = out + TOT;

    float* ws   = (float*)d_ws;
    ushort* xs  = (ushort*)(ws + OFF_XS);     // bf16 spikes; region later oid fp32
    float* oid  = ws + OFF_XS;
    float* qb   = ws + OFF_Q;      // q_pre fp32 (tim chain input)
    float* kb   = ws + OFF_K;      // later reused as proj_pre
    float* vb   = ws + OFF_V;
    float* outs = ws + OFF_OUTS;
    ushort* qbf = (ushort*)(ws + OFF_Q);      // overlays qb after tim chain done
    ushort* wsp = (ushort*)(ws + OFF_KTS);    // weight splits (dead after step 2)
    ushort* kth = (ushort*)(ws + OFF_KTS);
    ushort* ktm = kth + TOT;
    ushort* ktl = kth + 2L*TOT;
    float* vt   = ws + OFF_VT;
    unsigned* cnt = (unsigned*)(ws + OFF_CNT);
    unsigned* partials = (unsigned*)(ws + OFF_KTS);   // transient; dead before k_dst
    unsigned char* amap = (unsigned char*)(ws + OFF_OUTS);  // overlays outs after k_tim_lif

    // 1. shortcut LIF -> bf16 spikes; split weights
    k_lif_x<<<dim3(TSTR/256), 256, 0, stream>>>(x, xs);
    k_wsplit<<<dim3(3*CCSQ/256), 256, 0, stream>>>(wq, wk, wv, wsp);
    // 2. q/k/v 1x1 convs via MFMA (+BN for k,v)
    k_gemm_qkv_mfma<<<dim3(4, 6, 192), 256, 0, stream>>>(wsp, kbn, vbn, xs, qb, kb, vb);
    // 3. LIF on q/k/v; q[0]->outs[0]; v spikes -> d_out (heads layout)
    k_lif_qkv<<<dim3(TSTR/256, 3), 256, 0, stream>>>(qb, kb, vb, outs, vout);
    // 4. TIM recurrent conv chain
    for (int i = 1; i < TT; i++) {
        k_tim_conv<<<dim3(8, 6, 16), 256, 0, stream>>>(
            tw, tbi, outs + (long)(i-1)*TSTR, qb + (long)i*TSTR, outs + (long)i*TSTR);
    }
    // 5. TIM output LIF -> bf16 q spikes + per-block counts
    k_tim_lif<<<dim3(NPART), 256, 0, stream>>>(outs, qbf, partials);
    // 5b. reduce partial counts -> cnt
    k_cnt_reduce<<<dim3(1), 256, 0, stream>>>(partials, cnt);
    // 6. dst transform + bn_last; kt as bf16 hi/mid/lo, vt fp32
    k_dst<<<dim3(8, 16, 64), 256, 0, stream>>>(dw, dbn, kb, vb, kth, ktm, ktl, vt);
    // 7. MFMA attention + fused LIF -> binary map
    k_attn_mfma<<<dim3(4, 4, 128), 256, 0, stream>>>(qbf, kth, ktm, ktl, cnt, amap);
    // 8. attn_map @ v_t, reorder, + identity
    k_outmm<<<dim3(4, 8, 64), 256, 0, stream>>>(amap, vt, x, oid);
    // 9. proj GEMM + bias + BN (proj_pre into kb buffer)
    k_gemm_proj<<<dim3(4, 6, 64), 256, 0, stream>>>(pw, pb, pbn, oid, kb);
    // 10. final LIF -> out
    k_final_lif<<<dim3(TSTR/256), 256, 0, stream>>>(kb, out);
}

// Round 5
// 960.289 us; speedup vs baseline: 1.5436x; 1.0748x over previous
//
#include <hip/hip_runtime.h>
#include <math.h>

#define TT 4
#define BB 16
#define CC 384
#define NS 256
#define NHD 8
#define HDD 48
#define PLANE 98304      /* CC*NS */
#define TSTR  1572864    /* BB*PLANE */
#define TOT   6291456    /* TT*TSTR */
#define CCSQ  147456     /* CC*CC */

// workspace float offsets (total (8*TOT+16)*4 = 201.3 MB)
#define OFF_XS   0L            /* xs bf16 spikes / later: oid fp32 */
#define OFF_Q    (1L*TOT)      /* q_pre fp32 -> (dead) -> qtim bf16 (step5) */
#define OFF_K    (2L*TOT)      /* k_pre -> k spikes -> proj_pre */
#define OFF_V    (3L*TOT)      /* v_pre -> v spikes */
#define OFF_OUTS (4L*TOT)      /* qsp bf16 + s planes (steps3-5); amap u8 (step7+) */
#define OFF_KTS  (11L*TOT/2)   /* partials | wsp | timw (dead by step6) -> kt hi/mid/lo */
#define OFF_VT   (7L*TOT)      /* vt fp32 */
#define OFF_CNT  (8L*TOT)      /* u32 spike counter */

#define NPART 6144             /* TSTR/256 blocks of k_tim_lif */

typedef __attribute__((ext_vector_type(8))) short short8;
typedef __attribute__((ext_vector_type(4))) float f32x4;

__device__ __forceinline__ ushort f2bf(float x) {   // RTNE fp32->bf16
    union { float f; unsigned u; } c; c.f = x;
    unsigned r = c.u + 0x7FFFu + ((c.u >> 16) & 1u);
    return (ushort)(r >> 16);
}
__device__ __forceinline__ float bf2f(ushort h) {
    union { unsigned u; float f; } c; c.u = ((unsigned)h) << 16;
    return c.f;
}

// ---------------- LIF over input x -> xs bf16 spikes (vth=1.0) ----------------
__global__ __launch_bounds__(256) void k_lif_x(const float* __restrict__ x,
                                               ushort* __restrict__ xs)
{
    int i = blockIdx.x*256 + threadIdx.x;   // [0, TSTR)
    float v = 0.f;
    #pragma unroll
    for (int t = 0; t < TT; t++) {
        float xt = x[t*TSTR + i];
        v += (xt - v)*0.5f;
        float s = (v - 1.0f) >= 0.f ? 1.f : 0.f;
        xs[t*TSTR + i] = (s != 0.f) ? (ushort)0x3F80 : (ushort)0;
        v *= (1.f - s);
    }
}

// ---------------- split wq/wk/wv into bf16 hi/mid/lo planes ----------------
__global__ __launch_bounds__(256) void k_wsplit(
    const float* __restrict__ wq, const float* __restrict__ wk, const float* __restrict__ wv,
    ushort* __restrict__ wsp)
{
    int i = blockIdx.x*256 + threadIdx.x;   // [0, 3*CCSQ)
    int which = i / CCSQ, r = i % CCSQ;
    const float* W = (which==0) ? wq : (which==1 ? wk : wv);
    float v = W[r];
    ushort hi = f2bf(v);  float r1 = v - bf2f(hi);
    ushort md = f2bf(r1); float r2 = r1 - bf2f(md);
    ushort lo = f2bf(r2);
    long b = (long)which*3*CCSQ;
    wsp[b + r] = hi; wsp[b + CCSQ + r] = md; wsp[b + 2L*CCSQ + r] = lo;
}

// ---------------- split tim conv weights, tap-major: timw[(pl*5+tap)][d][c] ----------------
__global__ __launch_bounds__(256) void k_wsplit_tim(const float* __restrict__ tw,
                                                    ushort* __restrict__ timw)
{
    int i = blockIdx.x*256 + threadIdx.x;   // [0, CCSQ) = (d,c)
    const float* src = tw + (long)i*5;
    #pragma unroll
    for (int tap = 0; tap < 5; tap++) {
        float v = src[tap];
        ushort hi = f2bf(v);  float r1 = v - bf2f(hi);
        ushort md = f2bf(r1); float r2 = r1 - bf2f(md);
        ushort lo = f2bf(r2);
        timw[(long)(0*5 + tap)*CCSQ + i] = hi;
        timw[(long)(1*5 + tap)*CCSQ + i] = md;
        timw[(long)(2*5 + tap)*CCSQ + i] = lo;
    }
}

// ---------------- MFMA QKV GEMM: Y[t,b] = W @ xs[t,b], BN on k/v ----------------
__global__ __launch_bounds__(256) void k_gemm_qkv_mfma(
    const ushort* __restrict__ wsp,
    const float* __restrict__ kbn, const float* __restrict__ vbn,
    const ushort* __restrict__ xs,
    float* __restrict__ qo, float* __restrict__ ko, float* __restrict__ vo)
{
    int which = blockIdx.z >> 6;      // 0=q,1=k,2=v
    int tb    = blockIdx.z & 63;
    const float* bn = (which==0) ? nullptr : (which==1 ? kbn : vbn);
    float* Y        = ((which==0) ? qo : (which==1 ? ko : vo)) + (long)tb*PLANE;
    const ushort* X = xs + (long)tb*PLANE;
    const ushort* Wb = wsp + (long)which*3*CCSQ;
    int d0 = blockIdx.y*64, n0 = blockIdx.x*64;

    __shared__ ushort Ws[3][64][40];
    __shared__ ushort Xs[64][40];

    int tid = threadIdx.x, lane = tid & 63, w = tid >> 6;
    int q4 = lane >> 4, l16 = lane & 15;

    f32x4 acc[4];
    #pragma unroll
    for (int nt = 0; nt < 4; nt++) acc[nt] = (f32x4){0.f,0.f,0.f,0.f};

    for (int k0 = 0; k0 < CC; k0 += 32) {
        __syncthreads();
        {
            int d = tid >> 2, kq = (tid & 3)*8;
            long gofs = (long)(d0+d)*CC + k0 + kq;
            #pragma unroll
            for (int pl = 0; pl < 3; pl++) {
                uint4 t = *(const uint4*)(Wb + (long)pl*CCSQ + gofs);
                *(uint4*)&Ws[pl][d][kq] = t;
            }
        }
        for (int idx = tid; idx < 1024; idx += 256) {
            int kk = idx >> 5;
            int np = (idx & 31) << 1;
            unsigned v = *(const unsigned*)(X + (long)(k0+kk)*NS + n0 + np);
            Xs[np  ][kk] = (ushort)(v & 0xFFFFu);
            Xs[np+1][kk] = (ushort)(v >> 16);
        }
        __syncthreads();

        short8 a0 = *(short8*)&Ws[0][w*16 + l16][q4*8];
        short8 a1 = *(short8*)&Ws[1][w*16 + l16][q4*8];
        short8 a2 = *(short8*)&Ws[2][w*16 + l16][q4*8];
        #pragma unroll
        for (int nt = 0; nt < 4; nt++) {
            short8 b = *(short8*)&Xs[nt*16 + l16][q4*8];
            acc[nt] = __builtin_amdgcn_mfma_f32_16x16x32_bf16(a0, b, acc[nt], 0, 0, 0);
            acc[nt] = __builtin_amdgcn_mfma_f32_16x16x32_bf16(a1, b, acc[nt], 0, 0, 0);
            acc[nt] = __builtin_amdgcn_mfma_f32_16x16x32_bf16(a2, b, acc[nt], 0, 0, 0);
        }
    }

    bool hasbn = (bn != nullptr);
    #pragma unroll
    for (int r = 0; r < 4; r++) {
        int d = d0 + w*16 + q4*4 + r;
        float inv = 1.f, mu = 0.f, be = 0.f;
        if (hasbn) {
            float g = bn[d]; be = bn[CC+d]; mu = bn[2*CC+d]; float va = bn[3*CC+d];
            inv = g / sqrtf(va + 1e-5f);
        }
        #pragma unroll
        for (int nt = 0; nt < 4; nt++) {
            int n = n0 + nt*16 + l16;
            float v = acc[nt][r];
            if (hasbn) v = inv*(v - mu) + be;
            Y[(long)d*NS + n] = v;
        }
    }
}

// ---------------- LIF: q(0.05)->qsp bf16; k,v(1.0) in-place fp32; v->d_out ----------------
__global__ __launch_bounds__(256) void k_lif_qkv(
    const float* __restrict__ qb, float* __restrict__ kb, float* __restrict__ vb,
    ushort* __restrict__ qsp, float* __restrict__ vout)
{
    int which = blockIdx.y;
    int i = blockIdx.x*256 + threadIdx.x;
    const float* rbuf = (which==0) ? qb : (which==1 ? kb : vb);
    float* wbuf = (which==1) ? kb : vb;
    float vth  = (which==0) ? 0.05f : 1.0f;
    int b=0, n=0, h=0, dd=0;
    if (which == 2) {
        b = i / PLANE; int r = i % PLANE;
        int c = r >> 8; n = r & 255;
        h = c / HDD; dd = c % HDD;
    }
    float v = 0.f;
    #pragma unroll
    for (int t = 0; t < TT; t++) {
        float xt = rbuf[t*TSTR + i];
        v += (xt - v)*0.5f;
        float s = (v - vth) >= 0.f ? 1.f : 0.f;
        if (which == 0) qsp[t*TSTR + i] = (s != 0.f) ? (ushort)0x3F80 : (ushort)0;
        else            wbuf[t*TSTR + i] = s;
        if (which == 2)
            vout[(((long)(t*BB+b)*NHD + h)*NS + n)*HDD + dd] = s;
        v *= (1.f - s);
    }
}

// ---------------- MFMA TIM conv step: spike(conv(0.6s+0.4q)) -> s_i bf16 plane ----------------
// conv decomposed: 0.6*conv(s) + 0.4*conv(q); s,q binary bf16 (exact), w 3-split.
__global__ __launch_bounds__(256) void k_tim_conv_mfma(
    const ushort* __restrict__ timw, const float* __restrict__ bias,
    const ushort* __restrict__ qprev,   // q spikes t=i-1, [B,C,N] u16
    const ushort* __restrict__ sprev,   // s_{i-1} plane or null
    int hass,
    ushort* __restrict__ sout)          // s_i plane
{
    int b = blockIdx.z, d0 = blockIdx.y*64, n0 = blockIdx.x*64;
    const ushort* qp = qprev + (long)b*PLANE;
    const ushort* sp = sprev + (long)b*PLANE;   // unused if !hass

    __shared__ ushort Ws[3][3][64][40];   // [tap-local][plane][d][c]  46.1 KB
    __shared__ ushort Xq[68][40];         // halo n rows [n0-2, n0+66)
    __shared__ ushort Xsp[68][40];

    int tid = threadIdx.x, lane = tid & 63, w = tid >> 6;
    int q4 = lane >> 4, l16 = lane & 15;
    int drow = w*16 + l16;

    f32x4 accQ[4], accS[4];
    #pragma unroll
    for (int nt = 0; nt < 4; nt++) {
        accQ[nt] = (f32x4){0.f,0.f,0.f,0.f};
        accS[nt] = (f32x4){0.f,0.f,0.f,0.f};
    }

    for (int c0 = 0; c0 < CC; c0 += 32) {
        #pragma unroll
        for (int g = 0; g < 2; g++) {
            int ntap = g ? 2 : 3;
            __syncthreads();
            // stage W group: ntap*3 planes x 64 d x 32 c  (uint4 = 8 u16)
            int nu4 = ntap*3*64*4;
            for (int idx = tid; idx < nu4; idx += 256) {
                int c8 = idx & 3, d = (idx >> 2) & 63;
                int rest = idx >> 8;               // 0..ntap*3-1
                int tl = rest % ntap, pl = rest / ntap;
                int tap = g*3 + tl;
                uint4 t = *(const uint4*)(timw + (long)(pl*5 + tap)*CCSQ
                                          + (long)(d0+d)*CC + c0 + c8*8);
                *(uint4*)&Ws[tl][pl][d][c8*8] = t;
            }
            if (g == 0) {   // stage X halo tiles once per c-chunk
                for (int idx = tid; idx < 68*32; idx += 256) {
                    int c = idx / 68, nr = idx % 68;
                    int n = n0 + nr - 2;
                    bool ok = (n >= 0 && n < NS);
                    long go = (long)(c0 + c)*NS + n;
                    Xq[nr][c] = ok ? qp[go] : (ushort)0;
                    if (hass) Xsp[nr][c] = ok ? sp[go] : (ushort)0;
                }
            }
            __syncthreads();
            // compute group
            for (int tl = 0; tl < ntap; tl++) {
                int tap = g*3 + tl;
                short8 a0 = *(short8*)&Ws[tl][0][drow][q4*8];
                short8 a1 = *(short8*)&Ws[tl][1][drow][q4*8];
                short8 a2 = *(short8*)&Ws[tl][2][drow][q4*8];
                #pragma unroll
                for (int nt = 0; nt < 4; nt++) {
                    int row = nt*16 + l16 + tap;
                    short8 bq = *(short8*)&Xq[row][q4*8];
                    accQ[nt] = __builtin_amdgcn_mfma_f32_16x16x32_bf16(a0, bq, accQ[nt], 0, 0, 0);
                    accQ[nt] = __builtin_amdgcn_mfma_f32_16x16x32_bf16(a1, bq, accQ[nt], 0, 0, 0);
                    accQ[nt] = __builtin_amdgcn_mfma_f32_16x16x32_bf16(a2, bq, accQ[nt], 0, 0, 0);
                    if (hass) {
                        short8 bs = *(short8*)&Xsp[row][q4*8];
                        accS[nt] = __builtin_amdgcn_mfma_f32_16x16x32_bf16(a0, bs, accS[nt], 0, 0, 0);
                        accS[nt] = __builtin_amdgcn_mfma_f32_16x16x32_bf16(a1, bs, accS[nt], 0, 0, 0);
                        accS[nt] = __builtin_amdgcn_mfma_f32_16x16x32_bf16(a2, bs, accS[nt], 0, 0, 0);
                    }
                }
            }
        }
    }

    // epilogue: D row=q4*4+r -> d, col=l16 -> n
    ushort* so = sout + (long)b*PLANE;
    #pragma unroll
    for (int r = 0; r < 4; r++) {
        int d = d0 + w*16 + q4*4 + r;
        float bv = bias[d];
        #pragma unroll
        for (int nt = 0; nt < 4; nt++) {
            int n = n0 + nt*16 + l16;
            float conv = hass ? (0.6f*accS[nt][r] + 0.4f*accQ[nt][r]) : accQ[nt][r];
            float c = conv + bv;
            float s = (c*0.5f - 0.3f) >= 0.f ? 1.f : 0.f;
            so[(long)d*NS + n] = (s != 0.f) ? (ushort)0x3F80 : (ushort)0;
        }
    }
}

// ---------------- TIM output LIF: reconstruct outs, LIF(0.5) -> qtim bf16 + counts ----------------
__global__ __launch_bounds__(256) void k_tim_lif(const ushort* __restrict__ qsp,
                                                 const ushort* __restrict__ spl,
                                                 ushort* __restrict__ qtim,
                                                 unsigned* __restrict__ partials)
{
    int i = blockIdx.x*256 + threadIdx.x;
    float v = 0.f; unsigned c = 0;
    #pragma unroll
    for (int t = 0; t < TT; t++) {
        float val;
        if (t == 0) {
            val = bf2f(qsp[i]);
        } else {
            float sf = bf2f(spl[(t-1)*TSTR + i]);
            float qf = bf2f(qsp[t*TSTR + i]);
            val = sf*0.6f + qf*0.4f;     // matches reference x_tim formula
        }
        v += (val - v)*0.5f;
        float s = (v - 0.5f) >= 0.f ? 1.f : 0.f;
        qtim[t*TSTR + i] = (s != 0.f) ? (ushort)0x3F80 : (ushort)0;
        c += (unsigned)s;
        v *= (1.f - s);
    }
    #pragma unroll
    for (int off = 32; off >= 1; off >>= 1) c += __shfl_down(c, off, 64);
    __shared__ unsigned wsum[4];
    if ((threadIdx.x & 63) == 0) wsum[threadIdx.x >> 6] = c;
    __syncthreads();
    if (threadIdx.x == 0)
        partials[blockIdx.x] = wsum[0] + wsum[1] + wsum[2] + wsum[3];
}

// ---------------- reduce NPART partials -> cnt ----------------
__global__ __launch_bounds__(256) void k_cnt_reduce(const unsigned* __restrict__ partials,
                                                    unsigned* __restrict__ cnt)
{
    unsigned c = 0;
    for (int i = threadIdx.x; i < NPART; i += 256) c += partials[i];
    #pragma unroll
    for (int off = 32; off >= 1; off >>= 1) c += __shfl_down(c, off, 64);
    __shared__ unsigned wsum[4];
    if ((threadIdx.x & 63) == 0) wsum[threadIdx.x >> 6] = c;
    __syncthreads();
    if (threadIdx.x == 0)
        cnt[0] = wsum[0] + wsum[1] + wsum[2] + wsum[3];
}

// ---------------- dst transform + bn_last; kt -> bf16 hi/mid/lo, vt fp32 ----------------
__global__ __launch_bounds__(256) void k_dst(
    const float* __restrict__ dw, const float* __restrict__ dbn,
    const float* __restrict__ kin, const float* __restrict__ vin,
    ushort* __restrict__ kth, ushort* __restrict__ ktm, ushort* __restrict__ ktl,
    float* __restrict__ vt)
{
    int tb  = blockIdx.z;
    int h   = blockIdx.y & 7;
    int isv = blockIdx.y >> 3;
    int n0  = blockIdx.x*32;
    const float* src = (isv ? vin : kin) + (long)tb*PLANE + (h*HDD)*NS;
    long dstbase = ((long)(tb*NHD + h)*NS)*HDD;
    __shared__ float Xs[48][33];
    __shared__ float Wsh[48][49];
    int tid = threadIdx.x;
    for (int idx = tid; idx < 48*32; idx += 256) {
        int d = idx >> 5, n = idx & 31;
        Xs[d][n] = src[d*NS + n0 + n];
    }
    for (int idx = tid; idx < 48*48; idx += 256) {
        int e = idx / 48, d = idx % 48;
        Wsh[e][d] = dw[idx];
    }
    __syncthreads();
    #pragma unroll
    for (int r = 0; r < 6; r++) {
        int o = tid + r*256;
        int n = o / 48, e = o % 48;
        float acc = 0.f;
        #pragma unroll
        for (int d = 0; d < 48; d++) acc += Wsh[e][d]*Xs[d][n];
        float g = dbn[e], be = dbn[48+e], mu = dbn[96+e], va = dbn[144+e];
        float val = g / sqrtf(va + 1e-5f) * (acc - mu) + be;
        long gi = dstbase + (long)(n0+n)*HDD + e;
        if (isv) {
            vt[gi] = val;
        } else {
            ushort hi = f2bf(val);
            float r1 = val - bf2f(hi);
            ushort md = f2bf(r1);
            float r2 = r1 - bf2f(md);
            ushort lo = f2bf(r2);
            kth[gi] = hi; ktm[gi] = md; ktl[gi] = lo;
        }
    }
}

// ---------------- MFMA attention: QK^T * c1 -> fused LIF(0.5) -> u8 map ----------------
__global__ __launch_bounds__(256) void k_attn_mfma(
    const ushort* __restrict__ qbf,
    const ushort* __restrict__ kth, const ushort* __restrict__ ktm, const ushort* __restrict__ ktl,
    const unsigned* __restrict__ cnt, unsigned char* __restrict__ amap)
{
    int bh = blockIdx.z;            // b*8+h
    int b = bh >> 3, h = bh & 7;
    int nbase = blockIdx.y*64, mbase = blockIdx.x*64;

    __shared__ ushort Qs[64][72];
    __shared__ ushort Kh[64][72];
    __shared__ ushort Km[64][72];
    __shared__ ushort Kl[64][72];

    int tid  = threadIdx.x;
    int lane = tid & 63, w = tid >> 6;
    int q4 = lane >> 4, l16 = lane & 15;

    float mean = (float)(*cnt) / 6291456.0f;
    float c1 = fminf(1.0f / sqrtf(mean*48.0f + 1e-6f), 10.0f);

    {
        unsigned* z0 = (unsigned*)&Qs[0][0];
        unsigned* z1 = (unsigned*)&Kh[0][0];
        unsigned* z2 = (unsigned*)&Km[0][0];
        unsigned* z3 = (unsigned*)&Kl[0][0];
        for (int i2 = tid; i2 < 64*72/2; i2 += 256) {
            z0[i2] = 0; z1[i2] = 0; z2[i2] = 0; z3[i2] = 0;
        }
    }

    float vmem[4][4];
    #pragma unroll
    for (int a = 0; a < 4; a++)
        #pragma unroll
        for (int r = 0; r < 4; r++) vmem[a][r] = 0.f;

    for (int t = 0; t < TT; t++) {
        int tb = t*BB + b;
        __syncthreads();
        const ushort* qsrc = qbf + (long)tb*PLANE + (long)(h*HDD)*NS + nbase;
        for (int idx = tid; idx < 1536; idx += 256) {
            int d = idx >> 5, np = (idx & 31) << 1;
            unsigned v = *(const unsigned*)(qsrc + (long)d*NS + np);
            Qs[np  ][d] = (ushort)(v & 0xFFFFu);
            Qs[np+1][d] = (ushort)(v >> 16);
        }
        long kb0 = ((long)(tb*NHD + h)*NS + mbase)*HDD;
        const ushort* kbh = kth + kb0;
        const ushort* kbm = ktm + kb0;
        const ushort* kbl = ktl + kb0;
        for (int idx = tid; idx < 1536; idx += 256) {
            int e2 = idx << 1;
            int m = e2 / HDD, er = e2 % HDD;
            *(unsigned*)&Kh[m][er] = *(const unsigned*)(kbh + e2);
            *(unsigned*)&Km[m][er] = *(const unsigned*)(kbm + e2);
            *(unsigned*)&Kl[m][er] = *(const unsigned*)(kbl + e2);
        }
        __syncthreads();

        int nrow = w*16 + l16;
        f32x4 acc[4];
        #pragma unroll
        for (int mt = 0; mt < 4; mt++) acc[mt] = (f32x4){0.f, 0.f, 0.f, 0.f};

        #pragma unroll
        for (int ks = 0; ks < 2; ks++) {
            short8 a = *(short8*)&Qs[nrow][ks*32 + q4*8];
            #pragma unroll
            for (int mt = 0; mt < 4; mt++) {
                int mrow = mt*16 + l16;
                short8 b_h = *(short8*)&Kh[mrow][ks*32 + q4*8];
                short8 b_m = *(short8*)&Km[mrow][ks*32 + q4*8];
                short8 b_l = *(short8*)&Kl[mrow][ks*32 + q4*8];
                acc[mt] = __builtin_amdgcn_mfma_f32_16x16x32_bf16(a, b_h, acc[mt], 0, 0, 0);
                acc[mt] = __builtin_amdgcn_mfma_f32_16x16x32_bf16(a, b_m, acc[mt], 0, 0, 0);
                acc[mt] = __builtin_amdgcn_mfma_f32_16x16x32_bf16(a, b_l, acc[mt], 0, 0, 0);
            }
        }

        long abase0 = ((long)(tb*NHD + h)*NS)*NS;
        #pragma unroll
        for (int mt = 0; mt < 4; mt++) {
            int m = mbase + mt*16 + l16;
            #pragma unroll
            for (int r = 0; r < 4; r++) {
                int n = nbase + w*16 + q4*4 + r;
                float a = acc[mt][r]*c1;
                float v = vmem[mt][r];
                v += (a - v)*0.5f;
                float s = (v - 0.5f) >= 0.f ? 1.f : 0.f;
                amap[abase0 + (long)n*NS + m] = (unsigned char)s;
                vmem[mt][r] = v*(1.f - s);
            }
        }
    }
}

// ---------------- out = attn_map @ v_t, reorder + identity ----------------
__global__ __launch_bounds__(256) void k_outmm(
    const unsigned char* __restrict__ amap, const float* __restrict__ vt,
    const float* __restrict__ x, float* __restrict__ oid)
{
    int tb = blockIdx.z;
    int h  = blockIdx.y;
    int n0 = blockIdx.x*64;
    __shared__ float As[64][65];
    __shared__ float Vs[64][49];
    int tid = threadIdx.x, ty = tid >> 4, tx = tid & 15;
    float acc[4][3] = {};
    const unsigned char* abase = amap + ((long)(tb*NHD + h)*NS + n0)*NS;
    const float* vbase = vt + ((long)(tb*NHD + h)*NS)*HDD;

    for (int m0 = 0; m0 < NS; m0 += 64) {
        for (int idx = tid; idx < 1024; idx += 256) {
            int n = idx >> 4, mq = (idx & 15)*4;
            uchar4 u = *(const uchar4*)&abase[(long)n*NS + m0 + mq];
            As[n][mq+0]=(float)u.x; As[n][mq+1]=(float)u.y; As[n][mq+2]=(float)u.z; As[n][mq+3]=(float)u.w;
        }
        for (int idx = tid; idx < 64*48; idx += 256) {
            int m = idx / 48, e = idx % 48;
            Vs[m][e] = vbase[(long)(m0+m)*HDD + e];
        }
        __syncthreads();
        #pragma unroll
        for (int m = 0; m < 64; m++) {
            float a0=As[tx*4+0][m], a1=As[tx*4+1][m], a2=As[tx*4+2][m], a3=As[tx*4+3][m];
            float v0=Vs[m][ty*3+0], v1=Vs[m][ty*3+1], v2=Vs[m][ty*3+2];
            acc[0][0]+=a0*v0; acc[0][1]+=a0*v1; acc[0][2]+=a0*v2;
            acc[1][0]+=a1*v0; acc[1][1]+=a1*v1; acc[1][2]+=a1*v2;
            acc[2][0]+=a2*v0; acc[2][1]+=a2*v1; acc[2][2]+=a2*v2;
            acc[3][0]+=a3*v0; acc[3][1]+=a3*v1; acc[3][2]+=a3*v2;
        }
        __syncthreads();
    }
    #pragma unroll
    for (int j = 0; j < 3; j++) {
        int e = ty*3 + j;
        long base = (long)tb*PLANE + (h*HDD + e)*NS + n0 + tx*4;
        float4 o4;
        o4.x = acc[0][j] + x[base+0];
        o4.y = acc[1][j] + x[base+1];
        o4.z = acc[2][j] + x[base+2];
        o4.w = acc[3][j] + x[base+3];
        *(float4*)&oid[base] = o4;
    }
}

// ---------------- proj GEMM + bias + BN ----------------
__global__ __launch_bounds__(256) void k_gemm_proj(
    const float* __restrict__ W, const float* __restrict__ bias, const float* __restrict__ bn,
    const float* __restrict__ Xfull, float* __restrict__ Yfull)
{
    int tb = blockIdx.z;
    const float* X = Xfull + (long)tb*PLANE;
    float* Y = Yfull + (long)tb*PLANE;
    int d0 = blockIdx.y*64, n0 = blockIdx.x*64;

    __shared__ float As[16][68];
    __shared__ float Bs[16][68];
    int tid = threadIdx.x;
    int ty = tid >> 4, tx = tid & 15;
    float acc[4][4] = {};

    for (int k0 = 0; k0 < CC; k0 += 16) {
        {
            int d = tid >> 2, kq = (tid & 3)*4;
            float4 a4 = *(const float4*)&W[(long)(d0+d)*CC + k0 + kq];
            As[kq+0][d]=a4.x; As[kq+1][d]=a4.y; As[kq+2][d]=a4.z; As[kq+3][d]=a4.w;
        }
        {
            int k = tid >> 4, nq = (tid & 15)*4;
            *(float4*)&Bs[k][nq] = *(const float4*)&X[(long)(k0+k)*NS + n0 + nq];
        }
        __syncthreads();
        #pragma unroll
        for (int kk = 0; kk < 16; kk++) {
            float a0=As[kk][ty*4+0], a1=As[kk][ty*4+1], a2=As[kk][ty*4+2], a3=As[kk][ty*4+3];
            float b0=Bs[kk][tx*4+0], b1=Bs[kk][tx*4+1], b2=Bs[kk][tx*4+2], b3=Bs[kk][tx*4+3];
            acc[0][0]+=a0*b0; acc[0][1]+=a0*b1; acc[0][2]+=a0*b2; acc[0][3]+=a0*b3;
            acc[1][0]+=a1*b0; acc[1][1]+=a1*b1; acc[1][2]+=a1*b2; acc[1][3]+=a1*b3;
            acc[2][0]+=a2*b0; acc[2][1]+=a2*b1; acc[2][2]+=a2*b2; acc[2][3]+=a2*b3;
            acc[3][0]+=a3*b0; acc[3][1]+=a3*b1; acc[3][2]+=a3*b2; acc[3][3]+=a3*b3;
        }
        __syncthreads();
    }
    #pragma unroll
    for (int i = 0; i < 4; i++) {
        int d = d0 + ty*4 + i;
        float g = bn[d], be = bn[CC+d], mu = bn[2*CC+d], va = bn[3*CC+d];
        float inv = g / sqrtf(va + 1e-5f);
        float bv = bias[d];
        float4 o4;
        o4.x = inv*((acc[i][0]+bv) - mu) + be;
        o4.y = inv*((acc[i][1]+bv) - mu) + be;
        o4.z = inv*((acc[i][2]+bv) - mu) + be;
        o4.w = inv*((acc[i][3]+bv) - mu) + be;
        *(float4*)&Y[(long)d*NS + n0 + tx*4] = o4;
    }
}

// ---------------- final LIF (vth=1.0) -> d_out ----------------
__global__ __launch_bounds__(256) void k_final_lif(const float* __restrict__ pre,
                                                   float* __restrict__ out)
{
    int i = blockIdx.x*256 + threadIdx.x;
    float v = 0.f;
    #pragma unroll
    for (int t = 0; t < TT; t++) {
        float xt = pre[t*TSTR + i];
        v += (xt - v)*0.5f;
        float s = (v - 1.0f) >= 0.f ? 1.f : 0.f;
        out[t*TSTR + i] = s;
        v *= (1.f - s);
    }
}

extern "C" void kernel_launch(void* const* d_in, const int* in_sizes, int n_in,
                              void* d_out, int out_size, void* d_ws, size_t ws_size,
                              hipStream_t stream) {
    const float* x   = (const float*)d_in[0];
    const float* wq  = (const float*)d_in[1];
    const float* wk  = (const float*)d_in[2];
    const float* wv  = (const float*)d_in[3];
    const float* kbn = (const float*)d_in[4];
    const float* vbn = (const float*)d_in[5];
    const float* dw  = (const float*)d_in[6];
    const float* dbn = (const float*)d_in[7];
    const float* pw  = (const float*)d_in[8];
    const float* pb  = (const float*)d_in[9];
    const float* pbn = (const float*)d_in[10];
    const float* tw  = (const float*)d_in[11];
    const float* tbi = (const float*)d_in[12];

    float* out  = (float*)d_out;
    float* vout = out + TOT;

    float* ws   = (float*)d_ws;
    ushort* xs  = (ushort*)(ws + OFF_XS);     // bf16 spikes; region later oid fp32
    float* oid  = ws + OFF_XS;
    float* qb   = ws + OFF_Q;      // q_pre fp32 (dead after step 3)
    float* kb   = ws + OFF_K;      // later proj_pre
    float* vb   = ws + OFF_V;
    ushort* qtim = (ushort*)(ws + OFF_Q);     // TIM-out spikes (step 5+, Q region dead)
    // OUTS region: qsp (TOT u16) | s planes (3*TSTR u16); amap overlays after step 5
    ushort* qsp = (ushort*)(ws + OFF_OUTS);
    ushort* spl = qsp + TOT;
    unsigned char* amap = (unsigned char*)(ws + OFF_OUTS);
    // KTS region: partials (24KB) | qkv wsplit | tim wsplit; kth planes overlay at step 6
    unsigned* partials = (unsigned*)(ws + OFF_KTS);
    ushort* wsp  = (ushort*)(ws + OFF_KTS) + 32768;
    ushort* timw = wsp + 9L*CCSQ;
    ushort* kth = (ushort*)(ws + OFF_KTS);
    ushort* ktm = kth + TOT;
    ushort* ktl = kth + 2L*TOT;
    float* vt   = ws + OFF_VT;
    unsigned* cnt = (unsigned*)(ws + OFF_CNT);

    // 1. shortcut LIF -> bf16 spikes; split weights (qkv + tim)
    k_lif_x<<<dim3(TSTR/256), 256, 0, stream>>>(x, xs);
    k_wsplit<<<dim3(3*CCSQ/256), 256, 0, stream>>>(wq, wk, wv, wsp);
    k_wsplit_tim<<<dim3(CCSQ/256), 256, 0, stream>>>(tw, timw);
    // 2. q/k/v 1x1 convs via MFMA (+BN for k,v)
    k_gemm_qkv_mfma<<<dim3(4, 6, 192), 256, 0, stream>>>(wsp, kbn, vbn, xs, qb, kb, vb);
    // 3. LIF on q/k/v; q spikes -> qsp bf16; v spikes -> d_out (heads layout)
    k_lif_qkv<<<dim3(TSTR/256, 3), 256, 0, stream>>>(qb, kb, vb, qsp, vout);
    // 4. TIM recurrent conv chain via MFMA (s_i planes)
    for (int i = 1; i < TT; i++) {
        k_tim_conv_mfma<<<dim3(4, 6, 16), 256, 0, stream>>>(
            timw, tbi,
            qsp + (long)(i-1)*TSTR,
            (i >= 2) ? (spl + (long)(i-2)*TSTR) : qsp /*unused*/,
            (i >= 2) ? 1 : 0,
            spl + (long)(i-1)*TSTR);
    }
    // 5. TIM output LIF -> qtim bf16 spikes + per-block counts
    k_tim_lif<<<dim3(NPART), 256, 0, stream>>>(qsp, spl, qtim, partials);
    // 5b. reduce partial counts -> cnt
    k_cnt_reduce<<<dim3(1), 256, 0, stream>>>(partials, cnt);
    // 6. dst transform + bn_last; kt as bf16 hi/mid/lo, vt fp32
    k_dst<<<dim3(8, 16, 64), 256, 0, stream>>>(dw, dbn, kb, vb, kth, ktm, ktl, vt);
    // 7. MFMA attention + fused LIF -> binary map (overlays OUTS region)
    k_attn_mfma<<<dim3(4, 4, 128), 256, 0, stream>>>(qtim, kth, ktm, ktl, cnt, amap);
    // 8. attn_map @ v_t, reorder, + identity
    k_outmm<<<dim3(4, 8, 64), 256, 0, stream>>>(amap, vt, x, oid);
    // 9. proj GEMM + bias + BN (proj_pre into kb buffer)
    k_gemm_proj<<<dim3(4, 6, 64), 256, 0, stream>>>(pw, pb, pbn, oid, kb);
    // 10. final LIF -> out
    k_final_lif<<<dim3(TSTR/256), 256, 0, stream>>>(kb, out);
}

// Round 6
// 895.735 us; speedup vs baseline: 1.6548x; 1.0721x over previous
//
#include <hip/hip_runtime.h>
#include <math.h>

#define TT 4
#define BB 16
#define CC 384
#define NS 256
#define NHD 8
#define HDD 48
#define PLANE 98304      /* CC*NS */
#define TSTR  1572864    /* BB*PLANE */
#define TOT   6291456    /* TT*TSTR */
#define CCSQ  147456     /* CC*CC */
#define PB    99840      /* padded batch plane: 260*384 u16 */
#define PPL   1597440    /* padded t-plane: 16*260*384 u16 */

// workspace float offsets (total (8*TOT+16)*4 = 201.3 MB)
#define OFF_XS   0L            /* xs bf16 spikes / later: oid fp32 */
#define OFF_Q    (1L*TOT)      /* q_preT fp32 -> (dead) -> qtim bf16 (step5) */
#define OFF_K    (2L*TOT)      /* k_pre -> k spikes -> proj_pre */
#define OFF_V    (3L*TOT)      /* v_pre -> v spikes */
#define OFF_OUTS (4L*TOT)      /* qspT + splT padded u16 (steps3-5); amap u8 (step7+) */
#define OFF_KTS  (11L*TOT/2)   /* partials | wsp | timw (dead by step6) -> kt hi/mid/lo */
#define OFF_VT   (7L*TOT)      /* vt fp32 */
#define OFF_CNT  (8L*TOT)      /* u32 spike counter */

#define NPART 6144             /* TSTR/256 blocks of k_tim_lif */

typedef __attribute__((ext_vector_type(8))) short short8;
typedef __attribute__((ext_vector_type(4))) float f32x4;

__device__ __forceinline__ ushort f2bf(float x) {   // RTNE fp32->bf16
    union { float f; unsigned u; } c; c.f = x;
    unsigned r = c.u + 0x7FFFu + ((c.u >> 16) & 1u);
    return (ushort)(r >> 16);
}
__device__ __forceinline__ float bf2f(ushort h) {
    union { unsigned u; float f; } c; c.u = ((unsigned)h) << 16;
    return c.f;
}

// ---------------- LIF over input x -> xs bf16 spikes (vth=1.0) ----------------
__global__ __launch_bounds__(256) void k_lif_x(const float* __restrict__ x,
                                               ushort* __restrict__ xs)
{
    int i = blockIdx.x*256 + threadIdx.x;   // [0, TSTR)
    float v = 0.f;
    #pragma unroll
    for (int t = 0; t < TT; t++) {
        float xt = x[t*TSTR + i];
        v += (xt - v)*0.5f;
        float s = (v - 1.0f) >= 0.f ? 1.f : 0.f;
        xs[t*TSTR + i] = (s != 0.f) ? (ushort)0x3F80 : (ushort)0;
        v *= (1.f - s);
    }
}

// ---------------- zero the halo pad rows of qspT (4 t) and splT (3 planes) ----------------
// d_ws re-poisoned 0xAA every call -> pads must be zeroed every launch.
__global__ __launch_bounds__(256) void k_zero_pads(unsigned* __restrict__ qspT_u32)
{
    int i = blockIdx.x*256 + threadIdx.x;     // [0, 112*4*192)
    int plane = i / 768, rem = i % 768;
    int r = rem / 192, cu = rem % 192;
    int row = (r < 2) ? r : (256 + r);        // 0,1,258,259
    qspT_u32[(long)plane*(PB/2) + row*192 + cu] = 0;
}

// ---------------- split wq/wk/wv into bf16 hi/mid/lo planes ----------------
__global__ __launch_bounds__(256) void k_wsplit(
    const float* __restrict__ wq, const float* __restrict__ wk, const float* __restrict__ wv,
    ushort* __restrict__ wsp)
{
    int i = blockIdx.x*256 + threadIdx.x;   // [0, 3*CCSQ)
    int which = i / CCSQ, r = i % CCSQ;
    const float* W = (which==0) ? wq : (which==1 ? wk : wv);
    float v = W[r];
    ushort hi = f2bf(v);  float r1 = v - bf2f(hi);
    ushort md = f2bf(r1); float r2 = r1 - bf2f(md);
    ushort lo = f2bf(r2);
    long b = (long)which*3*CCSQ;
    wsp[b + r] = hi; wsp[b + CCSQ + r] = md; wsp[b + 2L*CCSQ + r] = lo;
}

// ---------------- split tim conv weights, tap-major: timw[(pl*5+tap)][d][c] ----------------
__global__ __launch_bounds__(256) void k_wsplit_tim(const float* __restrict__ tw,
                                                    ushort* __restrict__ timw)
{
    int i = blockIdx.x*256 + threadIdx.x;   // [0, CCSQ) = (d,c)
    const float* src = tw + (long)i*5;
    #pragma unroll
    for (int tap = 0; tap < 5; tap++) {
        float v = src[tap];
        ushort hi = f2bf(v);  float r1 = v - bf2f(hi);
        ushort md = f2bf(r1); float r2 = r1 - bf2f(md);
        ushort lo = f2bf(r2);
        timw[(long)(0*5 + tap)*CCSQ + i] = hi;
        timw[(long)(1*5 + tap)*CCSQ + i] = md;
        timw[(long)(2*5 + tap)*CCSQ + i] = lo;
    }
}

// ---------------- MFMA QKV GEMM; q output TRANSPOSED [b][n][c] ----------------
__global__ __launch_bounds__(256) void k_gemm_qkv_mfma(
    const ushort* __restrict__ wsp,
    const float* __restrict__ kbn, const float* __restrict__ vbn,
    const ushort* __restrict__ xs,
    float* __restrict__ qo, float* __restrict__ ko, float* __restrict__ vo)
{
    int which = blockIdx.z >> 6;      // 0=q,1=k,2=v
    int tb    = blockIdx.z & 63;
    const float* bn = (which==0) ? nullptr : (which==1 ? kbn : vbn);
    float* Y        = ((which==0) ? qo : (which==1 ? ko : vo)) + (long)tb*PLANE;
    const ushort* X = xs + (long)tb*PLANE;
    const ushort* Wb = wsp + (long)which*3*CCSQ;
    int d0 = blockIdx.y*64, n0 = blockIdx.x*64;

    __shared__ ushort Ws[3][64][40];
    __shared__ ushort Xs[64][40];

    int tid = threadIdx.x, lane = tid & 63, w = tid >> 6;
    int q4 = lane >> 4, l16 = lane & 15;

    f32x4 acc[4];
    #pragma unroll
    for (int nt = 0; nt < 4; nt++) acc[nt] = (f32x4){0.f,0.f,0.f,0.f};

    for (int k0 = 0; k0 < CC; k0 += 32) {
        __syncthreads();
        {
            int d = tid >> 2, kq = (tid & 3)*8;
            long gofs = (long)(d0+d)*CC + k0 + kq;
            #pragma unroll
            for (int pl = 0; pl < 3; pl++) {
                uint4 t = *(const uint4*)(Wb + (long)pl*CCSQ + gofs);
                *(uint4*)&Ws[pl][d][kq] = t;
            }
        }
        for (int idx = tid; idx < 1024; idx += 256) {
            int kk = idx >> 5;
            int np = (idx & 31) << 1;
            unsigned v = *(const unsigned*)(X + (long)(k0+kk)*NS + n0 + np);
            Xs[np  ][kk] = (ushort)(v & 0xFFFFu);
            Xs[np+1][kk] = (ushort)(v >> 16);
        }
        __syncthreads();

        short8 a0 = *(short8*)&Ws[0][w*16 + l16][q4*8];
        short8 a1 = *(short8*)&Ws[1][w*16 + l16][q4*8];
        short8 a2 = *(short8*)&Ws[2][w*16 + l16][q4*8];
        if (which == 0) {   // swapped: D[n][d] for transposed store
            #pragma unroll
            for (int nt = 0; nt < 4; nt++) {
                short8 b = *(short8*)&Xs[nt*16 + l16][q4*8];
                acc[nt] = __builtin_amdgcn_mfma_f32_16x16x32_bf16(b, a0, acc[nt], 0, 0, 0);
                acc[nt] = __builtin_amdgcn_mfma_f32_16x16x32_bf16(b, a1, acc[nt], 0, 0, 0);
                acc[nt] = __builtin_amdgcn_mfma_f32_16x16x32_bf16(b, a2, acc[nt], 0, 0, 0);
            }
        } else {
            #pragma unroll
            for (int nt = 0; nt < 4; nt++) {
                short8 b = *(short8*)&Xs[nt*16 + l16][q4*8];
                acc[nt] = __builtin_amdgcn_mfma_f32_16x16x32_bf16(a0, b, acc[nt], 0, 0, 0);
                acc[nt] = __builtin_amdgcn_mfma_f32_16x16x32_bf16(a1, b, acc[nt], 0, 0, 0);
                acc[nt] = __builtin_amdgcn_mfma_f32_16x16x32_bf16(a2, b, acc[nt], 0, 0, 0);
            }
        }
    }

    if (which == 0) {
        // D rows = n (q4*4+r within nt strip), cols = d (l16 within w strip)
        #pragma unroll
        for (int r = 0; r < 4; r++) {
            int d = d0 + w*16 + l16;
            #pragma unroll
            for (int nt = 0; nt < 4; nt++) {
                int n = n0 + nt*16 + q4*4 + r;
                Y[(long)n*CC + d] = acc[nt][r];
            }
        }
    } else {
        #pragma unroll
        for (int r = 0; r < 4; r++) {
            int d = d0 + w*16 + q4*4 + r;
            float g = bn[d], be = bn[CC+d], mu = bn[2*CC+d], va = bn[3*CC+d];
            float inv = g / sqrtf(va + 1e-5f);
            #pragma unroll
            for (int nt = 0; nt < 4; nt++) {
                int n = n0 + nt*16 + l16;
                Y[(long)d*NS + n] = inv*(acc[nt][r] - mu) + be;
            }
        }
    }
}

// ---------------- LIF: q(0.05)->qspT padded bf16; k,v(1.0) in-place; v->d_out ----------------
__global__ __launch_bounds__(256) void k_lif_qkv(
    const float* __restrict__ qb, float* __restrict__ kb, float* __restrict__ vb,
    ushort* __restrict__ qspT, float* __restrict__ vout)
{
    int which = blockIdx.y;
    int i = blockIdx.x*256 + threadIdx.x;
    const float* rbuf = (which==0) ? qb : (which==1 ? kb : vb);
    float* wbuf = (which==1) ? kb : vb;
    float vth  = (which==0) ? 0.05f : 1.0f;
    int b=0, n=0, h=0, dd=0;
    long qofs = 0;
    if (which == 0) {
        b = i / PLANE;
        qofs = (long)i + b*1536 + 768;   // padded [b][n+2][c] offset
    }
    if (which == 2) {
        b = i / PLANE; int r = i % PLANE;
        int c = r >> 8; n = r & 255;
        h = c / HDD; dd = c % HDD;
    }
    float v = 0.f;
    #pragma unroll
    for (int t = 0; t < TT; t++) {
        float xt = rbuf[t*TSTR + i];
        v += (xt - v)*0.5f;
        float s = (v - vth) >= 0.f ? 1.f : 0.f;
        if (which == 0) qspT[(long)t*PPL + qofs] = (s != 0.f) ? (ushort)0x3F80 : (ushort)0;
        else            wbuf[t*TSTR + i] = s;
        if (which == 2)
            vout[(((long)(t*BB+b)*NHD + h)*NS + n)*HDD + dd] = s;
        v *= (1.f - s);
    }
}

// ---------------- MFMA TIM conv step (n-major): s_i = spike(conv(0.6s+0.4q)) ----------------
// A-frags (X rows, tap-shifted) loaded directly from padded global; only W in LDS.
__global__ __launch_bounds__(512) void k_tim_conv_mfma(
    const ushort* __restrict__ timw, const float* __restrict__ bias,
    const ushort* __restrict__ qT,      // qspT plane t=i-1, [16][260][384]
    const ushort* __restrict__ sTp,     // s_{i-1} padded plane (unused if !hass)
    int hass,
    ushort* __restrict__ sTo)           // s_i padded plane
{
    int b = blockIdx.z, d0 = blockIdx.y*64, n0 = blockIdx.x*64;
    const ushort* qp = qT  + (long)b*PB;
    const ushort* sp = sTp + (long)b*PB;

    __shared__ ushort Ws[15][64][40];   // [pl*5+tap][d][c]  76.8 KB

    int tid = threadIdx.x, lane = tid & 63, w = tid >> 6;   // 8 waves
    int q4 = lane >> 4, l16 = lane & 15;
    int dstrip = w >> 1, nh = w & 1;    // wave: d-strip 16, n-half 32 (2 nt)

    f32x4 accQ[2], accS[2];
    #pragma unroll
    for (int nt = 0; nt < 2; nt++) {
        accQ[nt] = (f32x4){0.f,0.f,0.f,0.f};
        accS[nt] = (f32x4){0.f,0.f,0.f,0.f};
    }

    for (int c0 = 0; c0 < CC; c0 += 32) {
        __syncthreads();
        // stage all 15 plane-taps: 64 d x 32 c each, uint4
        for (int idx = tid; idx < 3840; idx += 512) {
            int pt = idx >> 8, rem = idx & 255;
            int d = rem >> 2, c8 = rem & 3;
            uint4 t = *(const uint4*)(timw + (long)pt*CCSQ + (long)(d0+d)*CC + c0 + c8*8);
            *(uint4*)&Ws[pt][d][c8*8] = t;
        }
        __syncthreads();

        #pragma unroll
        for (int tap = 0; tap < 5; tap++) {
            // A-frags: rows n = n0 + nh*32 + nt*16 + l16 + tap (padded layout)
            long rbase = (long)(n0 + nh*32 + l16 + tap)*CC + c0 + q4*8;
            short8 aq0 = *(const short8*)(qp + rbase);
            short8 aq1 = *(const short8*)(qp + rbase + 16*CC);
            short8 as0, as1;
            if (hass) {
                as0 = *(const short8*)(sp + rbase);
                as1 = *(const short8*)(sp + rbase + 16*CC);
            }
            #pragma unroll
            for (int pl = 0; pl < 3; pl++) {
                short8 bw = *(short8*)&Ws[pl*5 + tap][dstrip*16 + l16][q4*8];
                accQ[0] = __builtin_amdgcn_mfma_f32_16x16x32_bf16(aq0, bw, accQ[0], 0, 0, 0);
                accQ[1] = __builtin_amdgcn_mfma_f32_16x16x32_bf16(aq1, bw, accQ[1], 0, 0, 0);
                if (hass) {
                    accS[0] = __builtin_amdgcn_mfma_f32_16x16x32_bf16(as0, bw, accS[0], 0, 0, 0);
                    accS[1] = __builtin_amdgcn_mfma_f32_16x16x32_bf16(as1, bw, accS[1], 0, 0, 0);
                }
            }
        }
    }

    // epilogue: D rows = n (q4*4+r), cols = d (l16). Store padded n-major.
    ushort* so = sTo + (long)b*PB;
    int d = d0 + dstrip*16 + l16;
    float bv = bias[d];
    #pragma unroll
    for (int nt = 0; nt < 2; nt++) {
        #pragma unroll
        for (int r = 0; r < 4; r++) {
            int n = n0 + nh*32 + nt*16 + q4*4 + r;
            float conv = hass ? (0.6f*accS[nt][r] + 0.4f*accQ[nt][r]) : accQ[nt][r];
            float c = conv + bv;
            float s = (c*0.5f - 0.3f) >= 0.f ? 1.f : 0.f;
            so[(long)(n + 2)*CC + d] = (s != 0.f) ? (ushort)0x3F80 : (ushort)0;
        }
    }
}

// ---------------- TIM output LIF: reconstruct outs, LIF(0.5) -> qtim [b][n][c] + counts ----------------
__global__ __launch_bounds__(256) void k_tim_lif(const ushort* __restrict__ qspT,
                                                 const ushort* __restrict__ splT,
                                                 ushort* __restrict__ qtim,
                                                 unsigned* __restrict__ partials)
{
    int i = blockIdx.x*256 + threadIdx.x;    // flat (b,n,c)
    int b = i / PLANE;
    long po = (long)i + b*1536 + 768;        // padded offset
    float v = 0.f; unsigned c = 0;
    #pragma unroll
    for (int t = 0; t < TT; t++) {
        float val;
        if (t == 0) {
            val = bf2f(qspT[po]);
        } else {
            float sf = bf2f(splT[(long)(t-1)*PPL + po]);
            float qf = bf2f(qspT[(long)t*PPL + po]);
            val = sf*0.6f + qf*0.4f;
        }
        v += (val - v)*0.5f;
        float s = (v - 0.5f) >= 0.f ? 1.f : 0.f;
        qtim[(long)t*TSTR + i] = (s != 0.f) ? (ushort)0x3F80 : (ushort)0;
        c += (unsigned)s;
        v *= (1.f - s);
    }
    #pragma unroll
    for (int off = 32; off >= 1; off >>= 1) c += __shfl_down(c, off, 64);
    __shared__ unsigned wsum[4];
    if ((threadIdx.x & 63) == 0) wsum[threadIdx.x >> 6] = c;
    __syncthreads();
    if (threadIdx.x == 0)
        partials[blockIdx.x] = wsum[0] + wsum[1] + wsum[2] + wsum[3];
}

// ---------------- reduce NPART partials -> cnt ----------------
__global__ __launch_bounds__(256) void k_cnt_reduce(const unsigned* __restrict__ partials,
                                                    unsigned* __restrict__ cnt)
{
    unsigned c = 0;
    for (int i = threadIdx.x; i < NPART; i += 256) c += partials[i];
    #pragma unroll
    for (int off = 32; off >= 1; off >>= 1) c += __shfl_down(c, off, 64);
    __shared__ unsigned wsum[4];
    if ((threadIdx.x & 63) == 0) wsum[threadIdx.x >> 6] = c;
    __syncthreads();
    if (threadIdx.x == 0)
        cnt[0] = wsum[0] + wsum[1] + wsum[2] + wsum[3];
}

// ---------------- dst transform + bn_last; kt -> bf16 hi/mid/lo, vt fp32 ----------------
__global__ __launch_bounds__(256) void k_dst(
    const float* __restrict__ dw, const float* __restrict__ dbn,
    const float* __restrict__ kin, const float* __restrict__ vin,
    ushort* __restrict__ kth, ushort* __restrict__ ktm, ushort* __restrict__ ktl,
    float* __restrict__ vt)
{
    int tb  = blockIdx.z;
    int h   = blockIdx.y & 7;
    int isv = blockIdx.y >> 3;
    int n0  = blockIdx.x*32;
    const float* src = (isv ? vin : kin) + (long)tb*PLANE + (h*HDD)*NS;
    long dstbase = ((long)(tb*NHD + h)*NS)*HDD;
    __shared__ float Xs[48][33];
    __shared__ float Wsh[48][49];
    int tid = threadIdx.x;
    for (int idx = tid; idx < 48*32; idx += 256) {
        int d = idx >> 5, n = idx & 31;
        Xs[d][n] = src[d*NS + n0 + n];
    }
    for (int idx = tid; idx < 48*48; idx += 256) {
        int e = idx / 48, d = idx % 48;
        Wsh[e][d] = dw[idx];
    }
    __syncthreads();
    #pragma unroll
    for (int r = 0; r < 6; r++) {
        int o = tid + r*256;
        int n = o / 48, e = o % 48;
        float acc = 0.f;
        #pragma unroll
        for (int d = 0; d < 48; d++) acc += Wsh[e][d]*Xs[d][n];
        float g = dbn[e], be = dbn[48+e], mu = dbn[96+e], va = dbn[144+e];
        float val = g / sqrtf(va + 1e-5f) * (acc - mu) + be;
        long gi = dstbase + (long)(n0+n)*HDD + e;
        if (isv) {
            vt[gi] = val;
        } else {
            ushort hi = f2bf(val);
            float r1 = val - bf2f(hi);
            ushort md = f2bf(r1);
            float r2 = r1 - bf2f(md);
            ushort lo = f2bf(r2);
            kth[gi] = hi; ktm[gi] = md; ktl[gi] = lo;
        }
    }
}

// ---------------- MFMA attention: QK^T * c1 -> fused LIF(0.5) -> u8 map ----------------
// qtim now n-major [tb][n][c].
__global__ __launch_bounds__(256) void k_attn_mfma(
    const ushort* __restrict__ qtim,
    const ushort* __restrict__ kth, const ushort* __restrict__ ktm, const ushort* __restrict__ ktl,
    const unsigned* __restrict__ cnt, unsigned char* __restrict__ amap)
{
    int bh = blockIdx.z;            // b*8+h
    int b = bh >> 3, h = bh & 7;
    int nbase = blockIdx.y*64, mbase = blockIdx.x*64;

    __shared__ ushort Qs[64][72];
    __shared__ ushort Kh[64][72];
    __shared__ ushort Km[64][72];
    __shared__ ushort Kl[64][72];

    int tid  = threadIdx.x;
    int lane = tid & 63, w = tid >> 6;
    int q4 = lane >> 4, l16 = lane & 15;

    float mean = (float)(*cnt) / 6291456.0f;
    float c1 = fminf(1.0f / sqrtf(mean*48.0f + 1e-6f), 10.0f);

    {
        unsigned* z0 = (unsigned*)&Qs[0][0];
        unsigned* z1 = (unsigned*)&Kh[0][0];
        unsigned* z2 = (unsigned*)&Km[0][0];
        unsigned* z3 = (unsigned*)&Kl[0][0];
        for (int i2 = tid; i2 < 64*72/2; i2 += 256) {
            z0[i2] = 0; z1[i2] = 0; z2[i2] = 0; z3[i2] = 0;
        }
    }

    float vmem[4][4];
    #pragma unroll
    for (int a = 0; a < 4; a++)
        #pragma unroll
        for (int r = 0; r < 4; r++) vmem[a][r] = 0.f;

    for (int t = 0; t < TT; t++) {
        int tb = t*BB + b;
        __syncthreads();
        // Q stage: direct copy rows (no transpose; qtim n-major)
        const ushort* qsrc = qtim + (long)tb*PLANE + (long)nbase*CC + h*HDD;
        for (int idx = tid; idx < 768; idx += 256) {   // 64 rows x 12 u16x4
            int n = idx / 12, c4 = idx % 12;
            *(uint2*)&Qs[n][c4*4] = *(const uint2*)(qsrc + (long)n*CC + c4*4);
        }
        long kb0 = ((long)(tb*NHD + h)*NS + mbase)*HDD;
        const ushort* kbh = kth + kb0;
        const ushort* kbm = ktm + kb0;
        const ushort* kbl = ktl + kb0;
        for (int idx = tid; idx < 1536; idx += 256) {
            int e2 = idx << 1;
            int m = e2 / HDD, er = e2 % HDD;
            *(unsigned*)&Kh[m][er] = *(const unsigned*)(kbh + e2);
            *(unsigned*)&Km[m][er] = *(const unsigned*)(kbm + e2);
            *(unsigned*)&Kl[m][er] = *(const unsigned*)(kbl + e2);
        }
        __syncthreads();

        int nrow = w*16 + l16;
        f32x4 acc[4];
        #pragma unroll
        for (int mt = 0; mt < 4; mt++) acc[mt] = (f32x4){0.f, 0.f, 0.f, 0.f};

        #pragma unroll
        for (int ks = 0; ks < 2; ks++) {
            short8 a = *(short8*)&Qs[nrow][ks*32 + q4*8];
            #pragma unroll
            for (int mt = 0; mt < 4; mt++) {
                int mrow = mt*16 + l16;
                short8 b_h = *(short8*)&Kh[mrow][ks*32 + q4*8];
                short8 b_m = *(short8*)&Km[mrow][ks*32 + q4*8];
                short8 b_l = *(short8*)&Kl[mrow][ks*32 + q4*8];
                acc[mt] = __builtin_amdgcn_mfma_f32_16x16x32_bf16(a, b_h, acc[mt], 0, 0, 0);
                acc[mt] = __builtin_amdgcn_mfma_f32_16x16x32_bf16(a, b_m, acc[mt], 0, 0, 0);
                acc[mt] = __builtin_amdgcn_mfma_f32_16x16x32_bf16(a, b_l, acc[mt], 0, 0, 0);
            }
        }

        long abase0 = ((long)(tb*NHD + h)*NS)*NS;
        #pragma unroll
        for (int mt = 0; mt < 4; mt++) {
            int m = mbase + mt*16 + l16;
            #pragma unroll
            for (int r = 0; r < 4; r++) {
                int n = nbase + w*16 + q4*4 + r;
                float a = acc[mt][r]*c1;
                float v = vmem[mt][r];
                v += (a - v)*0.5f;
                float s = (v - 0.5f) >= 0.f ? 1.f : 0.f;
                amap[abase0 + (long)n*NS + m] = (unsigned char)s;
                vmem[mt][r] = v*(1.f - s);
            }
        }
    }
}

// ---------------- out = attn_map @ v_t, reorder + identity ----------------
__global__ __launch_bounds__(256) void k_outmm(
    const unsigned char* __restrict__ amap, const float* __restrict__ vt,
    const float* __restrict__ x, float* __restrict__ oid)
{
    int tb = blockIdx.z;
    int h  = blockIdx.y;
    int n0 = blockIdx.x*64;
    __shared__ float As[64][65];
    __shared__ float Vs[64][49];
    int tid = threadIdx.x, ty = tid >> 4, tx = tid & 15;
    float acc[4][3] = {};
    const unsigned char* abase = amap + ((long)(tb*NHD + h)*NS + n0)*NS;
    const float* vbase = vt + ((long)(tb*NHD + h)*NS)*HDD;

    for (int m0 = 0; m0 < NS; m0 += 64) {
        for (int idx = tid; idx < 1024; idx += 256) {
            int n = idx >> 4, mq = (idx & 15)*4;
            uchar4 u = *(const uchar4*)&abase[(long)n*NS + m0 + mq];
            As[n][mq+0]=(float)u.x; As[n][mq+1]=(float)u.y; As[n][mq+2]=(float)u.z; As[n][mq+3]=(float)u.w;
        }
        for (int idx = tid; idx < 64*48; idx += 256) {
            int m = idx / 48, e = idx % 48;
            Vs[m][e] = vbase[(long)(m0+m)*HDD + e];
        }
        __syncthreads();
        #pragma unroll
        for (int m = 0; m < 64; m++) {
            float a0=As[tx*4+0][m], a1=As[tx*4+1][m], a2=As[tx*4+2][m], a3=As[tx*4+3][m];
            float v0=Vs[m][ty*3+0], v1=Vs[m][ty*3+1], v2=Vs[m][ty*3+2];
            acc[0][0]+=a0*v0; acc[0][1]+=a0*v1; acc[0][2]+=a0*v2;
            acc[1][0]+=a1*v0; acc[1][1]+=a1*v1; acc[1][2]+=a1*v2;
            acc[2][0]+=a2*v0; acc[2][1]+=a2*v1; acc[2][2]+=a2*v2;
            acc[3][0]+=a3*v0; acc[3][1]+=a3*v1; acc[3][2]+=a3*v2;
        }
        __syncthreads();
    }
    #pragma unroll
    for (int j = 0; j < 3; j++) {
        int e = ty*3 + j;
        long base = (long)tb*PLANE + (h*HDD + e)*NS + n0 + tx*4;
        float4 o4;
        o4.x = acc[0][j] + x[base+0];
        o4.y = acc[1][j] + x[base+1];
        o4.z = acc[2][j] + x[base+2];
        o4.w = acc[3][j] + x[base+3];
        *(float4*)&oid[base] = o4;
    }
}

// ---------------- proj GEMM + bias + BN ----------------
__global__ __launch_bounds__(256) void k_gemm_proj(
    const float* __restrict__ W, const float* __restrict__ bias, const float* __restrict__ bn,
    const float* __restrict__ Xfull, float* __restrict__ Yfull)
{
    int tb = blockIdx.z;
    const float* X = Xfull + (long)tb*PLANE;
    float* Y = Yfull + (long)tb*PLANE;
    int d0 = blockIdx.y*64, n0 = blockIdx.x*64;

    __shared__ float As[16][68];
    __shared__ float Bs[16][68];
    int tid = threadIdx.x;
    int ty = tid >> 4, tx = tid & 15;
    float acc[4][4] = {};

    for (int k0 = 0; k0 < CC; k0 += 16) {
        {
            int d = tid >> 2, kq = (tid & 3)*4;
            float4 a4 = *(const float4*)&W[(long)(d0+d)*CC + k0 + kq];
            As[kq+0][d]=a4.x; As[kq+1][d]=a4.y; As[kq+2][d]=a4.z; As[kq+3][d]=a4.w;
        }
        {
            int k = tid >> 4, nq = (tid & 15)*4;
            *(float4*)&Bs[k][nq] = *(const float4*)&X[(long)(k0+k)*NS + n0 + nq];
        }
        __syncthreads();
        #pragma unroll
        for (int kk = 0; kk < 16; kk++) {
            float a0=As[kk][ty*4+0], a1=As[kk][ty*4+1], a2=As[kk][ty*4+2], a3=As[kk][ty*4+3];
            float b0=Bs[kk][tx*4+0], b1=Bs[kk][tx*4+1], b2=Bs[kk][tx*4+2], b3=Bs[kk][tx*4+3];
            acc[0][0]+=a0*b0; acc[0][1]+=a0*b1; acc[0][2]+=a0*b2; acc[0][3]+=a0*b3;
            acc[1][0]+=a1*b0; acc[1][1]+=a1*b1; acc[1][2]+=a1*b2; acc[1][3]+=a1*b3;
            acc[2][0]+=a2*b0; acc[2][1]+=a2*b1; acc[2][2]+=a2*b2; acc[2][3]+=a2*b3;
            acc[3][0]+=a3*b0; acc[3][1]+=a3*b1; acc[3][2]+=a3*b2; acc[3][3]+=a3*b3;
        }
        __syncthreads();
    }
    #pragma unroll
    for (int i = 0; i < 4; i++) {
        int d = d0 + ty*4 + i;
        float g = bn[d], be = bn[CC+d], mu = bn[2*CC+d], va = bn[3*CC+d];
        float inv = g / sqrtf(va + 1e-5f);
        float bv = bias[d];
        float4 o4;
        o4.x = inv*((acc[i][0]+bv) - mu) + be;
        o4.y = inv*((acc[i][1]+bv) - mu) + be;
        o4.z = inv*((acc[i][2]+bv) - mu) + be;
        o4.w = inv*((acc[i][3]+bv) - mu) + be;
        *(float4*)&Y[(long)d*NS + n0 + tx*4] = o4;
    }
}

// ---------------- final LIF (vth=1.0) -> d_out ----------------
__global__ __launch_bounds__(256) void k_final_lif(const float* __restrict__ pre,
                                                   float* __restrict__ out)
{
    int i = blockIdx.x*256 + threadIdx.x;
    float v = 0.f;
    #pragma unroll
    for (int t = 0; t < TT; t++) {
        float xt = pre[t*TSTR + i];
        v += (xt - v)*0.5f;
        float s = (v - 1.0f) >= 0.f ? 1.f : 0.f;
        out[t*TSTR + i] = s;
        v *= (1.f - s);
    }
}

extern "C" void kernel_launch(void* const* d_in, const int* in_sizes, int n_in,
                              void* d_out, int out_size, void* d_ws, size_t ws_size,
                              hipStream_t stream) {
    const float* x   = (const float*)d_in[0];
    const float* wq  = (const float*)d_in[1];
    const float* wk  = (const float*)d_in[2];
    const float* wv  = (const float*)d_in[3];
    const float* kbn = (const float*)d_in[4];
    const float* vbn = (const float*)d_in[5];
    const float* dw  = (const float*)d_in[6];
    const float* dbn = (const float*)d_in[7];
    const float* pw  = (const float*)d_in[8];
    const float* pb  = (const float*)d_in[9];
    const float* pbn = (const float*)d_in[10];
    const float* tw  = (const float*)d_in[11];
    const float* tbi = (const float*)d_in[12];

    float* out  = (float*)d_out;
    float* vout = out + TOT;

    float* ws   = (float*)d_ws;
    ushort* xs  = (ushort*)(ws + OFF_XS);     // bf16 spikes; region later oid fp32
    float* oid  = ws + OFF_XS;
    float* qb   = ws + OFF_Q;      // q_preT fp32 [t][b][n][c] (dead after step 3)
    float* kb   = ws + OFF_K;      // later proj_pre
    float* vb   = ws + OFF_V;
    ushort* qtim = (ushort*)(ws + OFF_Q);     // TIM-out spikes [t][b][n][c]
    // OUTS region: qspT (4*PPL u16) | splT (3*PPL u16); amap overlays after step 5
    ushort* qspT = (ushort*)(ws + OFF_OUTS);
    ushort* splT = qspT + 4L*PPL;
    unsigned char* amap = (unsigned char*)(ws + OFF_OUTS);
    // KTS region: partials (24KB) | qkv wsplit | tim wsplit; kth planes overlay at step 6
    unsigned* partials = (unsigned*)(ws + OFF_KTS);
    ushort* wsp  = (ushort*)(ws + OFF_KTS) + 32768;
    ushort* timw = wsp + 9L*CCSQ;
    ushort* kth = (ushort*)(ws + OFF_KTS);
    ushort* ktm = kth + TOT;
    ushort* ktl = kth + 2L*TOT;
    float* vt   = ws + OFF_VT;
    unsigned* cnt = (unsigned*)(ws + OFF_CNT);

    // 1. shortcut LIF -> bf16 spikes; split weights; zero halo pads
    k_lif_x<<<dim3(TSTR/256), 256, 0, stream>>>(x, xs);
    k_wsplit<<<dim3(3*CCSQ/256), 256, 0, stream>>>(wq, wk, wv, wsp);
    k_wsplit_tim<<<dim3(CCSQ/256), 256, 0, stream>>>(tw, timw);
    k_zero_pads<<<dim3(336), 256, 0, stream>>>((unsigned*)qspT);
    // 2. q/k/v 1x1 convs via MFMA (+BN for k,v); q output transposed
    k_gemm_qkv_mfma<<<dim3(4, 6, 192), 256, 0, stream>>>(wsp, kbn, vbn, xs, qb, kb, vb);
    // 3. LIF on q/k/v; q spikes -> qspT padded; v spikes -> d_out (heads layout)
    k_lif_qkv<<<dim3(TSTR/256, 3), 256, 0, stream>>>(qb, kb, vb, qspT, vout);
    // 4. TIM recurrent conv chain via MFMA (n-major, A from global)
    for (int i = 1; i < TT; i++) {
        k_tim_conv_mfma<<<dim3(4, 6, 16), 512, 0, stream>>>(
            timw, tbi,
            qspT + (long)(i-1)*PPL,
            (i >= 2) ? (splT + (long)(i-2)*PPL) : qspT /*unused*/,
            (i >= 2) ? 1 : 0,
            splT + (long)(i-1)*PPL);
    }
    // 5. TIM output LIF -> qtim bf16 spikes + per-block counts
    k_tim_lif<<<dim3(NPART), 256, 0, stream>>>(qspT, splT, qtim, partials);
    // 5b. reduce partial counts -> cnt
    k_cnt_reduce<<<dim3(1), 256, 0, stream>>>(partials, cnt);
    // 6. dst transform + bn_last; kt as bf16 hi/mid/lo, vt fp32
    k_dst<<<dim3(8, 16, 64), 256, 0, stream>>>(dw, dbn, kb, vb, kth, ktm, ktl, vt);
    // 7. MFMA attention + fused LIF -> binary map (overlays OUTS region)
    k_attn_mfma<<<dim3(4, 4, 128), 256, 0, stream>>>(qtim, kth, ktm, ktl, cnt, amap);
    // 8. attn_map @ v_t, reorder, + identity
    k_outmm<<<dim3(4, 8, 64), 256, 0, stream>>>(amap, vt, x, oid);
    // 9. proj GEMM + bias + BN (proj_pre into kb buffer)
    k_gemm_proj<<<dim3(4, 6, 64), 256, 0, stream>>>(pw, pb, pbn, oid, kb);
    // 10. final LIF -> out
    k_final_lif<<<dim3(TSTR/256), 256, 0, stream>>>(kb, out);
}

// Round 8
// 830.622 us; speedup vs baseline: 1.7845x; 1.0784x over previous
//
#include <hip/hip_runtime.h>
#include <math.h>

#define TT 4
#define BB 16
#define CC 384
#define NS 256
#define NHD 8
#define HDD 48
#define PLANE 98304      /* CC*NS */
#define TSTR  1572864    /* BB*PLANE */
#define TOT   6291456    /* TT*TSTR */
#define CCSQ  147456     /* CC*CC */
#define PB    99840      /* padded batch plane: 260*384 u16 */
#define PPL   1597440    /* padded t-plane: 16*260*384 u16 */

// workspace float offsets (total (8*TOT+16)*4 = 201.3 MB)
#define OFF_XS   0L            /* xs bf16 spikes / later: oid fp32 */
#define OFF_Q    (1L*TOT)      /* q_preT fp32 -> qtim u16 (lower half) + vtl u16 (upper half) */
#define OFF_K    (2L*TOT)      /* k_pre -> k spikes -> proj_pre */
#define OFF_V    (3L*TOT)      /* v_pre -> v spikes */
#define OFF_OUTS (4L*TOT)      /* qspT + splT padded u16 (steps3-5); amap u8 (step7+) */
#define OFF_KTS  (11L*TOT/2)   /* partials | wsp | timw (dead by step6) -> kt hi/mid/lo */
#define OFF_VT   (7L*TOT)      /* vth + vtm u16 planes */
#define OFF_CNT  (8L*TOT)      /* u32 spike counter */

#define NPART 6144             /* TSTR/256 blocks of k_tim_lif */

typedef __attribute__((ext_vector_type(8))) short short8;
typedef __attribute__((ext_vector_type(4))) float f32x4;

__device__ __forceinline__ ushort f2bf(float x) {   // RTNE fp32->bf16
    union { float f; unsigned u; } c; c.f = x;
    unsigned r = c.u + 0x7FFFu + ((c.u >> 16) & 1u);
    return (ushort)(r >> 16);
}
__device__ __forceinline__ float bf2f(ushort h) {
    union { unsigned u; float f; } c; c.u = ((unsigned)h) << 16;
    return c.f;
}

// ---------------- LIF over input x -> xs bf16 spikes (vth=1.0) ----------------
__global__ __launch_bounds__(256) void k_lif_x(const float* __restrict__ x,
                                               ushort* __restrict__ xs)
{
    int i = blockIdx.x*256 + threadIdx.x;   // [0, TSTR)
    float v = 0.f;
    #pragma unroll
    for (int t = 0; t < TT; t++) {
        float xt = x[t*TSTR + i];
        v += (xt - v)*0.5f;
        float s = (v - 1.0f) >= 0.f ? 1.f : 0.f;
        xs[t*TSTR + i] = (s != 0.f) ? (ushort)0x3F80 : (ushort)0;
        v *= (1.f - s);
    }
}

// ---------------- zero the halo pad rows of qspT (4 t) and splT (3 planes) ----------------
__global__ __launch_bounds__(256) void k_zero_pads(unsigned* __restrict__ qspT_u32)
{
    int i = blockIdx.x*256 + threadIdx.x;     // [0, 112*4*192)
    int plane = i / 768, rem = i % 768;
    int r = rem / 192, cu = rem % 192;
    int row = (r < 2) ? r : (256 + r);        // 0,1,258,259
    qspT_u32[(long)plane*(PB/2) + row*192 + cu] = 0;
}

// ---------------- split wq/wk/wv into bf16 hi/mid/lo planes ----------------
__global__ __launch_bounds__(256) void k_wsplit(
    const float* __restrict__ wq, const float* __restrict__ wk, const float* __restrict__ wv,
    ushort* __restrict__ wsp)
{
    int i = blockIdx.x*256 + threadIdx.x;   // [0, 3*CCSQ)
    int which = i / CCSQ, r = i % CCSQ;
    const float* W = (which==0) ? wq : (which==1 ? wk : wv);
    float v = W[r];
    ushort hi = f2bf(v);  float r1 = v - bf2f(hi);
    ushort md = f2bf(r1); float r2 = r1 - bf2f(md);
    ushort lo = f2bf(r2);
    long b = (long)which*3*CCSQ;
    wsp[b + r] = hi; wsp[b + CCSQ + r] = md; wsp[b + 2L*CCSQ + r] = lo;
}

// ---------------- split tim conv weights, tap-major: timw[(pl*5+tap)][d][c] ----------------
__global__ __launch_bounds__(256) void k_wsplit_tim(const float* __restrict__ tw,
                                                    ushort* __restrict__ timw)
{
    int i = blockIdx.x*256 + threadIdx.x;   // [0, CCSQ) = (d,c)
    const float* src = tw + (long)i*5;
    #pragma unroll
    for (int tap = 0; tap < 5; tap++) {
        float v = src[tap];
        ushort hi = f2bf(v);  float r1 = v - bf2f(hi);
        ushort md = f2bf(r1); float r2 = r1 - bf2f(md);
        ushort lo = f2bf(r2);
        timw[(long)(0*5 + tap)*CCSQ + i] = hi;
        timw[(long)(1*5 + tap)*CCSQ + i] = md;
        timw[(long)(2*5 + tap)*CCSQ + i] = lo;
    }
}

// ---------------- MFMA QKV GEMM; q output TRANSPOSED [b][n][c] ----------------
__global__ __launch_bounds__(256) void k_gemm_qkv_mfma(
    const ushort* __restrict__ wsp,
    const float* __restrict__ kbn, const float* __restrict__ vbn,
    const ushort* __restrict__ xs,
    float* __restrict__ qo, float* __restrict__ ko, float* __restrict__ vo)
{
    int which = blockIdx.z >> 6;      // 0=q,1=k,2=v
    int tb    = blockIdx.z & 63;
    const float* bn = (which==0) ? nullptr : (which==1 ? kbn : vbn);
    float* Y        = ((which==0) ? qo : (which==1 ? ko : vo)) + (long)tb*PLANE;
    const ushort* X = xs + (long)tb*PLANE;
    const ushort* Wb = wsp + (long)which*3*CCSQ;
    int d0 = blockIdx.y*64, n0 = blockIdx.x*64;

    __shared__ ushort Ws[3][64][40];
    __shared__ ushort Xs[64][40];

    int tid = threadIdx.x, lane = tid & 63, w = tid >> 6;
    int q4 = lane >> 4, l16 = lane & 15;

    f32x4 acc[4];
    #pragma unroll
    for (int nt = 0; nt < 4; nt++) acc[nt] = (f32x4){0.f,0.f,0.f,0.f};

    for (int k0 = 0; k0 < CC; k0 += 32) {
        __syncthreads();
        {
            int d = tid >> 2, kq = (tid & 3)*8;
            long gofs = (long)(d0+d)*CC + k0 + kq;
            #pragma unroll
            for (int pl = 0; pl < 3; pl++) {
                uint4 t = *(const uint4*)(Wb + (long)pl*CCSQ + gofs);
                *(uint4*)&Ws[pl][d][kq] = t;
            }
        }
        for (int idx = tid; idx < 1024; idx += 256) {
            int kk = idx >> 5;
            int np = (idx & 31) << 1;
            unsigned v = *(const unsigned*)(X + (long)(k0+kk)*NS + n0 + np);
            Xs[np  ][kk] = (ushort)(v & 0xFFFFu);
            Xs[np+1][kk] = (ushort)(v >> 16);
        }
        __syncthreads();

        short8 a0 = *(short8*)&Ws[0][w*16 + l16][q4*8];
        short8 a1 = *(short8*)&Ws[1][w*16 + l16][q4*8];
        short8 a2 = *(short8*)&Ws[2][w*16 + l16][q4*8];
        if (which == 0) {   // swapped: D[n][d] for transposed store
            #pragma unroll
            for (int nt = 0; nt < 4; nt++) {
                short8 b = *(short8*)&Xs[nt*16 + l16][q4*8];
                acc[nt] = __builtin_amdgcn_mfma_f32_16x16x32_bf16(b, a0, acc[nt], 0, 0, 0);
                acc[nt] = __builtin_amdgcn_mfma_f32_16x16x32_bf16(b, a1, acc[nt], 0, 0, 0);
                acc[nt] = __builtin_amdgcn_mfma_f32_16x16x32_bf16(b, a2, acc[nt], 0, 0, 0);
            }
        } else {
            #pragma unroll
            for (int nt = 0; nt < 4; nt++) {
                short8 b = *(short8*)&Xs[nt*16 + l16][q4*8];
                acc[nt] = __builtin_amdgcn_mfma_f32_16x16x32_bf16(a0, b, acc[nt], 0, 0, 0);
                acc[nt] = __builtin_amdgcn_mfma_f32_16x16x32_bf16(a1, b, acc[nt], 0, 0, 0);
                acc[nt] = __builtin_amdgcn_mfma_f32_16x16x32_bf16(a2, b, acc[nt], 0, 0, 0);
            }
        }
    }

    if (which == 0) {
        #pragma unroll
        for (int r = 0; r < 4; r++) {
            int d = d0 + w*16 + l16;
            #pragma unroll
            for (int nt = 0; nt < 4; nt++) {
                int n = n0 + nt*16 + q4*4 + r;
                Y[(long)n*CC + d] = acc[nt][r];
            }
        }
    } else {
        #pragma unroll
        for (int r = 0; r < 4; r++) {
            int d = d0 + w*16 + q4*4 + r;
            float g = bn[d], be = bn[CC+d], mu = bn[2*CC+d], va = bn[3*CC+d];
            float inv = g / sqrtf(va + 1e-5f);
            #pragma unroll
            for (int nt = 0; nt < 4; nt++) {
                int n = n0 + nt*16 + l16;
                Y[(long)d*NS + n] = inv*(acc[nt][r] - mu) + be;
            }
        }
    }
}

// ---------------- LIF: q(0.05)->qspT padded bf16; k,v(1.0) in-place; v->d_out ----------------
__global__ __launch_bounds__(256) void k_lif_qkv(
    const float* __restrict__ qb, float* __restrict__ kb, float* __restrict__ vb,
    ushort* __restrict__ qspT, float* __restrict__ vout)
{
    int which = blockIdx.y;
    int i = blockIdx.x*256 + threadIdx.x;
    const float* rbuf = (which==0) ? qb : (which==1 ? kb : vb);
    float* wbuf = (which==1) ? kb : vb;
    float vth  = (which==0) ? 0.05f : 1.0f;
    int b=0, n=0, h=0, dd=0;
    long qofs = 0;
    if (which == 0) {
        b = i / PLANE;
        qofs = (long)i + b*1536 + 768;   // padded [b][n+2][c] offset
    }
    if (which == 2) {
        b = i / PLANE; int r = i % PLANE;
        int c = r >> 8; n = r & 255;
        h = c / HDD; dd = c % HDD;
    }
    float v = 0.f;
    #pragma unroll
    for (int t = 0; t < TT; t++) {
        float xt = rbuf[t*TSTR + i];
        v += (xt - v)*0.5f;
        float s = (v - vth) >= 0.f ? 1.f : 0.f;
        if (which == 0) qspT[(long)t*PPL + qofs] = (s != 0.f) ? (ushort)0x3F80 : (ushort)0;
        else            wbuf[t*TSTR + i] = s;
        if (which == 2)
            vout[(((long)(t*BB+b)*NHD + h)*NS + n)*HDD + dd] = s;
        v *= (1.f - s);
    }
}

// ---------------- MFMA TIM conv step (n-major): s_i = spike(conv(0.6s+0.4q)) ----------------
__global__ __launch_bounds__(512) void k_tim_conv_mfma(
    const ushort* __restrict__ timw, const float* __restrict__ bias,
    const ushort* __restrict__ qT,      // qspT plane t=i-1, [16][260][384]
    const ushort* __restrict__ sTp,     // s_{i-1} padded plane (unused if !hass)
    int hass,
    ushort* __restrict__ sTo)           // s_i padded plane
{
    int b = blockIdx.z, d0 = blockIdx.y*64, n0 = blockIdx.x*64;
    const ushort* qp = qT  + (long)b*PB;
    const ushort* sp = sTp + (long)b*PB;

    __shared__ ushort Xs[2][68][40];    // 10.9 KB; rows n0-2..n0+65 (padded idx n0+r)

    int tid = threadIdx.x, lane = tid & 63, w = tid >> 6;   // 8 waves
    int q4 = lane >> 4, l16 = lane & 15;
    int dstrip = w >> 1, nh = w & 1;    // wave: 16 d x 32 n

    const ushort* wb = timw + (long)(d0 + dstrip*16 + l16)*CC;

    f32x4 accQ[2], accS[2];
    #pragma unroll
    for (int nt = 0; nt < 2; nt++) {
        accQ[nt] = (f32x4){0.f,0.f,0.f,0.f};
        accS[nt] = (f32x4){0.f,0.f,0.f,0.f};
    }

    for (int c0 = 0; c0 < CC; c0 += 32) {
        __syncthreads();
        int tot = hass ? 544 : 272;           // 68 rows x 4 uint4 x (1|2) tensors
        for (int idx = tid; idx < tot; idx += 512) {
            int tsel = (idx >= 272) ? 1 : 0;
            int rr = idx - tsel*272;
            int r = rr >> 2, c8 = rr & 3;
            const ushort* src = (tsel ? sp : qp) + (long)(n0 + r)*CC + c0 + c8*8;
            *(uint4*)&Xs[tsel][r][c8*8] = *(const uint4*)src;
        }
        __syncthreads();

        #pragma unroll
        for (int tap = 0; tap < 5; tap++) {
            short8 w0 = *(const short8*)(wb + (long)(0*5 + tap)*CCSQ + c0 + q4*8);
            short8 w1 = *(const short8*)(wb + (long)(1*5 + tap)*CCSQ + c0 + q4*8);
            short8 w2 = *(const short8*)(wb + (long)(2*5 + tap)*CCSQ + c0 + q4*8);
            #pragma unroll
            for (int nt = 0; nt < 2; nt++) {
                int row = nh*32 + nt*16 + l16 + tap;
                short8 aq = *(short8*)&Xs[0][row][q4*8];
                accQ[nt] = __builtin_amdgcn_mfma_f32_16x16x32_bf16(aq, w0, accQ[nt], 0, 0, 0);
                accQ[nt] = __builtin_amdgcn_mfma_f32_16x16x32_bf16(aq, w1, accQ[nt], 0, 0, 0);
                accQ[nt] = __builtin_amdgcn_mfma_f32_16x16x32_bf16(aq, w2, accQ[nt], 0, 0, 0);
                if (hass) {
                    short8 as = *(short8*)&Xs[1][row][q4*8];
                    accS[nt] = __builtin_amdgcn_mfma_f32_16x16x32_bf16(as, w0, accS[nt], 0, 0, 0);
                    accS[nt] = __builtin_amdgcn_mfma_f32_16x16x32_bf16(as, w1, accS[nt], 0, 0, 0);
                    accS[nt] = __builtin_amdgcn_mfma_f32_16x16x32_bf16(as, w2, accS[nt], 0, 0, 0);
                }
            }
        }
    }

    // epilogue: D rows = n (q4*4+r), cols = d (l16)
    ushort* so = sTo + (long)b*PB;
    int d = d0 + dstrip*16 + l16;
    float bv = bias[d];
    #pragma unroll
    for (int nt = 0; nt < 2; nt++) {
        #pragma unroll
        for (int r = 0; r < 4; r++) {
            int n = n0 + nh*32 + nt*16 + q4*4 + r;
            float conv = hass ? (0.6f*accS[nt][r] + 0.4f*accQ[nt][r]) : accQ[nt][r];
            float c = conv + bv;
            float s = (c*0.5f - 0.3f) >= 0.f ? 1.f : 0.f;
            so[(long)(n + 2)*CC + d] = (s != 0.f) ? (ushort)0x3F80 : (ushort)0;
        }
    }
}

// ---------------- TIM output LIF: reconstruct outs, LIF(0.5) -> qtim [b][n][c] + counts ----------------
__global__ __launch_bounds__(256) void k_tim_lif(const ushort* __restrict__ qspT,
                                                 const ushort* __restrict__ splT,
                                                 ushort* __restrict__ qtim,
                                                 unsigned* __restrict__ partials)
{
    int i = blockIdx.x*256 + threadIdx.x;    // flat (b,n,c)
    int b = i / PLANE;
    long po = (long)i + b*1536 + 768;        // padded offset
    float v = 0.f; unsigned c = 0;
    #pragma unroll
    for (int t = 0; t < TT; t++) {
        float val;
        if (t == 0) {
            val = bf2f(qspT[po]);
        } else {
            float sf = bf2f(splT[(long)(t-1)*PPL + po]);
            float qf = bf2f(qspT[(long)t*PPL + po]);
            val = sf*0.6f + qf*0.4f;
        }
        v += (val - v)*0.5f;
        float s = (v - 0.5f) >= 0.f ? 1.f : 0.f;
        qtim[(long)t*TSTR + i] = (s != 0.f) ? (ushort)0x3F80 : (ushort)0;
        c += (unsigned)s;
        v *= (1.f - s);
    }
    #pragma unroll
    for (int off = 32; off >= 1; off >>= 1) c += __shfl_down(c, off, 64);
    __shared__ unsigned wsum[4];
    if ((threadIdx.x & 63) == 0) wsum[threadIdx.x >> 6] = c;
    __syncthreads();
    if (threadIdx.x == 0)
        partials[blockIdx.x] = wsum[0] + wsum[1] + wsum[2] + wsum[3];
}

// ---------------- reduce NPART partials -> cnt ----------------
__global__ __launch_bounds__(256) void k_cnt_reduce(const unsigned* __restrict__ partials,
                                                    unsigned* __restrict__ cnt)
{
    unsigned c = 0;
    for (int i = threadIdx.x; i < NPART; i += 256) c += partials[i];
    #pragma unroll
    for (int off = 32; off >= 1; off >>= 1) c += __shfl_down(c, off, 64);
    __shared__ unsigned wsum[4];
    if ((threadIdx.x & 63) == 0) wsum[threadIdx.x >> 6] = c;
    __syncthreads();
    if (threadIdx.x == 0)
        cnt[0] = wsum[0] + wsum[1] + wsum[2] + wsum[3];
}

// ---------------- dst transform + bn_last; kt -> [n][e] 3-split; vtT -> [e][n] 3-split ----------------
__global__ __launch_bounds__(256) void k_dst(
    const float* __restrict__ dw, const float* __restrict__ dbn,
    const float* __restrict__ kin, const float* __restrict__ vin,
    ushort* __restrict__ kth, ushort* __restrict__ ktm, ushort* __restrict__ ktl,
    ushort* __restrict__ vth, ushort* __restrict__ vtm, ushort* __restrict__ vtl)
{
    int tb  = blockIdx.z;
    int h   = blockIdx.y & 7;
    int isv = blockIdx.y >> 3;
    int n0  = blockIdx.x*32;
    const float* src = (isv ? vin : kin) + (long)tb*PLANE + (h*HDD)*NS;
    __shared__ float Xs[48][33];
    __shared__ float Wsh[48][49];
    int tid = threadIdx.x;
    for (int idx = tid; idx < 48*32; idx += 256) {
        int d = idx >> 5, n = idx & 31;
        Xs[d][n] = src[d*NS + n0 + n];
    }
    for (int idx = tid; idx < 48*48; idx += 256) {
        int e = idx / 48, d = idx % 48;
        Wsh[e][d] = dw[idx];
    }
    __syncthreads();
    #pragma unroll
    for (int r = 0; r < 6; r++) {
        int o = tid + r*256;
        int n, e;
        if (isv) { e = o >> 5; n = o & 31; }        // coalesced in n for [e][n] stores
        else     { n = o / 48; e = o % 48; }
        float acc = 0.f;
        #pragma unroll
        for (int d = 0; d < 48; d++) acc += Wsh[e][d]*Xs[d][n];
        float g = dbn[e], be = dbn[48+e], mu = dbn[96+e], va = dbn[144+e];
        float val = g / sqrtf(va + 1e-5f) * (acc - mu) + be;
        ushort hi = f2bf(val);
        float r1 = val - bf2f(hi);
        ushort md = f2bf(r1);
        float r2 = r1 - bf2f(md);
        ushort lo = f2bf(r2);
        if (isv) {
            long gi = ((long)(tb*NHD + h)*HDD + e)*NS + n0 + n;
            vth[gi] = hi; vtm[gi] = md; vtl[gi] = lo;
        } else {
            long gi = ((long)(tb*NHD + h)*NS + n0 + n)*HDD + e;
            kth[gi] = hi; ktm[gi] = md; ktl[gi] = lo;
        }
    }
}

// ---------------- MFMA attention: QK^T * c1 -> fused LIF(0.5) -> u8 map ----------------
__global__ __launch_bounds__(256) void k_attn_mfma(
    const ushort* __restrict__ qtim,
    const ushort* __restrict__ kth, const ushort* __restrict__ ktm, const ushort* __restrict__ ktl,
    const unsigned* __restrict__ cnt, unsigned char* __restrict__ amap)
{
    int bh = blockIdx.z;            // b*8+h
    int b = bh >> 3, h = bh & 7;
    int nbase = blockIdx.y*64, mbase = blockIdx.x*64;

    __shared__ ushort Qs[64][72];
    __shared__ ushort Kh[64][72];
    __shared__ ushort Km[64][72];
    __shared__ ushort Kl[64][72];

    int tid  = threadIdx.x;
    int lane = tid & 63, w = tid >> 6;
    int q4 = lane >> 4, l16 = lane & 15;

    float mean = (float)(*cnt) / 6291456.0f;
    float c1 = fminf(1.0f / sqrtf(mean*48.0f + 1e-6f), 10.0f);

    {
        unsigned* z0 = (unsigned*)&Qs[0][0];
        unsigned* z1 = (unsigned*)&Kh[0][0];
        unsigned* z2 = (unsigned*)&Km[0][0];
        unsigned* z3 = (unsigned*)&Kl[0][0];
        for (int i2 = tid; i2 < 64*72/2; i2 += 256) {
            z0[i2] = 0; z1[i2] = 0; z2[i2] = 0; z3[i2] = 0;
        }
    }

    float vmem[4][4];
    #pragma unroll
    for (int a = 0; a < 4; a++)
        #pragma unroll
        for (int r = 0; r < 4; r++) vmem[a][r] = 0.f;

    for (int t = 0; t < TT; t++) {
        int tb = t*BB + b;
        __syncthreads();
        const ushort* qsrc = qtim + (long)tb*PLANE + (long)nbase*CC + h*HDD;
        for (int idx = tid; idx < 768; idx += 256) {
            int n = idx / 12, c4 = idx % 12;
            *(uint2*)&Qs[n][c4*4] = *(const uint2*)(qsrc + (long)n*CC + c4*4);
        }
        long kb0 = ((long)(tb*NHD + h)*NS + mbase)*HDD;
        const ushort* kbh = kth + kb0;
        const ushort* kbm = ktm + kb0;
        const ushort* kbl = ktl + kb0;
        for (int idx = tid; idx < 1536; idx += 256) {
            int e2 = idx << 1;
            int m = e2 / HDD, er = e2 % HDD;
            *(unsigned*)&Kh[m][er] = *(const unsigned*)(kbh + e2);
            *(unsigned*)&Km[m][er] = *(const unsigned*)(kbm + e2);
            *(unsigned*)&Kl[m][er] = *(const unsigned*)(kbl + e2);
        }
        __syncthreads();

        int nrow = w*16 + l16;
        f32x4 acc[4];
        #pragma unroll
        for (int mt = 0; mt < 4; mt++) acc[mt] = (f32x4){0.f, 0.f, 0.f, 0.f};

        #pragma unroll
        for (int ks = 0; ks < 2; ks++) {
            short8 a = *(short8*)&Qs[nrow][ks*32 + q4*8];
            #pragma unroll
            for (int mt = 0; mt < 4; mt++) {
                int mrow = mt*16 + l16;
                short8 b_h = *(short8*)&Kh[mrow][ks*32 + q4*8];
                short8 b_m = *(short8*)&Km[mrow][ks*32 + q4*8];
                short8 b_l = *(short8*)&Kl[mrow][ks*32 + q4*8];
                acc[mt] = __builtin_amdgcn_mfma_f32_16x16x32_bf16(a, b_h, acc[mt], 0, 0, 0);
                acc[mt] = __builtin_amdgcn_mfma_f32_16x16x32_bf16(a, b_m, acc[mt], 0, 0, 0);
                acc[mt] = __builtin_amdgcn_mfma_f32_16x16x32_bf16(a, b_l, acc[mt], 0, 0, 0);
            }
        }

        long abase0 = ((long)(tb*NHD + h)*NS)*NS;
        #pragma unroll
        for (int mt = 0; mt < 4; mt++) {
            int m = mbase + mt*16 + l16;
            #pragma unroll
            for (int r = 0; r < 4; r++) {
                int n = nbase + w*16 + q4*4 + r;
                float a = acc[mt][r]*c1;
                float v = vmem[mt][r];
                v += (a - v)*0.5f;
                float s = (v - 0.5f) >= 0.f ? 1.f : 0.f;
                amap[abase0 + (long)n*NS + m] = (unsigned char)s;
                vmem[mt][r] = v*(1.f - s);
            }
        }
    }
}

// ---------------- MFMA out = amap @ v_t, + identity -> oid [tb][c][n] ----------------
// amap binary u8 -> exact bf16 A-frags; vtT 3-split [e][m] bf16 B-frags (direct global).
__global__ __launch_bounds__(256) void k_outmm_mfma(
    const unsigned char* __restrict__ amap,
    const ushort* __restrict__ vth, const ushort* __restrict__ vtm, const ushort* __restrict__ vtl,
    const float* __restrict__ x, float* __restrict__ oid)
{
    int tbh = blockIdx.y;           // tb*8+h, [0, 512)
    int tb = tbh >> 3, h = tbh & 7;
    int tid = threadIdx.x, lane = tid & 63, w = tid >> 6;
    int q4 = lane >> 4, l16 = lane & 15;
    int nbase = blockIdx.x*64 + w*16;

    const unsigned char* arow = amap + ((long)tbh*NS + nbase + l16)*NS;
    long vbase = (long)tbh*HDD*NS;

    f32x4 acc[3];
    #pragma unroll
    for (int et = 0; et < 3; et++) acc[et] = (f32x4){0.f,0.f,0.f,0.f};

    for (int k0 = 0; k0 < NS; k0 += 32) {
        uint2 u = *(const uint2*)(arow + k0 + q4*8);
        short8 a;
        #pragma unroll
        for (int j = 0; j < 4; j++) {
            a[j]   = ((u.x >> (8*j)) & 0xFFu) ? (short)0x3F80 : (short)0;
            a[j+4] = ((u.y >> (8*j)) & 0xFFu) ? (short)0x3F80 : (short)0;
        }
        #pragma unroll
        for (int et = 0; et < 3; et++) {
            long vo = vbase + (long)(et*16 + l16)*NS + k0 + q4*8;
            short8 bh = *(const short8*)(vth + vo);
            short8 bm = *(const short8*)(vtm + vo);
            short8 bl = *(const short8*)(vtl + vo);
            acc[et] = __builtin_amdgcn_mfma_f32_16x16x32_bf16(a, bh, acc[et], 0, 0, 0);
            acc[et] = __builtin_amdgcn_mfma_f32_16x16x32_bf16(a, bm, acc[et], 0, 0, 0);
            acc[et] = __builtin_amdgcn_mfma_f32_16x16x32_bf16(a, bl, acc[et], 0, 0, 0);
        }
    }
    // epilogue: D rows (q4*4+r) -> n, cols l16 -> e; + identity, fp32 [c][n] store
    #pragma unroll
    for (int et = 0; et < 3; et++) {
        int e = et*16 + l16;
        int n = nbase + q4*4;
        long base = (long)tb*PLANE + (long)(h*HDD + e)*NS + n;
        float4 xi = *(const float4*)(x + base);
        float4 o4;
        o4.x = acc[et][0] + xi.x;
        o4.y = acc[et][1] + xi.y;
        o4.z = acc[et][2] + xi.z;
        o4.w = acc[et][3] + xi.w;
        *(float4*)(oid + base) = o4;
    }
}

// ---------------- proj GEMM + bias + BN ----------------
__global__ __launch_bounds__(256) void k_gemm_proj(
    const float* __restrict__ W, const float* __restrict__ bias, const float* __restrict__ bn,
    const float* __restrict__ Xfull, float* __restrict__ Yfull)
{
    int tb = blockIdx.z;
    const float* X = Xfull + (long)tb*PLANE;
    float* Y = Yfull + (long)tb*PLANE;
    int d0 = blockIdx.y*64, n0 = blockIdx.x*64;

    __shared__ float As[16][68];
    __shared__ float Bs[16][68];
    int tid = threadIdx.x;
    int ty = tid >> 4, tx = tid & 15;
    float acc[4][4] = {};

    for (int k0 = 0; k0 < CC; k0 += 16) {
        {
            int d = tid >> 2, kq = (tid & 3)*4;
            float4 a4 = *(const float4*)&W[(long)(d0+d)*CC + k0 + kq];
            As[kq+0][d]=a4.x; As[kq+1][d]=a4.y; As[kq+2][d]=a4.z; As[kq+3][d]=a4.w;
        }
        {
            int k = tid >> 4, nq = (tid & 15)*4;
            *(float4*)&Bs[k][nq] = *(const float4*)&X[(long)(k0+k)*NS + n0 + nq];
        }
        __syncthreads();
        #pragma unroll
        for (int kk = 0; kk < 16; kk++) {
            float a0=As[kk][ty*4+0], a1=As[kk][ty*4+1], a2=As[kk][ty*4+2], a3=As[kk][ty*4+3];
            float b0=Bs[kk][tx*4+0], b1=Bs[kk][tx*4+1], b2=Bs[kk][tx*4+2], b3=Bs[kk][tx*4+3];
            acc[0][0]+=a0*b0; acc[0][1]+=a0*b1; acc[0][2]+=a0*b2; acc[0][3]+=a0*b3;
            acc[1][0]+=a1*b0; acc[1][1]+=a1*b1; acc[1][2]+=a1*b2; acc[1][3]+=a1*b3;
            acc[2][0]+=a2*b0; acc[2][1]+=a2*b1; acc[2][2]+=a2*b2; acc[2][3]+=a2*b3;
            acc[3][0]+=a3*b0; acc[3][1]+=a3*b1; acc[3][2]+=a3*b2; acc[3][3]+=a3*b3;
        }
        __syncthreads();
    }
    #pragma unroll
    for (int i = 0; i < 4; i++) {
        int d = d0 + ty*4 + i;
        float g = bn[d], be = bn[CC+d], mu = bn[2*CC+d], va = bn[3*CC+d];
        float inv = g / sqrtf(va + 1e-5f);
        float bv = bias[d];
        float4 o4;
        o4.x = inv*((acc[i][0]+bv) - mu) + be;
        o4.y = inv*((acc[i][1]+bv) - mu) + be;
        o4.z = inv*((acc[i][2]+bv) - mu) + be;
        o4.w = inv*((acc[i][3]+bv) - mu) + be;
        *(float4*)&Y[(long)d*NS + n0 + tx*4] = o4;
    }
}

// ---------------- final LIF (vth=1.0) -> d_out ----------------
__global__ __launch_bounds__(256) void k_final_lif(const float* __restrict__ pre,
                                                   float* __restrict__ out)
{
    int i = blockIdx.x*256 + threadIdx.x;
    float v = 0.f;
    #pragma unroll
    for (int t = 0; t < TT; t++) {
        float xt = pre[t*TSTR + i];
        v += (xt - v)*0.5f;
        float s = (v - 1.0f) >= 0.f ? 1.f : 0.f;
        out[t*TSTR + i] = s;
        v *= (1.f - s);
    }
}

extern "C" void kernel_launch(void* const* d_in, const int* in_sizes, int n_in,
                              void* d_out, int out_size, void* d_ws, size_t ws_size,
                              hipStream_t stream) {
    const float* x   = (const float*)d_in[0];
    const float* wq  = (const float*)d_in[1];
    const float* wk  = (const float*)d_in[2];
    const float* wv  = (const float*)d_in[3];
    const float* kbn = (const float*)d_in[4];
    const float* vbn = (const float*)d_in[5];
    const float* dw  = (const float*)d_in[6];
    const float* dbn = (const float*)d_in[7];
    const float* pw  = (const float*)d_in[8];
    const float* pb  = (const float*)d_in[9];
    const float* pbn = (const float*)d_in[10];
    const float* tw  = (const float*)d_in[11];
    const float* tbi = (const float*)d_in[12];

    float* out  = (float*)d_out;
    float* vout = out + TOT;

    float* ws   = (float*)d_ws;
    ushort* xs  = (ushort*)(ws + OFF_XS);     // bf16 spikes; region later oid fp32
    float* oid  = ws + OFF_XS;
    float* qb   = ws + OFF_Q;      // q_preT fp32 (dead after step 3)
    float* kb   = ws + OFF_K;      // later proj_pre
    float* vb   = ws + OFF_V;
    ushort* qtim = (ushort*)(ws + OFF_Q);          // lower half of Q region
    ushort* vtl  = (ushort*)(ws + OFF_Q) + TOT;    // upper half of Q region (step6+)
    // OUTS region: qspT (4*PPL u16) | splT (3*PPL u16); amap overlays after step 5
    ushort* qspT = (ushort*)(ws + OFF_OUTS);
    ushort* splT = qspT + 4L*PPL;
    unsigned char* amap = (unsigned char*)(ws + OFF_OUTS);
    // KTS region: partials (24KB) | qkv wsplit | tim wsplit; kth planes overlay at step 6
    unsigned* partials = (unsigned*)(ws + OFF_KTS);
    ushort* wsp  = (ushort*)(ws + OFF_KTS) + 32768;
    ushort* timw = wsp + 9L*CCSQ;
    ushort* kth = (ushort*)(ws + OFF_KTS);
    ushort* ktm = kth + TOT;
    ushort* ktl = kth + 2L*TOT;
    ushort* vth = (ushort*)(ws + OFF_VT);
    ushort* vtm = vth + TOT;
    unsigned* cnt = (unsigned*)(ws + OFF_CNT);

    // 1. shortcut LIF -> bf16 spikes; split weights; zero halo pads
    k_lif_x<<<dim3(TSTR/256), 256, 0, stream>>>(x, xs);
    k_wsplit<<<dim3(3*CCSQ/256), 256, 0, stream>>>(wq, wk, wv, wsp);
    k_wsplit_tim<<<dim3(CCSQ/256), 256, 0, stream>>>(tw, timw);
    k_zero_pads<<<dim3(336), 256, 0, stream>>>((unsigned*)qspT);
    // 2. q/k/v 1x1 convs via MFMA (+BN for k,v); q output transposed
    k_gemm_qkv_mfma<<<dim3(4, 6, 192), 256, 0, stream>>>(wsp, kbn, vbn, xs, qb, kb, vb);
    // 3. LIF on q/k/v; q spikes -> qspT padded; v spikes -> d_out (heads layout)
    k_lif_qkv<<<dim3(TSTR/256, 3), 256, 0, stream>>>(qb, kb, vb, qspT, vout);
    // 4. TIM recurrent conv chain via MFMA (X in LDS, W streamed to VGPR)
    for (int i = 1; i < TT; i++) {
        k_tim_conv_mfma<<<dim3(4, 6, 16), 512, 0, stream>>>(
            timw, tbi,
            qspT + (long)(i-1)*PPL,
            (i >= 2) ? (splT + (long)(i-2)*PPL) : qspT /*unused*/,
            (i >= 2) ? 1 : 0,
            splT + (long)(i-1)*PPL);
    }
    // 5. TIM output LIF -> qtim bf16 spikes + per-block counts
    k_tim_lif<<<dim3(NPART), 256, 0, stream>>>(qspT, splT, qtim, partials);
    // 5b. reduce partial counts -> cnt
    k_cnt_reduce<<<dim3(1), 256, 0, stream>>>(partials, cnt);
    // 6. dst transform + bn_last; kt [n][e] + vtT [e][n], both 3-split bf16
    k_dst<<<dim3(8, 16, 64), 256, 0, stream>>>(dw, dbn, kb, vb, kth, ktm, ktl, vth, vtm, vtl);
    // 7. MFMA attention + fused LIF -> binary map (overlays OUTS region)
    k_attn_mfma<<<dim3(4, 4, 128), 256, 0, stream>>>(qtim, kth, ktm, ktl, cnt, amap);
    // 8. MFMA out = amap @ v_t + identity -> oid  (grid.y = 512 head-planes; R6 bug: was 128)
    k_outmm_mfma<<<dim3(4, 512), 256, 0, stream>>>(amap, vth, vtm, vtl, x, oid);
    // 9. proj GEMM + bias + BN (proj_pre into kb buffer)
    k_gemm_proj<<<dim3(4, 6, 64), 256, 0, stream>>>(pw, pb, pbn, oid, kb);
    // 10. final LIF -> out
    k_final_lif<<<dim3(TSTR/256), 256, 0, stream>>>(kb, out);
}